// Round 4
// baseline (884.084 us; speedup 1.0000x reference)
//
#include <hip/hip_runtime.h>

// ---------------- problem constants ----------------
constexpr int BB = 4, TT = 1024, DD = 512, HH = 8, HDIM = 64;
constexpr int FFD = 2048, NLAYER = 2, MM = 512, SS = 1536;
constexpr float LN_EPS = 1e-5f;
constexpr float SCALE = 0.04419417382415922f; // 1/sqrt(512)

typedef unsigned short u16;
typedef __attribute__((ext_vector_type(8))) short bf16x8;
typedef __attribute__((ext_vector_type(4))) float f32x4;

__device__ __forceinline__ float b2f(u16 u) {
  union { unsigned int i; float f; } c; c.i = ((unsigned int)u) << 16; return c.f;
}
__device__ __forceinline__ u16 f2b(float f) {
  unsigned int x = __builtin_bit_cast(unsigned int, f);
  x += 0x7fffu + ((x >> 16) & 1u);   // RNE (finite values only)
  return (u16)(x >> 16);
}

// async global->LDS DMA, 16B per lane. LDS dest = uniform base + lane*16.
__device__ __forceinline__ void dma16(const u16* g, u16* l) {
  __builtin_amdgcn_global_load_lds(
      (const __attribute__((address_space(1))) unsigned int*)g,
      (__attribute__((address_space(3))) unsigned int*)l, 16, 0, 0);
}

// ---------------- canonical input buffer offsets (elements) ----------------
constexpr int OFF_X    = 0;          // 2,097,152
constexpr int OFF_MEMS = 2097152;    // 3,145,728
constexpr int OFF_UB   = 5242880;    // 512
constexpr int OFF_VB   = 5243392;    // 512
constexpr int OFF_QKVW = 5243904;    // 1,572,864 (786,432 per layer)
constexpr int OFF_POSW = 6816768;    // 524,288 (262,144 per layer)
constexpr int OFF_OUTW = 7341056;    // 524,288
constexpr int OFF_L1W  = 7865344;    // 2,097,152 (1,048,576 per layer)
constexpr int OFF_L1B  = 9962496;    // 4,096 (2,048 per layer)
constexpr int OFF_L2W  = 9966592;    // 2,097,152
constexpr int OFF_L2B  = 12063744;   // 1,024 (512 per layer)
constexpr int OFF_LN1S = 12064768;
constexpr int OFF_LN1B = 12065792;
constexpr int OFF_LN2S = 12066816;
constexpr int OFF_LN2B = 12067840;
constexpr int TOT_IN   = 12068864;   // = 47,144 * 256

// ---------------- dtype probe ----------------
__global__ void txl_probe(const u16* __restrict__ xr, int* __restrict__ flag) {
  int lane = threadIdx.x;   // 64 threads
  int cnt = 0;
  for (int k = 0; k < 8; ++k) {
    u16 u = xr[lane * 8 + k];
    int e = (u >> 7) & 0xFF;
    if (e >= 0xC0) ++cnt;
  }
  for (int o = 32; o; o >>= 1) cnt += __shfl_xor(cnt, o);
  if (lane == 0) *flag = (cnt >= 32) ? 1 : 0;   // 1 => inputs are f32
}

// ---------------- convert all float inputs to canonical bf16 buffer ----------------
__global__ __launch_bounds__(256) void txl_convert(
    const void* x, const void* mems, const void* ub, const void* vb,
    const void* qkvw, const void* posw, const void* outw,
    const void* l1w, const void* l1b, const void* l2w, const void* l2b,
    const void* ln1s, const void* ln1b, const void* ln2s, const void* ln2b,
    u16* __restrict__ dst, const int* __restrict__ flag) {
  int idx = blockIdx.x * 256 + threadIdx.x;
  if (idx >= TOT_IN) return;
  const void* p; int local;
  if      (idx < OFF_MEMS) { p = x;    local = idx; }
  else if (idx < OFF_UB)   { p = mems; local = idx - OFF_MEMS; }
  else if (idx < OFF_VB)   { p = ub;   local = idx - OFF_UB; }
  else if (idx < OFF_QKVW) { p = vb;   local = idx - OFF_VB; }
  else if (idx < OFF_POSW) { p = qkvw; local = idx - OFF_QKVW; }
  else if (idx < OFF_OUTW) { p = posw; local = idx - OFF_POSW; }
  else if (idx < OFF_L1W)  { p = outw; local = idx - OFF_OUTW; }
  else if (idx < OFF_L1B)  { p = l1w;  local = idx - OFF_L1W; }
  else if (idx < OFF_L2W)  { p = l1b;  local = idx - OFF_L1B; }
  else if (idx < OFF_L2B)  { p = l2w;  local = idx - OFF_L2W; }
  else if (idx < OFF_LN1S) { p = l2b;  local = idx - OFF_L2B; }
  else if (idx < OFF_LN1B) { p = ln1s; local = idx - OFF_LN1S; }
  else if (idx < OFF_LN2S) { p = ln1b; local = idx - OFF_LN1B; }
  else if (idx < OFF_LN2B) { p = ln2s; local = idx - OFF_LN2S; }
  else                     { p = ln2b; local = idx - OFF_LN2B; }
  dst[idx] = (*flag) ? f2b(((const float*)p)[local]) : ((const u16*)p)[local];
}

// ---------------- GEMM v3: C = A[M,K] * B[N,K]^T, fused epilogues ----------------
// m97 structure (128x128 tile, BK=32, global_load_lds width-16 into linear LDS).
// EPI 0: f32 C.  EPI 1: bias+relu -> bf16 (O1, bias1).
// EPI 2: qkv scatter -> qu/qv (u,v bias; rows s>=512), kb, vbf. A split: rows
//        < msplit from A (mems), else A2 (cur). Dead blocks (q-cols x mem-rows)
//        early-exit.
// EPI 3: r scatter -> rb[(n*SS+p)*64+d].
template <int EPI>
__global__ __launch_bounds__(256) void txl_gemm3(
    const u16* __restrict__ A, const u16* __restrict__ A2, int msplit,
    const u16* __restrict__ B, float* __restrict__ C,
    u16* __restrict__ O1, u16* __restrict__ O2, u16* __restrict__ O3,
    u16* __restrict__ O4, const u16* __restrict__ bias1, const u16* __restrict__ bias2,
    int M, int N, int K) {
  const int m0 = blockIdx.x * 128, n0 = blockIdx.y * 128;
  if (EPI == 2 && n0 < 512 && m0 < msplit) return;   // q-output for mem rows: unused
  __shared__ __align__(16) u16 As[128 * 32];
  __shared__ __align__(16) u16 Bs[128 * 32];
  const int tid = threadIdx.x;
  const int wave = tid >> 6, lane = tid & 63;
  const int wm = (wave & 1) * 64, wn = (wave >> 1) * 64;
  const int L15 = lane & 15, quad = lane >> 4;
  const u16* Abase = (m0 < msplit) ? (A + (size_t)m0 * K) : (A2 + (size_t)(m0 - msplit) * K);
  f32x4 acc[4][4] = {};
  for (int k0 = 0; k0 < K; k0 += 32) {
    for (int c = 0; c < 2; ++c) {
      int segBase = c * 256 + wave * 64;
      int seg = segBase + lane;
      int row = seg >> 2, q = seg & 3;
      dma16(&Abase[(size_t)row * K + k0 + q * 8], &As[segBase * 8]);
      dma16(&B[(size_t)(n0 + row) * K + k0 + q * 8], &Bs[segBase * 8]);
    }
    __syncthreads();
    bf16x8 af[4], bfr[4];
    for (int t = 0; t < 4; ++t)
      af[t] = *reinterpret_cast<const bf16x8*>(&As[(wm + t * 16 + L15) * 32 + quad * 8]);
    for (int t = 0; t < 4; ++t)
      bfr[t] = *reinterpret_cast<const bf16x8*>(&Bs[(wn + t * 16 + L15) * 32 + quad * 8]);
    for (int tm = 0; tm < 4; ++tm)
      for (int tn = 0; tn < 4; ++tn)
        acc[tm][tn] = __builtin_amdgcn_mfma_f32_16x16x32_bf16(af[tm], bfr[tn], acc[tm][tn], 0, 0, 0);
    __syncthreads();
  }
  for (int tm = 0; tm < 4; ++tm)
    for (int tn = 0; tn < 4; ++tn) {
      const int col = n0 + wn + tn * 16 + L15;
      float ubv = 0.f, vbv = 0.f;
      if (EPI == 2 && n0 < 512) { ubv = b2f(bias1[col]); vbv = b2f(bias2[col]); }
      for (int r = 0; r < 4; ++r) {
        const int row = m0 + wm + tm * 16 + quad * 4 + r;
        const float v = acc[tm][tn][r];
        if (EPI == 0) {
          C[(size_t)row * N + col] = v;
        } else if (EPI == 1) {
          O1[(size_t)row * N + col] = f2b(fmaxf(v + b2f(bias1[col]), 0.f));
        } else if (EPI == 2) {
          const int s = row >> 2, bb = row & 3;
          if (n0 < 512) {          // q (s >= 512 guaranteed by early-exit)
            const int n = col >> 6, d = col & 63;
            size_t o = ((size_t)(bb * HH + n) * TT + (s - MM)) * HDIM + d;
            O1[o] = f2b(v + ubv);
            O2[o] = f2b(v + vbv);
          } else if (n0 < 1024) {  // k
            const int e2 = col - 512, n = e2 >> 6, d = e2 & 63;
            O3[((size_t)(bb * HH + n) * SS + s) * HDIM + d] = f2b(v);
          } else {                 // v -> compact bf16 row-major buffer
            O4[(size_t)row * 512 + (col - 1024)] = f2b(v);
          }
        } else {                   // EPI == 3: r
          const int n = col >> 6, d = col & 63;
          O1[((size_t)n * SS + row) * HDIM + d] = f2b(v);
        }
      }
    }
}

// ---------------- sinusoid positional encoding (positions are S-1..0) ----------------
__global__ void txl_pe(u16* __restrict__ pe) {
  int idx = blockIdx.x * 256 + threadIdx.x;    // SS*256
  if (idx >= SS * 256) return;
  int p = idx >> 8, m = idx & 255;
  float posf = (float)(SS - 1 - p);
  float div = expf((float)(2 * m) * (-9.210340371976184f / 512.0f));
  float a = posf * div;
  pe[(size_t)p * DD + 2 * m] = f2b(sinf(a));
  pe[(size_t)p * DD + 2 * m + 1] = f2b(cosf(a));
}

// ---------------- [B,T,D] -> [T,B,D] + fused new_mems[0] store ----------------
__global__ void txl_transpose_in(const u16* __restrict__ x, u16* __restrict__ cur_bf,
                                 float* __restrict__ cur_f, void* __restrict__ outv,
                                 const int* __restrict__ flag) {
  int idx = blockIdx.x * 256 + threadIdx.x;    // BB*TT*DD
  if (idx >= BB * TT * DD) return;
  int b = idx >> 19, t = (idx >> 9) & 1023, d = idx & 511;
  u16 v = x[idx];
  size_t o = ((size_t)t * BB + b) * DD + d;
  cur_bf[o] = v; cur_f[o] = b2f(v);
  if (t >= 512) {                               // new_mems[0] = xs rows 512..1023
    size_t mo = 2097152 + (o - 1048576);
    if (*flag) ((float*)outv)[mo] = b2f(v);
    else       ((u16*)outv)[mo] = v;
  }
}

__global__ void txl_store_final(const u16* __restrict__ cur_bf, void* __restrict__ outv,
                                const int* __restrict__ flag) {
  int idx = blockIdx.x * 256 + threadIdx.x;
  if (idx >= BB * TT * DD) return;
  int b = idx >> 19, t = (idx >> 9) & 1023, d = idx & 511;
  u16 v = cur_bf[((size_t)t * BB + b) * DD + d];
  if (*flag) ((float*)outv)[idx] = b2f(v);
  else       ((u16*)outv)[idx] = v;
}

// ---------------- V transpose via LDS: coalesced vT stores (bf16 input) ----------------
__global__ __launch_bounds__(256) void txl_v_transpose(const u16* __restrict__ vbf,
                                                       u16* __restrict__ vT) {
  __shared__ u16 t[64][68];
  int bx = blockIdx.x;
  int sb = bx >> 5;           // 0..23
  int bn = bx & 31;
  int n = bn & 7, b = bn >> 3;
  int tid = threadIdx.x;
  int s0 = sb * 64;
  {
    int d = tid & 63, sr = tid >> 6;
    for (int i = 0; i < 16; ++i) {
      int s = s0 + sr + i * 4;
      t[sr + i * 4][d] = vbf[(size_t)(s * 4 + b) * 512 + n * 64 + d];
    }
  }
  __syncthreads();
  {
    int s = tid & 63, dr = tid >> 6;
    u16* dst = vT + (size_t)(b * HH + n) * HDIM * SS;
    for (int i = 0; i < 16; ++i) {
      int d2 = dr + i * 4;
      dst[(size_t)d2 * SS + s0 + s] = t[s][d2];
    }
  }
}

// ---------------- flash attention v9: K-split pieces + LDS DMA staging ----------------
// 1024 blocks x 256 threads (4 waves), 4 blocks/CU (LDS 37,888B x4 = 151.5KB).
// v8's makespan = heaviest block (st=15: 48 latency-bound chunks ~ 58us; all 512
// blocks co-resident so LPT order was a no-op). v9 splits every supertile's
// chunk range into 2 EQUAL pieces of 9+st chunks (jcEnd=18+2st is even), max 24
// vs 48. Pieces write unnormalized f32 O + denominator l (no-max softmax: merge
// is a plain add) to per-piece buffers; txl_attn_merge normalizes -> ctx bf16.
__global__ __launch_bounds__(256) void txl_attn9(
    const u16* __restrict__ qu, const u16* __restrict__ qv, const u16* __restrict__ kbuf,
    const u16* __restrict__ vT, const u16* __restrict__ rbuf,
    float* __restrict__ O0, float* __restrict__ O1,
    float* __restrict__ L0, float* __restrict__ L1) {
  __shared__ __align__(16) u16 Kb[2][2048];   // chunk K: 32 rows x 64
  __shared__ __align__(16) u16 Vb[2][2048];   // chunk V^T: 64 d-rows x 32
  __shared__ __align__(16) u16 Rr[8][1024];   // r ring: 8 slabs of 16 rows x 64
  __shared__ __align__(16) u16 ps4[4][640];   // per-wave P staging [16][40]

  const int bx = blockIdx.x;
  const int n = bx & 7;                 // XCD class = head
  const int rest = bx >> 3;
  const int b = rest & 3;
  const int rest2 = rest >> 2;          // 0..31
  const int st = rest2 & 15;
  const int piece = rest2 >> 4;
  const int i0b = st * 64;
  const int g0 = 63 - (i0b >> 4);
  const int jcEnd = 18 + 2 * st;        // chunks covering j <= i0b+63+512
  const int half = 9 + st;
  const int jcBeg = piece ? half : 0;
  const int jcLim = piece ? jcEnd : half;
  const int gB = g0 + 2 * jcBeg;

  const int tid = threadIdx.x, w = tid >> 6, lane = tid & 63;
  const int L15 = lane & 15, quad = lane >> 4;
  const int i0w = i0b + 16 * w;
  const int bh = b * HH + n;

  const u16* kB = kbuf + (size_t)bh * SS * HDIM;
  const u16* rB = rbuf + (size_t)n * SS * HDIM;
  const u16* vB = vT + (size_t)bh * HDIM * SS;

  // Q fragments (regular loads; drained by prologue barrier)
  const u16* quB = qu + ((size_t)bh * TT + i0w) * HDIM;
  const u16* qvB = qv + ((size_t)bh * TT + i0w) * HDIM;
  bf16x8 aqu[2], aqv[2];
  for (int c = 0; c < 2; ++c) {
    aqu[c] = *reinterpret_cast<const bf16x8*>(&quB[(size_t)L15 * HDIM + c * 32 + quad * 8]);
    aqv[c] = *reinterpret_cast<const bf16x8*>(&qvB[(size_t)L15 * HDIM + c * 32 + quad * 8]);
  }

  u16* ps = &ps4[w][0];

  auto stageK = [&](int jc) {
    const u16* src = kB + (size_t)(jc * 32 + (lane & 31)) * HDIM + (2 * w + (lane >> 5)) * 8;
    dma16(src, &Kb[jc & 1][512 * w]);
  };
  auto stageV = [&](int jc) {
    const u16* src = vB + (size_t)lane * SS + jc * 32 + 8 * w;
    dma16(src, &Vb[jc & 1][512 * w]);
  };
  auto stageRslab = [&](int slab) {
    int rrow = slab * 16 + (lane & 15);
    rrow = (rrow > SS - 1) ? (SS - 1) : rrow;   // clamped rows only feed masked lanes
    const u16* s0 = rB + (size_t)rrow * HDIM + (lane >> 4) * 8;
    dma16(s0, &Rr[slab & 7][0]);
    dma16(s0 + 32, &Rr[slab & 7][512]);
  };
  auto rfrag = [&](int slab, int h) {
    return *reinterpret_cast<const bf16x8*>(&Rr[slab & 7][((quad + 4 * h) * 16 + L15) * 8]);
  };

  // ---- prologue: stage chunk jcBeg + r window [gB-3, gB+2] ----
  stageK(jcBeg); stageV(jcBeg);
  stageRslab(gB - 3 + w);
  if (w < 2) stageRslab(gB + 1 + w);
  __syncthreads();

  f32x4 pT0 = {};
  pT0 = __builtin_amdgcn_mfma_f32_16x16x32_bf16(aqv[0], rfrag(gB - w, 0), pT0, 0, 0, 0);
  pT0 = __builtin_amdgcn_mfma_f32_16x16x32_bf16(aqv[1], rfrag(gB - w, 1), pT0, 0, 0, 0);

  float l_lane[4] = {0.f, 0.f, 0.f, 0.f};
  f32x4 Oacc[4] = {};

  for (int jc = jcBeg; jc < jcLim; ++jc) {
    if (jc + 1 < jcLim) {               // issue next-chunk DMA (disjoint LDS regions)
      stageK(jc + 1); stageV(jc + 1);
      if (w < 2) stageRslab(g0 + 3 + 2 * jc + w);
    }
    const int hslot = jc & 1, j0 = jc * 32;
    bf16x8 k00 = *reinterpret_cast<const bf16x8*>(&Kb[hslot][((quad) * 32 + L15) * 8]);
    bf16x8 k01 = *reinterpret_cast<const bf16x8*>(&Kb[hslot][((quad + 4) * 32 + L15) * 8]);
    bf16x8 k10 = *reinterpret_cast<const bf16x8*>(&Kb[hslot][((quad) * 32 + 16 + L15) * 8]);
    bf16x8 k11 = *reinterpret_cast<const bf16x8*>(&Kb[hslot][((quad + 4) * 32 + 16 + L15) * 8]);
    f32x4 s0v = {}, s1v = {};
    s0v = __builtin_amdgcn_mfma_f32_16x16x32_bf16(aqu[0], k00, s0v, 0, 0, 0);
    s0v = __builtin_amdgcn_mfma_f32_16x16x32_bf16(aqu[1], k01, s0v, 0, 0, 0);
    s1v = __builtin_amdgcn_mfma_f32_16x16x32_bf16(aqu[0], k10, s1v, 0, 0, 0);
    s1v = __builtin_amdgcn_mfma_f32_16x16x32_bf16(aqu[1], k11, s1v, 0, 0, 0);
    const int sl1 = g0 - w + 2 * jc + 1;
    f32x4 pT1 = {}, pT2 = {};
    pT1 = __builtin_amdgcn_mfma_f32_16x16x32_bf16(aqv[0], rfrag(sl1, 0), pT1, 0, 0, 0);
    pT1 = __builtin_amdgcn_mfma_f32_16x16x32_bf16(aqv[1], rfrag(sl1, 1), pT1, 0, 0, 0);
    pT2 = __builtin_amdgcn_mfma_f32_16x16x32_bf16(aqv[0], rfrag(sl1 + 1, 0), pT2, 0, 0, 0);
    pT2 = __builtin_amdgcn_mfma_f32_16x16x32_bf16(aqv[1], rfrag(sl1 + 1, 1), pT2, 0, 0, 0);
    for (int r = 0; r < 4; ++r) {
      int ii = quad * 4 + r;
      int i = i0w + ii;
      int c = 15 + L15 - ii;                       // [0,30]
      int srcLane = (quad << 4) | (c & 15);
      float a0 = __shfl(pT0[r], srcLane);
      float a1 = __shfl(pT1[r], srcLane);
      float b1v = __shfl(pT2[r], srcLane);
      float sv0 = s0v[r] + ((c < 16) ? a0 : a1);
      float sv1 = s1v[r] + ((c < 16) ? a1 : b1v);
      sv0 = (j0 + L15 <= i + MM) ? sv0 : -3e38f;
      sv1 = (j0 + 16 + L15 <= i + MM) ? sv1 : -3e38f;
      float e0 = __expf(sv0 * SCALE);              // masked -> 0
      float e1 = __expf(sv1 * SCALE);
      l_lane[r] += e0 + e1;
      int row = ii * 40;
      ps[row + L15] = f2b(e0);
      ps[row + 16 + L15] = f2b(e1);
    }
    bf16x8 ap = *reinterpret_cast<const bf16x8*>(&ps[L15 * 40 + quad * 8]);
    bf16x8 v0 = *reinterpret_cast<const bf16x8*>(&Vb[hslot][(quad * 64 + L15) * 8]);
    bf16x8 v1 = *reinterpret_cast<const bf16x8*>(&Vb[hslot][(quad * 64 + 16 + L15) * 8]);
    bf16x8 v2 = *reinterpret_cast<const bf16x8*>(&Vb[hslot][(quad * 64 + 32 + L15) * 8]);
    bf16x8 v3 = *reinterpret_cast<const bf16x8*>(&Vb[hslot][(quad * 64 + 48 + L15) * 8]);
    Oacc[0] = __builtin_amdgcn_mfma_f32_16x16x32_bf16(ap, v0, Oacc[0], 0, 0, 0);
    Oacc[1] = __builtin_amdgcn_mfma_f32_16x16x32_bf16(ap, v1, Oacc[1], 0, 0, 0);
    Oacc[2] = __builtin_amdgcn_mfma_f32_16x16x32_bf16(ap, v2, Oacc[2], 0, 0, 0);
    Oacc[3] = __builtin_amdgcn_mfma_f32_16x16x32_bf16(ap, v3, Oacc[3], 0, 0, 0);
    pT0 = pT2;
    __syncthreads();   // drains this iter's DMA + publishes staging
  }

  // ---- write unnormalized piece results ----
  float lsum[4];
  for (int r = 0; r < 4; ++r) {
    float s = l_lane[r];
    for (int o = 1; o < 16; o <<= 1) s += __shfl_xor(s, o);
    lsum[r] = s;
  }
  float* Op = piece ? O1 : O0;
  float* Lp = piece ? L1 : L0;
  for (int tn = 0; tn < 4; ++tn)
    for (int r = 0; r < 4; ++r) {
      int ii = quad * 4 + r;
      Op[((size_t)(i0w + ii) * BB + b) * DD + n * HDIM + tn * 16 + L15] = Oacc[tn][r];
    }
  if (L15 == 0)
    for (int r = 0; r < 4; ++r)
      Lp[(size_t)bh * TT + i0w + quad * 4 + r] = lsum[r];
}

// ---------------- merge attention pieces -> ctx bf16 ----------------
__global__ void txl_attn_merge(const float* __restrict__ O0, const float* __restrict__ O1,
                               const float* __restrict__ L0, const float* __restrict__ L1,
                               u16* __restrict__ ctx) {
  int o = blockIdx.x * 256 + threadIdx.x;   // 2,097,152
  if (o >= BB * TT * DD) return;
  int i = o >> 11, b = (o >> 9) & 3, e = o & 511, n = e >> 6;
  size_t li = (size_t)(b * HH + n) * TT + i;
  float l = L0[li] + L1[li];
  ctx[o] = f2b((O0[o] + O1[o]) / l);
}

// ---------------- LayerNorm (+ optional fused new_mems store) ----------------
__global__ __launch_bounds__(256) void txl_ln(
    const float* __restrict__ gout, const u16* __restrict__ bias,
    const float* __restrict__ resid, const u16* __restrict__ gam, const u16* __restrict__ bet,
    u16* __restrict__ ybf, float* __restrict__ yf,
    void* __restrict__ outv, int off, const int* __restrict__ flag) {
  const int row = blockIdx.x, tid = threadIdx.x;
  const int lane = tid & 63, wave = tid >> 6;
  __shared__ float red[4];
  size_t base = (size_t)row * DD;
  float x0 = gout[base + tid] + resid[base + tid];
  float x1 = gout[base + tid + 256] + resid[base + tid + 256];
  if (bias) { x0 += b2f(bias[tid]); x1 += b2f(bias[tid + 256]); }
  float s = x0 + x1;
  for (int o = 32; o; o >>= 1) s += __shfl_xor(s, o);
  if (lane == 0) red[wave] = s;
  __syncthreads();
  float mean = (red[0] + red[1] + red[2] + red[3]) * (1.f / DD);
  __syncthreads();
  float d0 = x0 - mean, d1 = x1 - mean;
  float q = d0 * d0 + d1 * d1;
  for (int o = 32; o; o >>= 1) q += __shfl_xor(q, o);
  if (lane == 0) red[wave] = q;
  __syncthreads();
  float var = (red[0] + red[1] + red[2] + red[3]) * (1.f / DD);
  float rstd = rsqrtf(var + LN_EPS);
  float y0 = d0 * rstd * b2f(gam[tid]) + b2f(bet[tid]);
  float y1 = d1 * rstd * b2f(gam[tid + 256]) + b2f(bet[tid + 256]);
  u16 u0 = f2b(y0), u1 = f2b(y1);
  ybf[base + tid] = u0;
  ybf[base + tid + 256] = u1;
  yf[base + tid] = y0;
  yf[base + tid + 256] = y1;
  if (outv && row >= 2048) {   // fused new_mems[l+1] store (rows t>=512)
    size_t mo = (size_t)off + (size_t)(row - 2048) * DD;
    if (*flag) {
      ((float*)outv)[mo + tid] = y0;
      ((float*)outv)[mo + tid + 256] = y1;
    } else {
      ((u16*)outv)[mo + tid] = u0;
      ((u16*)outv)[mo + tid + 256] = u1;
    }
  }
}

// ---------------- workspace layout (bytes) ----------------
constexpr size_t WS_CUR_F  = 0;           // 8,388,608
constexpr size_t WS_CBUF   = 8388608;     // 8,388,608 (f32 4096x512)
constexpr size_t WS_OB0    = 16777216;    // 8,388,608
constexpr size_t WS_OB1    = 25165824;    // 8,388,608
constexpr size_t WS_LB0    = 33554432;    // 131,072
constexpr size_t WS_LB1    = 33685504;    // 131,072
constexpr size_t WS_VBF    = 33816576;    // 6,291,456 (bf16 6144x512)
constexpr size_t WS_QU     = 40108032;    // 4,194,304
constexpr size_t WS_QV     = 44302336;    // 4,194,304
constexpr size_t WS_K      = 48496640;    // 6,291,456
constexpr size_t WS_VT     = 54788096;    // 6,291,456
constexpr size_t WS_R      = 61079552;    // 1,572,864
constexpr size_t WS_PE     = 62652416;    // 1,572,864
constexpr size_t WS_CTX    = 64225280;    // 4,194,304
constexpr size_t WS_HBF    = 68419584;    // 4,194,304
constexpr size_t WS_HF     = 72613888;    // 8,388,608
constexpr size_t WS_FF1    = 81002496;    // 16,777,216
constexpr size_t WS_CURBF  = 97779712;    // 4,194,304
constexpr size_t WS_CIN    = 101974016;   // 24,137,728
constexpr size_t WS_FLAG   = 126111744;   // int
constexpr size_t WS_TOTAL  = 126111808;

extern "C" void kernel_launch(void* const* d_in, const int* in_sizes, int n_in,
                              void* d_out, int out_size, void* d_ws, size_t ws_size,
                              hipStream_t stream) {
  (void)in_sizes; (void)n_in;

  if (ws_size < WS_TOTAL) {  // fail cleanly
    hipMemsetAsync(d_out, 0, (size_t)out_size * 2, stream);
    return;
  }
  char* ws = (char*)d_ws;
  float* cur_f  = (float*)(ws + WS_CUR_F);
  float* Cbuf   = (float*)(ws + WS_CBUF);
  float* Ob0    = (float*)(ws + WS_OB0);
  float* Ob1    = (float*)(ws + WS_OB1);
  float* Lb0    = (float*)(ws + WS_LB0);
  float* Lb1    = (float*)(ws + WS_LB1);
  u16*   vbf    = (u16*)(ws + WS_VBF);
  u16*   qu     = (u16*)(ws + WS_QU);
  u16*   qv     = (u16*)(ws + WS_QV);
  u16*   kb     = (u16*)(ws + WS_K);
  u16*   vT     = (u16*)(ws + WS_VT);
  u16*   rb     = (u16*)(ws + WS_R);
  u16*   pe     = (u16*)(ws + WS_PE);
  u16*   ctx    = (u16*)(ws + WS_CTX);
  u16*   hbf    = (u16*)(ws + WS_HBF);
  float* hf     = (float*)(ws + WS_HF);
  u16*   ff1    = (u16*)(ws + WS_FF1);
  u16*   cur_bf = (u16*)(ws + WS_CURBF);
  u16*   cin    = (u16*)(ws + WS_CIN);
  int*   flag   = (int*)(ws + WS_FLAG);

  // dtype probe + canonicalize all float inputs to bf16
  txl_probe<<<1, 64, 0, stream>>>((const u16*)d_in[0], flag);
  txl_convert<<<47144, 256, 0, stream>>>(
      d_in[0], d_in[3], d_in[4], d_in[5], d_in[6], d_in[7], d_in[8],
      d_in[9], d_in[10], d_in[11], d_in[12], d_in[13], d_in[14], d_in[15], d_in[16],
      cin, flag);

  const u16* ub = cin + OFF_UB;
  const u16* vb = cin + OFF_VB;

  txl_pe<<<SS, 256, 0, stream>>>(pe);
  txl_transpose_in<<<8192, 256, 0, stream>>>(cin + OFF_X, cur_bf, cur_f, d_out, flag);

  for (int l = 0; l < NLAYER; ++l) {
    // qkv GEMM with fused scatter epilogue; A = [mems_l rows<2048 | cur rows>=2048]
    txl_gemm3<2><<<dim3(48, 12), 256, 0, stream>>>(
        cin + OFF_MEMS + (size_t)l * 1048576, cur_bf, 2048,
        cin + OFF_QKVW + (size_t)l * 786432, nullptr,
        qu, qv, kb, vbf, ub, vb, 6144, 1536, 512);
    txl_v_transpose<<<768, 256, 0, stream>>>(vbf, vT);
    // r = pe @ pos_w^T with fused scatter
    txl_gemm3<3><<<dim3(12, 4), 256, 0, stream>>>(
        pe, nullptr, 1 << 30, cin + OFF_POSW + (size_t)l * 262144, nullptr,
        rb, nullptr, nullptr, nullptr, nullptr, nullptr, 1536, 512, 512);
    // attention: 2 balanced K-pieces per supertile + merge
    txl_attn9<<<1024, 256, 0, stream>>>(qu, qv, kb, vT, rb, Ob0, Ob1, Lb0, Lb1);
    txl_attn_merge<<<8192, 256, 0, stream>>>(Ob0, Ob1, Lb0, Lb1, ctx);
    // out projection
    txl_gemm3<0><<<dim3(32, 4), 256, 0, stream>>>(
        ctx, nullptr, 1 << 30, cin + OFF_OUTW + (size_t)l * 262144, Cbuf,
        nullptr, nullptr, nullptr, nullptr, nullptr, nullptr, 4096, 512, 512);
    txl_ln<<<4096, 256, 0, stream>>>(Cbuf, nullptr, cur_f,
                                     cin + OFF_LN1S + l * 512, cin + OFF_LN1B + l * 512,
                                     hbf, hf, nullptr, 0, flag);
    // FFN (bias+relu fused into GEMM epilogue)
    txl_gemm3<1><<<dim3(32, 16), 256, 0, stream>>>(
        hbf, nullptr, 1 << 30, cin + OFF_L1W + (size_t)l * 1048576, nullptr,
        ff1, nullptr, nullptr, nullptr, cin + OFF_L1B + l * 2048, nullptr, 4096, 2048, 512);
    txl_gemm3<0><<<dim3(32, 4), 256, 0, stream>>>(
        ff1, nullptr, 1 << 30, cin + OFF_L2W + (size_t)l * 1048576, Cbuf,
        nullptr, nullptr, nullptr, nullptr, nullptr, nullptr, 4096, 512, 2048);
    // ln2 with fused new_mems[l+1] store
    txl_ln<<<4096, 256, 0, stream>>>(Cbuf, cin + OFF_L2B + l * 512, hf,
                                     cin + OFF_LN2S + l * 512, cin + OFF_LN2B + l * 512,
                                     cur_bf, cur_f, d_out, 2097152 + (l + 1) * 1048576, flag);
  }
  // final = swapaxes(out, 0, 1)
  txl_store_final<<<8192, 256, 0, stream>>>(cur_bf, d_out, flag);
}

// Round 5
// 550.443 us; speedup vs baseline: 1.6061x; 1.6061x over previous
//
#include <hip/hip_runtime.h>

// ---------------- problem constants ----------------
constexpr int BB = 4, TT = 1024, DD = 512, HH = 8, HDIM = 64;
constexpr int FFD = 2048, NLAYER = 2, MM = 512, SS = 1536;
constexpr float LN_EPS = 1e-5f;
constexpr float SCALE = 0.04419417382415922f; // 1/sqrt(512)

typedef unsigned short u16;
typedef __attribute__((ext_vector_type(8))) short bf16x8;
typedef __attribute__((ext_vector_type(4))) float f32x4;

__device__ __forceinline__ float b2f(u16 u) {
  union { unsigned int i; float f; } c; c.i = ((unsigned int)u) << 16; return c.f;
}
__device__ __forceinline__ u16 f2b(float f) {
  unsigned int x = __builtin_bit_cast(unsigned int, f);
  x += 0x7fffu + ((x >> 16) & 1u);   // RNE (finite values only)
  return (u16)(x >> 16);
}

// async global->LDS DMA, 16B per lane. LDS dest = uniform base + lane*16.
__device__ __forceinline__ void dma16(const u16* g, u16* l) {
  __builtin_amdgcn_global_load_lds(
      (const __attribute__((address_space(1))) unsigned int*)g,
      (__attribute__((address_space(3))) unsigned int*)l, 16, 0, 0);
}

// ---------------- canonical input buffer offsets (elements) ----------------
constexpr int OFF_X    = 0;          // 2,097,152
constexpr int OFF_MEMS = 2097152;    // 3,145,728
constexpr int OFF_UB   = 5242880;    // 512
constexpr int OFF_VB   = 5243392;    // 512
constexpr int OFF_QKVW = 5243904;    // 1,572,864 (786,432 per layer)
constexpr int OFF_POSW = 6816768;    // 524,288 (262,144 per layer)
constexpr int OFF_OUTW = 7341056;    // 524,288
constexpr int OFF_L1W  = 7865344;    // 2,097,152 (1,048,576 per layer)
constexpr int OFF_L1B  = 9962496;    // 4,096 (2,048 per layer)
constexpr int OFF_L2W  = 9966592;    // 2,097,152
constexpr int OFF_L2B  = 12063744;   // 1,024 (512 per layer)
constexpr int OFF_LN1S = 12064768;
constexpr int OFF_LN1B = 12065792;
constexpr int OFF_LN2S = 12066816;
constexpr int OFF_LN2B = 12067840;
constexpr int TOT_IN   = 12068864;   // = 47,144 * 256

// ---------------- dtype probe ----------------
__global__ void txl_probe(const u16* __restrict__ xr, int* __restrict__ flag) {
  int lane = threadIdx.x;   // 64 threads
  int cnt = 0;
  for (int k = 0; k < 8; ++k) {
    u16 u = xr[lane * 8 + k];
    int e = (u >> 7) & 0xFF;
    if (e >= 0xC0) ++cnt;
  }
  for (int o = 32; o; o >>= 1) cnt += __shfl_xor(cnt, o);
  if (lane == 0) *flag = (cnt >= 32) ? 1 : 0;   // 1 => inputs are f32
}

// ---------------- convert all float inputs to canonical bf16 buffer ----------------
__global__ __launch_bounds__(256) void txl_convert(
    const void* x, const void* mems, const void* ub, const void* vb,
    const void* qkvw, const void* posw, const void* outw,
    const void* l1w, const void* l1b, const void* l2w, const void* l2b,
    const void* ln1s, const void* ln1b, const void* ln2s, const void* ln2b,
    u16* __restrict__ dst, const int* __restrict__ flag) {
  int idx = blockIdx.x * 256 + threadIdx.x;
  if (idx >= TOT_IN) return;
  const void* p; int local;
  if      (idx < OFF_MEMS) { p = x;    local = idx; }
  else if (idx < OFF_UB)   { p = mems; local = idx - OFF_MEMS; }
  else if (idx < OFF_VB)   { p = ub;   local = idx - OFF_UB; }
  else if (idx < OFF_QKVW) { p = vb;   local = idx - OFF_VB; }
  else if (idx < OFF_POSW) { p = qkvw; local = idx - OFF_QKVW; }
  else if (idx < OFF_OUTW) { p = posw; local = idx - OFF_POSW; }
  else if (idx < OFF_L1W)  { p = outw; local = idx - OFF_OUTW; }
  else if (idx < OFF_L1B)  { p = l1w;  local = idx - OFF_L1W; }
  else if (idx < OFF_L2W)  { p = l1b;  local = idx - OFF_L1B; }
  else if (idx < OFF_L2B)  { p = l2w;  local = idx - OFF_L2W; }
  else if (idx < OFF_LN1S) { p = l2b;  local = idx - OFF_L2B; }
  else if (idx < OFF_LN1B) { p = ln1s; local = idx - OFF_LN1S; }
  else if (idx < OFF_LN2S) { p = ln1b; local = idx - OFF_LN1B; }
  else if (idx < OFF_LN2B) { p = ln2s; local = idx - OFF_LN2S; }
  else                     { p = ln2b; local = idx - OFF_LN2B; }
  dst[idx] = (*flag) ? f2b(((const float*)p)[local]) : ((const u16*)p)[local];
}

// ---------------- GEMM v2 (R3-proven): C = A[M,K] * B[N,K]^T ----------------
// m97 structure (128x128 tile, BK=32, global_load_lds width-16, linear LDS).
// EPI=0: f32 C.  EPI=1: fused bias+relu -> bf16.
// NOTE (R4 lesson, rule #20): complex/branchy epilogues stop the compiler from
// unrolling the tm/tn loops -> acc[][] becomes runtime-indexed -> demoted to
// scratch -> 546MB of HBM scratch traffic, MfmaUtil 1.5%. Keep epilogues SIMPLE.
template <int EPI>
__global__ __launch_bounds__(256) void txl_gemm2(const u16* __restrict__ A,
                                                 const u16* __restrict__ B,
                                                 float* __restrict__ C,
                                                 u16* __restrict__ Obf,
                                                 const u16* __restrict__ bias,
                                                 int M, int N, int K) {
  __shared__ __align__(16) u16 As[128 * 32];
  __shared__ __align__(16) u16 Bs[128 * 32];
  const int tid = threadIdx.x;
  const int wave = tid >> 6, lane = tid & 63;
  const int wm = (wave & 1) * 64, wn = (wave >> 1) * 64;
  const int m0 = blockIdx.x * 128, n0 = blockIdx.y * 128;
  const int L15 = lane & 15, quad = lane >> 4;
  f32x4 acc[4][4] = {};
  for (int k0 = 0; k0 < K; k0 += 32) {
    for (int c = 0; c < 2; ++c) {
      int segBase = c * 256 + wave * 64;
      int seg = segBase + lane;
      int row = seg >> 2, q = seg & 3;
      dma16(&A[(size_t)(m0 + row) * K + k0 + q * 8], &As[segBase * 8]);
      dma16(&B[(size_t)(n0 + row) * K + k0 + q * 8], &Bs[segBase * 8]);
    }
    __syncthreads();   // drains DMA (vmcnt 0) + publishes
    bf16x8 af[4], bfr[4];
    for (int t = 0; t < 4; ++t)
      af[t] = *reinterpret_cast<const bf16x8*>(&As[(wm + t * 16 + L15) * 32 + quad * 8]);
    for (int t = 0; t < 4; ++t)
      bfr[t] = *reinterpret_cast<const bf16x8*>(&Bs[(wn + t * 16 + L15) * 32 + quad * 8]);
    for (int tm = 0; tm < 4; ++tm)
      for (int tn = 0; tn < 4; ++tn)
        acc[tm][tn] = __builtin_amdgcn_mfma_f32_16x16x32_bf16(af[tm], bfr[tn], acc[tm][tn], 0, 0, 0);
    __syncthreads();
  }
  for (int tm = 0; tm < 4; ++tm)
    for (int tn = 0; tn < 4; ++tn) {
      int col = n0 + wn + tn * 16 + L15;
      for (int r = 0; r < 4; ++r) {
        int row = m0 + wm + tm * 16 + quad * 4 + r;
        if (EPI == 0) {
          C[(size_t)row * N + col] = acc[tm][tn][r];
        } else {
          float v = acc[tm][tn][r] + b2f(bias[col]);
          Obf[(size_t)row * N + col] = f2b(fmaxf(v, 0.f));
        }
      }
    }
}

// ---------------- sinusoid positional encoding (positions are S-1..0) ----------------
__global__ void txl_pe(u16* __restrict__ pe) {
  int idx = blockIdx.x * 256 + threadIdx.x;    // SS*256
  if (idx >= SS * 256) return;
  int p = idx >> 8, m = idx & 255;
  float posf = (float)(SS - 1 - p);
  float div = expf((float)(2 * m) * (-9.210340371976184f / 512.0f));
  float a = posf * div;
  pe[(size_t)p * DD + 2 * m] = f2b(sinf(a));
  pe[(size_t)p * DD + 2 * m + 1] = f2b(cosf(a));
}

// ---------------- [B,T,D] -> [T,B,D] + fused new_mems[0] store ----------------
__global__ void txl_transpose_in(const u16* __restrict__ x, u16* __restrict__ cur_bf,
                                 float* __restrict__ cur_f, void* __restrict__ outv,
                                 const int* __restrict__ flag) {
  int idx = blockIdx.x * 256 + threadIdx.x;    // BB*TT*DD
  if (idx >= BB * TT * DD) return;
  int b = idx >> 19, t = (idx >> 9) & 1023, d = idx & 511;
  u16 v = x[idx];
  size_t o = ((size_t)t * BB + b) * DD + d;
  cur_bf[o] = v; cur_f[o] = b2f(v);
  if (t >= 512) {                               // new_mems[0] = xs rows 512..1023
    size_t mo = 2097152 + (o - 1048576);
    if (*flag) ((float*)outv)[mo] = b2f(v);
    else       ((u16*)outv)[mo] = v;
  }
}

__global__ void txl_store_final(const u16* __restrict__ cur_bf, void* __restrict__ outv,
                                const int* __restrict__ flag) {
  int idx = blockIdx.x * 256 + threadIdx.x;
  if (idx >= BB * TT * DD) return;
  int b = idx >> 19, t = (idx >> 9) & 1023, d = idx & 511;
  u16 v = cur_bf[((size_t)t * BB + b) * DD + d];
  if (*flag) ((float*)outv)[idx] = b2f(v);
  else       ((u16*)outv)[idx] = v;
}

// ---------------- qkv scatter (q,k only; v handled by txl_v_transpose) ----------------
__global__ __launch_bounds__(256) void txl_qkv_scatter(
    const float* __restrict__ C, const u16* __restrict__ ub, const u16* __restrict__ vb,
    u16* __restrict__ qu, u16* __restrict__ qv, u16* __restrict__ kb) {
  size_t idx = (size_t)blockIdx.x * 256 + threadIdx.x;
  if (idx >= (size_t)SS * BB * 1536) return;
  int e = (int)(idx % 1536);
  if (e >= 1024) return;
  int row = (int)(idx / 1536);
  int s = row >> 2, b = row & 3;
  float val = C[idx];
  if (e < 512) {
    if (s >= MM) {
      int i = s - MM, n = e >> 6, d = e & 63;
      size_t o = ((size_t)(b * HH + n) * TT + i) * HDIM + d;
      qu[o] = f2b(val + b2f(ub[e]));
      qv[o] = f2b(val + b2f(vb[e]));
    }
  } else {
    int e2 = e - 512, n = e2 >> 6, d = e2 & 63;
    kb[((size_t)(b * HH + n) * SS + s) * HDIM + d] = f2b(val);
  }
}

// ---------------- V transpose via LDS: coalesced vT stores ----------------
__global__ __launch_bounds__(256) void txl_v_transpose(const float* __restrict__ C,
                                                       u16* __restrict__ vT) {
  __shared__ u16 t[64][68];
  int bx = blockIdx.x;
  int sb = bx >> 5;           // 0..23
  int bn = bx & 31;
  int n = bn & 7, b = bn >> 3;
  int tid = threadIdx.x;
  int s0 = sb * 64;
  {
    int d = tid & 63, sr = tid >> 6;
    for (int i = 0; i < 16; ++i) {
      int s = s0 + sr + i * 4;
      t[sr + i * 4][d] = f2b(C[(size_t)(s * 4 + b) * 1536 + 1024 + n * 64 + d]);
    }
  }
  __syncthreads();
  {
    int s = tid & 63, dr = tid >> 6;
    u16* dst = vT + (size_t)(b * HH + n) * HDIM * SS;
    for (int i = 0; i < 16; ++i) {
      int d2 = dr + i * 4;
      dst[(size_t)d2 * SS + s0 + s] = t[s][d2];
    }
  }
}

// ---------------- r scatter ----------------
__global__ void txl_r_scatter(const float* __restrict__ C, u16* __restrict__ rb) {
  int idx = blockIdx.x * 256 + threadIdx.x;    // SS*DD
  if (idx >= SS * DD) return;
  int p = idx >> 9, e = idx & 511;
  int n = e >> 6, d = e & 63;
  rb[((size_t)n * SS + p) * HDIM + d] = f2b(C[idx]);
}

// ---------------- flash attention v9: K-split pieces + LDS DMA staging ----------------
// 1024 blocks x 256 threads (4 waves), 4 blocks/CU (LDS 37,888B x4 = 151.5KB).
// v8's makespan = heaviest block (st=15: 48 latency-bound chunks; all 512 blocks
// co-resident). v9 splits each supertile's chunk range into 2 EQUAL pieces of
// 9+st chunks (max 24 vs 48). Pieces write unnormalized f32 O + denominator l
// (no-max softmax: merge is a plain add); txl_attn_merge normalizes -> ctx bf16.
__global__ __launch_bounds__(256) void txl_attn9(
    const u16* __restrict__ qu, const u16* __restrict__ qv, const u16* __restrict__ kbuf,
    const u16* __restrict__ vT, const u16* __restrict__ rbuf,
    float* __restrict__ O0, float* __restrict__ O1,
    float* __restrict__ L0, float* __restrict__ L1) {
  __shared__ __align__(16) u16 Kb[2][2048];   // chunk K: 32 rows x 64
  __shared__ __align__(16) u16 Vb[2][2048];   // chunk V^T: 64 d-rows x 32
  __shared__ __align__(16) u16 Rr[8][1024];   // r ring: 8 slabs of 16 rows x 64
  __shared__ __align__(16) u16 ps4[4][640];   // per-wave P staging [16][40]

  const int bx = blockIdx.x;
  const int n = bx & 7;                 // XCD class = head
  const int rest = bx >> 3;
  const int b = rest & 3;
  const int rest2 = rest >> 2;          // 0..31
  const int st = rest2 & 15;
  const int piece = rest2 >> 4;
  const int i0b = st * 64;
  const int g0 = 63 - (i0b >> 4);
  const int jcEnd = 18 + 2 * st;        // chunks covering j <= i0b+63+512
  const int half = 9 + st;
  const int jcBeg = piece ? half : 0;
  const int jcLim = piece ? jcEnd : half;
  const int gB = g0 + 2 * jcBeg;

  const int tid = threadIdx.x, w = tid >> 6, lane = tid & 63;
  const int L15 = lane & 15, quad = lane >> 4;
  const int i0w = i0b + 16 * w;
  const int bh = b * HH + n;

  const u16* kB = kbuf + (size_t)bh * SS * HDIM;
  const u16* rB = rbuf + (size_t)n * SS * HDIM;
  const u16* vB = vT + (size_t)bh * HDIM * SS;

  // Q fragments (regular loads; drained by prologue barrier)
  const u16* quB = qu + ((size_t)bh * TT + i0w) * HDIM;
  const u16* qvB = qv + ((size_t)bh * TT + i0w) * HDIM;
  bf16x8 aqu[2], aqv[2];
  for (int c = 0; c < 2; ++c) {
    aqu[c] = *reinterpret_cast<const bf16x8*>(&quB[(size_t)L15 * HDIM + c * 32 + quad * 8]);
    aqv[c] = *reinterpret_cast<const bf16x8*>(&qvB[(size_t)L15 * HDIM + c * 32 + quad * 8]);
  }

  u16* ps = &ps4[w][0];

  auto stageK = [&](int jc) {
    const u16* src = kB + (size_t)(jc * 32 + (lane & 31)) * HDIM + (2 * w + (lane >> 5)) * 8;
    dma16(src, &Kb[jc & 1][512 * w]);
  };
  auto stageV = [&](int jc) {
    const u16* src = vB + (size_t)lane * SS + jc * 32 + 8 * w;
    dma16(src, &Vb[jc & 1][512 * w]);
  };
  auto stageRslab = [&](int slab) {
    int rrow = slab * 16 + (lane & 15);
    rrow = (rrow > SS - 1) ? (SS - 1) : rrow;   // clamped rows only feed masked lanes
    const u16* s0 = rB + (size_t)rrow * HDIM + (lane >> 4) * 8;
    dma16(s0, &Rr[slab & 7][0]);
    dma16(s0 + 32, &Rr[slab & 7][512]);
  };
  auto rfrag = [&](int slab, int h) {
    return *reinterpret_cast<const bf16x8*>(&Rr[slab & 7][((quad + 4 * h) * 16 + L15) * 8]);
  };

  // ---- prologue: stage chunk jcBeg + r window [gB-3, gB+2] ----
  stageK(jcBeg); stageV(jcBeg);
  stageRslab(gB - 3 + w);
  if (w < 2) stageRslab(gB + 1 + w);
  __syncthreads();

  f32x4 pT0 = {};
  pT0 = __builtin_amdgcn_mfma_f32_16x16x32_bf16(aqv[0], rfrag(gB - w, 0), pT0, 0, 0, 0);
  pT0 = __builtin_amdgcn_mfma_f32_16x16x32_bf16(aqv[1], rfrag(gB - w, 1), pT0, 0, 0, 0);

  float l_lane[4] = {0.f, 0.f, 0.f, 0.f};
  f32x4 Oacc[4] = {};

  for (int jc = jcBeg; jc < jcLim; ++jc) {
    if (jc + 1 < jcLim) {               // issue next-chunk DMA (disjoint LDS regions)
      stageK(jc + 1); stageV(jc + 1);
      if (w < 2) stageRslab(g0 + 3 + 2 * jc + w);
    }
    const int hslot = jc & 1, j0 = jc * 32;
    bf16x8 k00 = *reinterpret_cast<const bf16x8*>(&Kb[hslot][((quad) * 32 + L15) * 8]);
    bf16x8 k01 = *reinterpret_cast<const bf16x8*>(&Kb[hslot][((quad + 4) * 32 + L15) * 8]);
    bf16x8 k10 = *reinterpret_cast<const bf16x8*>(&Kb[hslot][((quad) * 32 + 16 + L15) * 8]);
    bf16x8 k11 = *reinterpret_cast<const bf16x8*>(&Kb[hslot][((quad + 4) * 32 + 16 + L15) * 8]);
    f32x4 s0v = {}, s1v = {};
    s0v = __builtin_amdgcn_mfma_f32_16x16x32_bf16(aqu[0], k00, s0v, 0, 0, 0);
    s0v = __builtin_amdgcn_mfma_f32_16x16x32_bf16(aqu[1], k01, s0v, 0, 0, 0);
    s1v = __builtin_amdgcn_mfma_f32_16x16x32_bf16(aqu[0], k10, s1v, 0, 0, 0);
    s1v = __builtin_amdgcn_mfma_f32_16x16x32_bf16(aqu[1], k11, s1v, 0, 0, 0);
    const int sl1 = g0 - w + 2 * jc + 1;
    f32x4 pT1 = {}, pT2 = {};
    pT1 = __builtin_amdgcn_mfma_f32_16x16x32_bf16(aqv[0], rfrag(sl1, 0), pT1, 0, 0, 0);
    pT1 = __builtin_amdgcn_mfma_f32_16x16x32_bf16(aqv[1], rfrag(sl1, 1), pT1, 0, 0, 0);
    pT2 = __builtin_amdgcn_mfma_f32_16x16x32_bf16(aqv[0], rfrag(sl1 + 1, 0), pT2, 0, 0, 0);
    pT2 = __builtin_amdgcn_mfma_f32_16x16x32_bf16(aqv[1], rfrag(sl1 + 1, 1), pT2, 0, 0, 0);
    for (int r = 0; r < 4; ++r) {
      int ii = quad * 4 + r;
      int i = i0w + ii;
      int c = 15 + L15 - ii;                       // [0,30]
      int srcLane = (quad << 4) | (c & 15);
      float a0 = __shfl(pT0[r], srcLane);
      float a1 = __shfl(pT1[r], srcLane);
      float b1v = __shfl(pT2[r], srcLane);
      float sv0 = s0v[r] + ((c < 16) ? a0 : a1);
      float sv1 = s1v[r] + ((c < 16) ? a1 : b1v);
      sv0 = (j0 + L15 <= i + MM) ? sv0 : -3e38f;
      sv1 = (j0 + 16 + L15 <= i + MM) ? sv1 : -3e38f;
      float e0 = __expf(sv0 * SCALE);              // masked -> 0
      float e1 = __expf(sv1 * SCALE);
      l_lane[r] += e0 + e1;
      int row = ii * 40;
      ps[row + L15] = f2b(e0);
      ps[row + 16 + L15] = f2b(e1);
    }
    bf16x8 ap = *reinterpret_cast<const bf16x8*>(&ps[L15 * 40 + quad * 8]);
    bf16x8 v0 = *reinterpret_cast<const bf16x8*>(&Vb[hslot][(quad * 64 + L15) * 8]);
    bf16x8 v1 = *reinterpret_cast<const bf16x8*>(&Vb[hslot][(quad * 64 + 16 + L15) * 8]);
    bf16x8 v2 = *reinterpret_cast<const bf16x8*>(&Vb[hslot][(quad * 64 + 32 + L15) * 8]);
    bf16x8 v3 = *reinterpret_cast<const bf16x8*>(&Vb[hslot][(quad * 64 + 48 + L15) * 8]);
    Oacc[0] = __builtin_amdgcn_mfma_f32_16x16x32_bf16(ap, v0, Oacc[0], 0, 0, 0);
    Oacc[1] = __builtin_amdgcn_mfma_f32_16x16x32_bf16(ap, v1, Oacc[1], 0, 0, 0);
    Oacc[2] = __builtin_amdgcn_mfma_f32_16x16x32_bf16(ap, v2, Oacc[2], 0, 0, 0);
    Oacc[3] = __builtin_amdgcn_mfma_f32_16x16x32_bf16(ap, v3, Oacc[3], 0, 0, 0);
    pT0 = pT2;
    __syncthreads();   // drains this iter's DMA + publishes staging
  }

  // ---- write unnormalized piece results ----
  float lsum[4];
  for (int r = 0; r < 4; ++r) {
    float s = l_lane[r];
    for (int o = 1; o < 16; o <<= 1) s += __shfl_xor(s, o);
    lsum[r] = s;
  }
  float* Op = piece ? O1 : O0;
  float* Lp = piece ? L1 : L0;
  for (int tn = 0; tn < 4; ++tn)
    for (int r = 0; r < 4; ++r) {
      int ii = quad * 4 + r;
      Op[((size_t)(i0w + ii) * BB + b) * DD + n * HDIM + tn * 16 + L15] = Oacc[tn][r];
    }
  if (L15 == 0)
    for (int r = 0; r < 4; ++r)
      Lp[(size_t)bh * TT + i0w + quad * 4 + r] = lsum[r];
}

// ---------------- merge attention pieces -> ctx bf16 ----------------
__global__ void txl_attn_merge(const float* __restrict__ O0, const float* __restrict__ O1,
                               const float* __restrict__ L0, const float* __restrict__ L1,
                               u16* __restrict__ ctx) {
  int o = blockIdx.x * 256 + threadIdx.x;   // 2,097,152
  if (o >= BB * TT * DD) return;
  int i = o >> 11, b = (o >> 9) & 3, e = o & 511, n = e >> 6;
  size_t li = (size_t)(b * HH + n) * TT + i;
  float l = L0[li] + L1[li];
  ctx[o] = f2b((O0[o] + O1[o]) / l);
}

// ---------------- LayerNorm (+ optional fused new_mems store) ----------------
__global__ __launch_bounds__(256) void txl_ln(
    const float* __restrict__ gout, const u16* __restrict__ bias,
    const float* __restrict__ resid, const u16* __restrict__ gam, const u16* __restrict__ bet,
    u16* __restrict__ ybf, float* __restrict__ yf,
    void* __restrict__ outv, int off, const int* __restrict__ flag) {
  const int row = blockIdx.x, tid = threadIdx.x;
  const int lane = tid & 63, wave = tid >> 6;
  __shared__ float red[4];
  size_t base = (size_t)row * DD;
  float x0 = gout[base + tid] + resid[base + tid];
  float x1 = gout[base + tid + 256] + resid[base + tid + 256];
  if (bias) { x0 += b2f(bias[tid]); x1 += b2f(bias[tid + 256]); }
  float s = x0 + x1;
  for (int o = 32; o; o >>= 1) s += __shfl_xor(s, o);
  if (lane == 0) red[wave] = s;
  __syncthreads();
  float mean = (red[0] + red[1] + red[2] + red[3]) * (1.f / DD);
  __syncthreads();
  float d0 = x0 - mean, d1 = x1 - mean;
  float q = d0 * d0 + d1 * d1;
  for (int o = 32; o; o >>= 1) q += __shfl_xor(q, o);
  if (lane == 0) red[wave] = q;
  __syncthreads();
  float var = (red[0] + red[1] + red[2] + red[3]) * (1.f / DD);
  float rstd = rsqrtf(var + LN_EPS);
  float y0 = d0 * rstd * b2f(gam[tid]) + b2f(bet[tid]);
  float y1 = d1 * rstd * b2f(gam[tid + 256]) + b2f(bet[tid + 256]);
  u16 u0 = f2b(y0), u1 = f2b(y1);
  ybf[base + tid] = u0;
  ybf[base + tid + 256] = u1;
  yf[base + tid] = y0;
  yf[base + tid + 256] = y1;
  if (outv && row >= 2048) {   // fused new_mems[l+1] store (rows t>=512)
    size_t mo = (size_t)off + (size_t)(row - 2048) * DD;
    if (*flag) {
      ((float*)outv)[mo + tid] = y0;
      ((float*)outv)[mo + tid + 256] = y1;
    } else {
      ((u16*)outv)[mo + tid] = u0;
      ((u16*)outv)[mo + tid + 256] = u1;
    }
  }
}

// ---------------- workspace layout (bytes; R3-proven 138MB footprint) ----------------
constexpr size_t WS_CUR_F  = 0;
constexpr size_t WS_CAT    = 8388608;
constexpr size_t WS_CBUF   = 14680064;    // 37,748,736 (f32 6144x1536 max)
constexpr size_t WS_QU     = 52428800;
constexpr size_t WS_QV     = 56623104;
constexpr size_t WS_K      = 60817408;
constexpr size_t WS_VT     = 67108864;
constexpr size_t WS_R      = 73400320;
constexpr size_t WS_PE     = 74973184;
constexpr size_t WS_CTX    = 76546048;
constexpr size_t WS_HBF    = 80740352;
constexpr size_t WS_HF     = 84934656;
constexpr size_t WS_FF1    = 93323264;
constexpr size_t WS_CURBF  = 110100480;
constexpr size_t WS_CIN    = 114294784;   // bf16 [12,068,864] = 24,137,728 B
constexpr size_t WS_FLAG   = 138432512;   // int
constexpr size_t WS_TOTAL  = 138432576;
// attn piece buffers alias the (dead-at-that-point) Cbuf region:
constexpr size_t WS_OB0 = WS_CBUF;              // 8,388,608
constexpr size_t WS_OB1 = WS_CBUF + 8388608;    // 8,388,608
constexpr size_t WS_LB0 = WS_CBUF + 16777216;   // 131,072
constexpr size_t WS_LB1 = WS_CBUF + 16908288;   // 131,072

extern "C" void kernel_launch(void* const* d_in, const int* in_sizes, int n_in,
                              void* d_out, int out_size, void* d_ws, size_t ws_size,
                              hipStream_t stream) {
  (void)in_sizes; (void)n_in;

  if (ws_size < WS_TOTAL) {  // fail cleanly
    hipMemsetAsync(d_out, 0, (size_t)out_size * 2, stream);
    return;
  }
  char* ws = (char*)d_ws;
  float* cur_f  = (float*)(ws + WS_CUR_F);
  u16*   cat    = (u16*)(ws + WS_CAT);
  float* Cbuf   = (float*)(ws + WS_CBUF);
  float* Ob0    = (float*)(ws + WS_OB0);
  float* Ob1    = (float*)(ws + WS_OB1);
  float* Lb0    = (float*)(ws + WS_LB0);
  float* Lb1    = (float*)(ws + WS_LB1);
  u16*   qu     = (u16*)(ws + WS_QU);
  u16*   qv     = (u16*)(ws + WS_QV);
  u16*   kb     = (u16*)(ws + WS_K);
  u16*   vT     = (u16*)(ws + WS_VT);
  u16*   rb     = (u16*)(ws + WS_R);
  u16*   pe     = (u16*)(ws + WS_PE);
  u16*   ctx    = (u16*)(ws + WS_CTX);
  u16*   hbf    = (u16*)(ws + WS_HBF);
  float* hf     = (float*)(ws + WS_HF);
  u16*   ff1    = (u16*)(ws + WS_FF1);
  u16*   cur_bf = (u16*)(ws + WS_CURBF);
  u16*   cin    = (u16*)(ws + WS_CIN);
  int*   flag   = (int*)(ws + WS_FLAG);

  // dtype probe + canonicalize all float inputs to bf16
  txl_probe<<<1, 64, 0, stream>>>((const u16*)d_in[0], flag);
  txl_convert<<<47144, 256, 0, stream>>>(
      d_in[0], d_in[3], d_in[4], d_in[5], d_in[6], d_in[7], d_in[8],
      d_in[9], d_in[10], d_in[11], d_in[12], d_in[13], d_in[14], d_in[15], d_in[16],
      cin, flag);

  const u16* ub = cin + OFF_UB;
  const u16* vb = cin + OFF_VB;

  txl_pe<<<SS, 256, 0, stream>>>(pe);
  txl_transpose_in<<<8192, 256, 0, stream>>>(cin + OFF_X, cur_bf, cur_f, d_out, flag);

  for (int l = 0; l < NLAYER; ++l) {
    // cat = [mems[l]; cur]
    hipMemcpyAsync(cat, cin + OFF_MEMS + (size_t)l * 1048576, 2097152,
                   hipMemcpyDeviceToDevice, stream);
    hipMemcpyAsync(cat + 1048576, cur_bf, 4194304, hipMemcpyDeviceToDevice, stream);
    // qkv
    txl_gemm2<0><<<dim3(48, 12), 256, 0, stream>>>(
        cat, cin + OFF_QKVW + (size_t)l * 786432, Cbuf, nullptr, nullptr, 6144, 1536, 512);
    txl_qkv_scatter<<<36864, 256, 0, stream>>>(Cbuf, ub, vb, qu, qv, kb);
    txl_v_transpose<<<768, 256, 0, stream>>>(Cbuf, vT);
    // r = pe @ pos_w^T
    txl_gemm2<0><<<dim3(12, 4), 256, 0, stream>>>(
        pe, cin + OFF_POSW + (size_t)l * 262144, Cbuf, nullptr, nullptr, 1536, 512, 512);
    txl_r_scatter<<<3072, 256, 0, stream>>>(Cbuf, rb);
    // attention: 2 balanced K-pieces per supertile + merge (piece bufs alias Cbuf)
    txl_attn9<<<1024, 256, 0, stream>>>(qu, qv, kb, vT, rb, Ob0, Ob1, Lb0, Lb1);
    txl_attn_merge<<<8192, 256, 0, stream>>>(Ob0, Ob1, Lb0, Lb1, ctx);
    // out projection
    txl_gemm2<0><<<dim3(32, 4), 256, 0, stream>>>(
        ctx, cin + OFF_OUTW + (size_t)l * 262144, Cbuf, nullptr, nullptr, 4096, 512, 512);
    txl_ln<<<4096, 256, 0, stream>>>(Cbuf, nullptr, cur_f,
                                     cin + OFF_LN1S + l * 512, cin + OFF_LN1B + l * 512,
                                     hbf, hf, nullptr, 0, flag);
    // FFN (bias+relu fused into GEMM epilogue)
    txl_gemm2<1><<<dim3(32, 16), 256, 0, stream>>>(
        hbf, cin + OFF_L1W + (size_t)l * 1048576, nullptr, ff1,
        cin + OFF_L1B + l * 2048, 4096, 2048, 512);
    txl_gemm2<0><<<dim3(32, 4), 256, 0, stream>>>(
        ff1, cin + OFF_L2W + (size_t)l * 1048576, Cbuf, nullptr, nullptr, 4096, 512, 2048);
    // ln2 with fused new_mems[l+1] store
    txl_ln<<<4096, 256, 0, stream>>>(Cbuf, cin + OFF_L2B + l * 512, hf,
                                     cin + OFF_LN2S + l * 512, cin + OFF_LN2B + l * 512,
                                     cur_bf, cur_f, d_out, 2097152 + (l + 1) * 1048576, flag);
  }
  // final = swapaxes(out, 0, 1)
  txl_store_final<<<8192, 256, 0, stream>>>(cur_bf, d_out, flag);
}

// Round 6
// 496.017 us; speedup vs baseline: 1.7824x; 1.1097x over previous
//
#include <hip/hip_runtime.h>

// ---------------- problem constants ----------------
constexpr int BB = 4, TT = 1024, DD = 512, HH = 8, HDIM = 64;
constexpr int FFD = 2048, NLAYER = 2, MM = 512, SS = 1536;
constexpr float LN_EPS = 1e-5f;
constexpr float SCALE = 0.04419417382415922f; // 1/sqrt(512)

typedef unsigned short u16;
typedef __attribute__((ext_vector_type(8))) short bf16x8;
typedef __attribute__((ext_vector_type(4))) float f32x4;

__device__ __forceinline__ float b2f(u16 u) {
  union { unsigned int i; float f; } c; c.i = ((unsigned int)u) << 16; return c.f;
}
__device__ __forceinline__ u16 f2b(float f) {
  unsigned int x = __builtin_bit_cast(unsigned int, f);
  x += 0x7fffu + ((x >> 16) & 1u);   // RNE (finite values only)
  return (u16)(x >> 16);
}

// async global->LDS DMA, 16B per lane. LDS dest = uniform base + lane*16.
__device__ __forceinline__ void dma16(const u16* g, u16* l) {
  __builtin_amdgcn_global_load_lds(
      (const __attribute__((address_space(1))) unsigned int*)g,
      (__attribute__((address_space(3))) unsigned int*)l, 16, 0, 0);
}

// ---------------- canonical input buffer offsets (elements) ----------------
constexpr int OFF_X    = 0;          // 2,097,152
constexpr int OFF_MEMS = 2097152;    // 3,145,728
constexpr int OFF_UB   = 5242880;    // 512
constexpr int OFF_VB   = 5243392;    // 512
constexpr int OFF_QKVW = 5243904;    // 1,572,864 (786,432 per layer)
constexpr int OFF_POSW = 6816768;    // 524,288 (262,144 per layer)
constexpr int OFF_OUTW = 7341056;    // 524,288
constexpr int OFF_L1W  = 7865344;    // 2,097,152 (1,048,576 per layer)
constexpr int OFF_L1B  = 9962496;    // 4,096 (2,048 per layer)
constexpr int OFF_L2W  = 9966592;    // 2,097,152
constexpr int OFF_L2B  = 12063744;   // 1,024 (512 per layer)
constexpr int OFF_LN1S = 12064768;
constexpr int OFF_LN1B = 12065792;
constexpr int OFF_LN2S = 12066816;
constexpr int OFF_LN2B = 12067840;
constexpr int TOT_IN   = 12068864;   // = 47,144 * 256

// ---------------- dtype probe ----------------
__global__ void txl_probe(const u16* __restrict__ xr, int* __restrict__ flag) {
  int lane = threadIdx.x;   // 64 threads
  int cnt = 0;
  for (int k = 0; k < 8; ++k) {
    u16 u = xr[lane * 8 + k];
    int e = (u >> 7) & 0xFF;
    if (e >= 0xC0) ++cnt;
  }
  for (int o = 32; o; o >>= 1) cnt += __shfl_xor(cnt, o);
  if (lane == 0) *flag = (cnt >= 32) ? 1 : 0;   // 1 => inputs are f32
}

// ---------------- convert all float inputs to canonical bf16 buffer ----------------
__global__ __launch_bounds__(256) void txl_convert(
    const void* x, const void* mems, const void* ub, const void* vb,
    const void* qkvw, const void* posw, const void* outw,
    const void* l1w, const void* l1b, const void* l2w, const void* l2b,
    const void* ln1s, const void* ln1b, const void* ln2s, const void* ln2b,
    u16* __restrict__ dst, const int* __restrict__ flag) {
  int idx = blockIdx.x * 256 + threadIdx.x;
  if (idx >= TOT_IN) return;
  const void* p; int local;
  if      (idx < OFF_MEMS) { p = x;    local = idx; }
  else if (idx < OFF_UB)   { p = mems; local = idx - OFF_MEMS; }
  else if (idx < OFF_VB)   { p = ub;   local = idx - OFF_UB; }
  else if (idx < OFF_QKVW) { p = vb;   local = idx - OFF_VB; }
  else if (idx < OFF_POSW) { p = qkvw; local = idx - OFF_QKVW; }
  else if (idx < OFF_OUTW) { p = posw; local = idx - OFF_POSW; }
  else if (idx < OFF_L1W)  { p = outw; local = idx - OFF_OUTW; }
  else if (idx < OFF_L1B)  { p = l1w;  local = idx - OFF_L1W; }
  else if (idx < OFF_L2W)  { p = l1b;  local = idx - OFF_L1B; }
  else if (idx < OFF_L2B)  { p = l2w;  local = idx - OFF_L2W; }
  else if (idx < OFF_LN1S) { p = l2b;  local = idx - OFF_L2B; }
  else if (idx < OFF_LN1B) { p = ln1s; local = idx - OFF_LN1S; }
  else if (idx < OFF_LN2S) { p = ln1b; local = idx - OFF_LN1B; }
  else if (idx < OFF_LN2B) { p = ln2s; local = idx - OFF_LN2S; }
  else                     { p = ln2b; local = idx - OFF_LN2B; }
  dst[idx] = (*flag) ? f2b(((const float*)p)[local]) : ((const u16*)p)[local];
}

// ---------------- GEMM v4: split-K + double-buffered DMA staging ----------------
// C = A[M,K] * B[N,K]^T over K-range [z*KS, (z+1)*KS); 128x128 tile, BK=32.
// Double-buffered LDS (attn8-proven single-barrier loop): stage(k+1 -> buf^1)
// issued BEFORE compute(buf) so DMA latency hides under ds_read+MFMA; the
// iter-end __syncthreads() drains it. R5 counters: FFN2 (128 blocks, 64 serial
// drain-bound iters) = 47.9us @ occ 4.7%. Split-K gives 512/256 blocks; partial
// f32 C written at z*M*N (deterministic; summed in the following LayerNorm).
// EPI=0: f32 partial C.  EPI=1: fused bias+relu -> bf16 (S=1 only).
// R4 lesson (rule #20): keep epilogues simple so tm/tn fully unroll.
template <int EPI>
__global__ __launch_bounds__(256) void txl_gemm4(const u16* __restrict__ A,
                                                 const u16* __restrict__ B,
                                                 float* __restrict__ C,
                                                 u16* __restrict__ Obf,
                                                 const u16* __restrict__ bias,
                                                 int M, int N, int K, int KS) {
  __shared__ __align__(16) u16 As[2][128 * 32];
  __shared__ __align__(16) u16 Bs[2][128 * 32];
  const int tid = threadIdx.x;
  const int wave = tid >> 6, lane = tid & 63;
  const int wm = (wave & 1) * 64, wn = (wave >> 1) * 64;
  const int m0 = blockIdx.x * 128, n0 = blockIdx.y * 128;
  const int kbeg = blockIdx.z * KS, kend = kbeg + KS;
  const int L15 = lane & 15, quad = lane >> 4;

  auto stage = [&](int k0, int buf) {
    for (int c = 0; c < 2; ++c) {
      int segBase = c * 256 + wave * 64;
      int seg = segBase + lane;
      int row = seg >> 2, q = seg & 3;
      dma16(&A[(size_t)(m0 + row) * K + k0 + q * 8], &As[buf][segBase * 8]);
      dma16(&B[(size_t)(n0 + row) * K + k0 + q * 8], &Bs[buf][segBase * 8]);
    }
  };

  f32x4 acc[4][4] = {};
  stage(kbeg, 0);
  __syncthreads();                       // drain prologue DMA
  int buf = 0;
  for (int k0 = kbeg; k0 < kend; k0 += 32) {
    if (k0 + 32 < kend) stage(k0 + 32, buf ^ 1);   // prefetch next tile
    bf16x8 af[4], bfr[4];
    for (int t = 0; t < 4; ++t)
      af[t] = *reinterpret_cast<const bf16x8*>(&As[buf][(wm + t * 16 + L15) * 32 + quad * 8]);
    for (int t = 0; t < 4; ++t)
      bfr[t] = *reinterpret_cast<const bf16x8*>(&Bs[buf][(wn + t * 16 + L15) * 32 + quad * 8]);
    for (int tm = 0; tm < 4; ++tm)
      for (int tn = 0; tn < 4; ++tn)
        acc[tm][tn] = __builtin_amdgcn_mfma_f32_16x16x32_bf16(af[tm], bfr[tn], acc[tm][tn], 0, 0, 0);
    buf ^= 1;
    __syncthreads();                     // drains prefetch DMA + guards reuse
  }
  float* Cz = C + (size_t)blockIdx.z * ((size_t)M * N);
  for (int tm = 0; tm < 4; ++tm)
    for (int tn = 0; tn < 4; ++tn) {
      int col = n0 + wn + tn * 16 + L15;
      for (int r = 0; r < 4; ++r) {
        int row = m0 + wm + tm * 16 + quad * 4 + r;
        if (EPI == 0) {
          Cz[(size_t)row * N + col] = acc[tm][tn][r];
        } else {
          float v = acc[tm][tn][r] + b2f(bias[col]);
          Obf[(size_t)row * N + col] = f2b(fmaxf(v, 0.f));
        }
      }
    }
}

// ---------------- sinusoid positional encoding (positions are S-1..0) ----------------
__global__ void txl_pe(u16* __restrict__ pe) {
  int idx = blockIdx.x * 256 + threadIdx.x;    // SS*256
  if (idx >= SS * 256) return;
  int p = idx >> 8, m = idx & 255;
  float posf = (float)(SS - 1 - p);
  float div = expf((float)(2 * m) * (-9.210340371976184f / 512.0f));
  float a = posf * div;
  pe[(size_t)p * DD + 2 * m] = f2b(sinf(a));
  pe[(size_t)p * DD + 2 * m + 1] = f2b(cosf(a));
}

// ---------------- [B,T,D] -> [T,B,D] + fused new_mems[0] store ----------------
__global__ void txl_transpose_in(const u16* __restrict__ x, u16* __restrict__ cur_bf,
                                 float* __restrict__ cur_f, void* __restrict__ outv,
                                 const int* __restrict__ flag) {
  int idx = blockIdx.x * 256 + threadIdx.x;    // BB*TT*DD
  if (idx >= BB * TT * DD) return;
  int b = idx >> 19, t = (idx >> 9) & 1023, d = idx & 511;
  u16 v = x[idx];
  size_t o = ((size_t)t * BB + b) * DD + d;
  cur_bf[o] = v; cur_f[o] = b2f(v);
  if (t >= 512) {                               // new_mems[0] = xs rows 512..1023
    size_t mo = 2097152 + (o - 1048576);
    if (*flag) ((float*)outv)[mo] = b2f(v);
    else       ((u16*)outv)[mo] = v;
  }
}

__global__ void txl_store_final(const u16* __restrict__ cur_bf, void* __restrict__ outv,
                                const int* __restrict__ flag) {
  int idx = blockIdx.x * 256 + threadIdx.x;
  if (idx >= BB * TT * DD) return;
  int b = idx >> 19, t = (idx >> 9) & 1023, d = idx & 511;
  u16 v = cur_bf[((size_t)t * BB + b) * DD + d];
  if (*flag) ((float*)outv)[idx] = b2f(v);
  else       ((u16*)outv)[idx] = v;
}

// ---------------- qkv scatter (q,k only; v handled by txl_v_transpose) ----------------
__global__ __launch_bounds__(256) void txl_qkv_scatter(
    const float* __restrict__ C, const u16* __restrict__ ub, const u16* __restrict__ vb,
    u16* __restrict__ qu, u16* __restrict__ qv, u16* __restrict__ kb) {
  size_t idx = (size_t)blockIdx.x * 256 + threadIdx.x;
  if (idx >= (size_t)SS * BB * 1536) return;
  int e = (int)(idx % 1536);
  if (e >= 1024) return;
  int row = (int)(idx / 1536);
  int s = row >> 2, b = row & 3;
  float val = C[idx];
  if (e < 512) {
    if (s >= MM) {
      int i = s - MM, n = e >> 6, d = e & 63;
      size_t o = ((size_t)(b * HH + n) * TT + i) * HDIM + d;
      qu[o] = f2b(val + b2f(ub[e]));
      qv[o] = f2b(val + b2f(vb[e]));
    }
  } else {
    int e2 = e - 512, n = e2 >> 6, d = e2 & 63;
    kb[((size_t)(b * HH + n) * SS + s) * HDIM + d] = f2b(val);
  }
}

// ---------------- V transpose via LDS: coalesced vT stores ----------------
__global__ __launch_bounds__(256) void txl_v_transpose(const float* __restrict__ C,
                                                       u16* __restrict__ vT) {
  __shared__ u16 t[64][68];
  int bx = blockIdx.x;
  int sb = bx >> 5;           // 0..23
  int bn = bx & 31;
  int n = bn & 7, b = bn >> 3;
  int tid = threadIdx.x;
  int s0 = sb * 64;
  {
    int d = tid & 63, sr = tid >> 6;
    for (int i = 0; i < 16; ++i) {
      int s = s0 + sr + i * 4;
      t[sr + i * 4][d] = f2b(C[(size_t)(s * 4 + b) * 1536 + 1024 + n * 64 + d]);
    }
  }
  __syncthreads();
  {
    int s = tid & 63, dr = tid >> 6;
    u16* dst = vT + (size_t)(b * HH + n) * HDIM * SS;
    for (int i = 0; i < 16; ++i) {
      int d2 = dr + i * 4;
      dst[(size_t)d2 * SS + s0 + s] = t[s][d2];
    }
  }
}

// ---------------- r scatter ----------------
__global__ void txl_r_scatter(const float* __restrict__ C, u16* __restrict__ rb) {
  int idx = blockIdx.x * 256 + threadIdx.x;    // SS*DD
  if (idx >= SS * DD) return;
  int p = idx >> 9, e = idx & 511;
  int n = e >> 6, d = e & 63;
  rb[((size_t)n * SS + p) * HDIM + d] = f2b(C[idx]);
}

// ---------------- flash attention v9: K-split pieces + LDS DMA staging ----------------
// 1024 blocks x 256 threads (4 waves). Each supertile's chunk range split into
// 2 EQUAL pieces of 9+st chunks (max 24). Pieces write unnormalized f32 O +
// denominator l (no-max softmax: merge is a plain add); merge normalizes.
__global__ __launch_bounds__(256) void txl_attn9(
    const u16* __restrict__ qu, const u16* __restrict__ qv, const u16* __restrict__ kbuf,
    const u16* __restrict__ vT, const u16* __restrict__ rbuf,
    float* __restrict__ O0, float* __restrict__ O1,
    float* __restrict__ L0, float* __restrict__ L1) {
  __shared__ __align__(16) u16 Kb[2][2048];   // chunk K: 32 rows x 64
  __shared__ __align__(16) u16 Vb[2][2048];   // chunk V^T: 64 d-rows x 32
  __shared__ __align__(16) u16 Rr[8][1024];   // r ring: 8 slabs of 16 rows x 64
  __shared__ __align__(16) u16 ps4[4][640];   // per-wave P staging [16][40]

  const int bx = blockIdx.x;
  const int n = bx & 7;                 // XCD class = head
  const int rest = bx >> 3;
  const int b = rest & 3;
  const int rest2 = rest >> 2;          // 0..31
  const int st = rest2 & 15;
  const int piece = rest2 >> 4;
  const int i0b = st * 64;
  const int g0 = 63 - (i0b >> 4);
  const int jcEnd = 18 + 2 * st;        // chunks covering j <= i0b+63+512
  const int half = 9 + st;
  const int jcBeg = piece ? half : 0;
  const int jcLim = piece ? jcEnd : half;
  const int gB = g0 + 2 * jcBeg;

  const int tid = threadIdx.x, w = tid >> 6, lane = tid & 63;
  const int L15 = lane & 15, quad = lane >> 4;
  const int i0w = i0b + 16 * w;
  const int bh = b * HH + n;

  const u16* kB = kbuf + (size_t)bh * SS * HDIM;
  const u16* rB = rbuf + (size_t)n * SS * HDIM;
  const u16* vB = vT + (size_t)bh * HDIM * SS;

  // Q fragments (regular loads; drained by prologue barrier)
  const u16* quB = qu + ((size_t)bh * TT + i0w) * HDIM;
  const u16* qvB = qv + ((size_t)bh * TT + i0w) * HDIM;
  bf16x8 aqu[2], aqv[2];
  for (int c = 0; c < 2; ++c) {
    aqu[c] = *reinterpret_cast<const bf16x8*>(&quB[(size_t)L15 * HDIM + c * 32 + quad * 8]);
    aqv[c] = *reinterpret_cast<const bf16x8*>(&qvB[(size_t)L15 * HDIM + c * 32 + quad * 8]);
  }

  u16* ps = &ps4[w][0];

  auto stageK = [&](int jc) {
    const u16* src = kB + (size_t)(jc * 32 + (lane & 31)) * HDIM + (2 * w + (lane >> 5)) * 8;
    dma16(src, &Kb[jc & 1][512 * w]);
  };
  auto stageV = [&](int jc) {
    const u16* src = vB + (size_t)lane * SS + jc * 32 + 8 * w;
    dma16(src, &Vb[jc & 1][512 * w]);
  };
  auto stageRslab = [&](int slab) {
    int rrow = slab * 16 + (lane & 15);
    rrow = (rrow > SS - 1) ? (SS - 1) : rrow;   // clamped rows only feed masked lanes
    const u16* s0 = rB + (size_t)rrow * HDIM + (lane >> 4) * 8;
    dma16(s0, &Rr[slab & 7][0]);
    dma16(s0 + 32, &Rr[slab & 7][512]);
  };
  auto rfrag = [&](int slab, int h) {
    return *reinterpret_cast<const bf16x8*>(&Rr[slab & 7][((quad + 4 * h) * 16 + L15) * 8]);
  };

  // ---- prologue: stage chunk jcBeg + r window [gB-3, gB+2] ----
  stageK(jcBeg); stageV(jcBeg);
  stageRslab(gB - 3 + w);
  if (w < 2) stageRslab(gB + 1 + w);
  __syncthreads();

  f32x4 pT0 = {};
  pT0 = __builtin_amdgcn_mfma_f32_16x16x32_bf16(aqv[0], rfrag(gB - w, 0), pT0, 0, 0, 0);
  pT0 = __builtin_amdgcn_mfma_f32_16x16x32_bf16(aqv[1], rfrag(gB - w, 1), pT0, 0, 0, 0);

  float l_lane[4] = {0.f, 0.f, 0.f, 0.f};
  f32x4 Oacc[4] = {};

  for (int jc = jcBeg; jc < jcLim; ++jc) {
    if (jc + 1 < jcLim) {               // issue next-chunk DMA (disjoint LDS regions)
      stageK(jc + 1); stageV(jc + 1);
      if (w < 2) stageRslab(g0 + 3 + 2 * jc + w);
    }
    const int hslot = jc & 1, j0 = jc * 32;
    bf16x8 k00 = *reinterpret_cast<const bf16x8*>(&Kb[hslot][((quad) * 32 + L15) * 8]);
    bf16x8 k01 = *reinterpret_cast<const bf16x8*>(&Kb[hslot][((quad + 4) * 32 + L15) * 8]);
    bf16x8 k10 = *reinterpret_cast<const bf16x8*>(&Kb[hslot][((quad) * 32 + 16 + L15) * 8]);
    bf16x8 k11 = *reinterpret_cast<const bf16x8*>(&Kb[hslot][((quad + 4) * 32 + 16 + L15) * 8]);
    f32x4 s0v = {}, s1v = {};
    s0v = __builtin_amdgcn_mfma_f32_16x16x32_bf16(aqu[0], k00, s0v, 0, 0, 0);
    s0v = __builtin_amdgcn_mfma_f32_16x16x32_bf16(aqu[1], k01, s0v, 0, 0, 0);
    s1v = __builtin_amdgcn_mfma_f32_16x16x32_bf16(aqu[0], k10, s1v, 0, 0, 0);
    s1v = __builtin_amdgcn_mfma_f32_16x16x32_bf16(aqu[1], k11, s1v, 0, 0, 0);
    const int sl1 = g0 - w + 2 * jc + 1;
    f32x4 pT1 = {}, pT2 = {};
    pT1 = __builtin_amdgcn_mfma_f32_16x16x32_bf16(aqv[0], rfrag(sl1, 0), pT1, 0, 0, 0);
    pT1 = __builtin_amdgcn_mfma_f32_16x16x32_bf16(aqv[1], rfrag(sl1, 1), pT1, 0, 0, 0);
    pT2 = __builtin_amdgcn_mfma_f32_16x16x32_bf16(aqv[0], rfrag(sl1 + 1, 0), pT2, 0, 0, 0);
    pT2 = __builtin_amdgcn_mfma_f32_16x16x32_bf16(aqv[1], rfrag(sl1 + 1, 1), pT2, 0, 0, 0);
    for (int r = 0; r < 4; ++r) {
      int ii = quad * 4 + r;
      int i = i0w + ii;
      int c = 15 + L15 - ii;                       // [0,30]
      int srcLane = (quad << 4) | (c & 15);
      float a0 = __shfl(pT0[r], srcLane);
      float a1 = __shfl(pT1[r], srcLane);
      float b1v = __shfl(pT2[r], srcLane);
      float sv0 = s0v[r] + ((c < 16) ? a0 : a1);
      float sv1 = s1v[r] + ((c < 16) ? a1 : b1v);
      sv0 = (j0 + L15 <= i + MM) ? sv0 : -3e38f;
      sv1 = (j0 + 16 + L15 <= i + MM) ? sv1 : -3e38f;
      float e0 = __expf(sv0 * SCALE);              // masked -> 0
      float e1 = __expf(sv1 * SCALE);
      l_lane[r] += e0 + e1;
      int row = ii * 40;
      ps[row + L15] = f2b(e0);
      ps[row + 16 + L15] = f2b(e1);
    }
    bf16x8 ap = *reinterpret_cast<const bf16x8*>(&ps[L15 * 40 + quad * 8]);
    bf16x8 v0 = *reinterpret_cast<const bf16x8*>(&Vb[hslot][(quad * 64 + L15) * 8]);
    bf16x8 v1 = *reinterpret_cast<const bf16x8*>(&Vb[hslot][(quad * 64 + 16 + L15) * 8]);
    bf16x8 v2 = *reinterpret_cast<const bf16x8*>(&Vb[hslot][(quad * 64 + 32 + L15) * 8]);
    bf16x8 v3 = *reinterpret_cast<const bf16x8*>(&Vb[hslot][(quad * 64 + 48 + L15) * 8]);
    Oacc[0] = __builtin_amdgcn_mfma_f32_16x16x32_bf16(ap, v0, Oacc[0], 0, 0, 0);
    Oacc[1] = __builtin_amdgcn_mfma_f32_16x16x32_bf16(ap, v1, Oacc[1], 0, 0, 0);
    Oacc[2] = __builtin_amdgcn_mfma_f32_16x16x32_bf16(ap, v2, Oacc[2], 0, 0, 0);
    Oacc[3] = __builtin_amdgcn_mfma_f32_16x16x32_bf16(ap, v3, Oacc[3], 0, 0, 0);
    pT0 = pT2;
    __syncthreads();   // drains this iter's DMA + publishes staging
  }

  // ---- write unnormalized piece results ----
  float lsum[4];
  for (int r = 0; r < 4; ++r) {
    float s = l_lane[r];
    for (int o = 1; o < 16; o <<= 1) s += __shfl_xor(s, o);
    lsum[r] = s;
  }
  float* Op = piece ? O1 : O0;
  float* Lp = piece ? L1 : L0;
  for (int tn = 0; tn < 4; ++tn)
    for (int r = 0; r < 4; ++r) {
      int ii = quad * 4 + r;
      Op[((size_t)(i0w + ii) * BB + b) * DD + n * HDIM + tn * 16 + L15] = Oacc[tn][r];
    }
  if (L15 == 0)
    for (int r = 0; r < 4; ++r)
      Lp[(size_t)bh * TT + i0w + quad * 4 + r] = lsum[r];
}

// ---------------- merge attention pieces -> ctx bf16 ----------------
__global__ void txl_attn_merge(const float* __restrict__ O0, const float* __restrict__ O1,
                               const float* __restrict__ L0, const float* __restrict__ L1,
                               u16* __restrict__ ctx) {
  int o = blockIdx.x * 256 + threadIdx.x;   // 2,097,152
  if (o >= BB * TT * DD) return;
  int i = o >> 11, b = (o >> 9) & 3, e = o & 511, n = e >> 6;
  size_t li = (size_t)(b * HH + n) * TT + i;
  float l = L0[li] + L1[li];
  ctx[o] = f2b((O0[o] + O1[o]) / l);
}

// ---------------- LayerNorm over nparts f32 partials (+ optional mems store) ----------------
__global__ __launch_bounds__(256) void txl_ln(
    const float* __restrict__ gout, int nparts, const u16* __restrict__ bias,
    const float* __restrict__ resid, const u16* __restrict__ gam, const u16* __restrict__ bet,
    u16* __restrict__ ybf, float* __restrict__ yf,
    void* __restrict__ outv, int off, const int* __restrict__ flag) {
  const int row = blockIdx.x, tid = threadIdx.x;
  const int lane = tid & 63, wave = tid >> 6;
  __shared__ float red[4];
  size_t base = (size_t)row * DD;
  float x0 = resid[base + tid];
  float x1 = resid[base + tid + 256];
  for (int p = 0; p < nparts; ++p) {          // split-K partial sum (scalar accum)
    x0 += gout[(size_t)p * 2097152 + base + tid];
    x1 += gout[(size_t)p * 2097152 + base + tid + 256];
  }
  if (bias) { x0 += b2f(bias[tid]); x1 += b2f(bias[tid + 256]); }
  float s = x0 + x1;
  for (int o = 32; o; o >>= 1) s += __shfl_xor(s, o);
  if (lane == 0) red[wave] = s;
  __syncthreads();
  float mean = (red[0] + red[1] + red[2] + red[3]) * (1.f / DD);
  __syncthreads();
  float d0 = x0 - mean, d1 = x1 - mean;
  float q = d0 * d0 + d1 * d1;
  for (int o = 32; o; o >>= 1) q += __shfl_xor(q, o);
  if (lane == 0) red[wave] = q;
  __syncthreads();
  float var = (red[0] + red[1] + red[2] + red[3]) * (1.f / DD);
  float rstd = rsqrtf(var + LN_EPS);
  float y0 = d0 * rstd * b2f(gam[tid]) + b2f(bet[tid]);
  float y1 = d1 * rstd * b2f(gam[tid + 256]) + b2f(bet[tid + 256]);
  u16 u0 = f2b(y0), u1 = f2b(y1);
  ybf[base + tid] = u0;
  ybf[base + tid + 256] = u1;
  yf[base + tid] = y0;
  yf[base + tid + 256] = y1;
  if (outv && row >= 2048) {   // fused new_mems[l+1] store (rows t>=512)
    size_t mo = (size_t)off + (size_t)(row - 2048) * DD;
    if (*flag) {
      ((float*)outv)[mo + tid] = y0;
      ((float*)outv)[mo + tid + 256] = y1;
    } else {
      ((u16*)outv)[mo + tid] = u0;
      ((u16*)outv)[mo + tid + 256] = u1;
    }
  }
}

// ---------------- workspace layout (bytes; R3-proven 138MB footprint) ----------------
constexpr size_t WS_CUR_F  = 0;
constexpr size_t WS_CAT    = 8388608;
constexpr size_t WS_CBUF   = 14680064;    // 37,748,736 (f32; fits 4x 8.4MB split-K parts)
constexpr size_t WS_QU     = 52428800;
constexpr size_t WS_QV     = 56623104;
constexpr size_t WS_K      = 60817408;
constexpr size_t WS_VT     = 67108864;
constexpr size_t WS_R      = 73400320;
constexpr size_t WS_PE     = 74973184;
constexpr size_t WS_CTX    = 76546048;
constexpr size_t WS_HBF    = 80740352;
constexpr size_t WS_HF     = 84934656;
constexpr size_t WS_FF1    = 93323264;
constexpr size_t WS_CURBF  = 110100480;
constexpr size_t WS_CIN    = 114294784;   // bf16 [12,068,864] = 24,137,728 B
constexpr size_t WS_FLAG   = 138432512;   // int
constexpr size_t WS_TOTAL  = 138432576;
// attn piece buffers alias the (dead-at-that-point) Cbuf region:
constexpr size_t WS_OB0 = WS_CBUF;              // 8,388,608
constexpr size_t WS_OB1 = WS_CBUF + 8388608;    // 8,388,608
constexpr size_t WS_LB0 = WS_CBUF + 16777216;   // 131,072
constexpr size_t WS_LB1 = WS_CBUF + 16908288;   // 131,072

extern "C" void kernel_launch(void* const* d_in, const int* in_sizes, int n_in,
                              void* d_out, int out_size, void* d_ws, size_t ws_size,
                              hipStream_t stream) {
  (void)in_sizes; (void)n_in;

  if (ws_size < WS_TOTAL) {  // fail cleanly
    hipMemsetAsync(d_out, 0, (size_t)out_size * 2, stream);
    return;
  }
  char* ws = (char*)d_ws;
  float* cur_f  = (float*)(ws + WS_CUR_F);
  u16*   cat    = (u16*)(ws + WS_CAT);
  float* Cbuf   = (float*)(ws + WS_CBUF);
  float* Ob0    = (float*)(ws + WS_OB0);
  float* Ob1    = (float*)(ws + WS_OB1);
  float* Lb0    = (float*)(ws + WS_LB0);
  float* Lb1    = (float*)(ws + WS_LB1);
  u16*   qu     = (u16*)(ws + WS_QU);
  u16*   qv     = (u16*)(ws + WS_QV);
  u16*   kb     = (u16*)(ws + WS_K);
  u16*   vT     = (u16*)(ws + WS_VT);
  u16*   rb     = (u16*)(ws + WS_R);
  u16*   pe     = (u16*)(ws + WS_PE);
  u16*   ctx    = (u16*)(ws + WS_CTX);
  u16*   hbf    = (u16*)(ws + WS_HBF);
  float* hf     = (float*)(ws + WS_HF);
  u16*   ff1    = (u16*)(ws + WS_FF1);
  u16*   cur_bf = (u16*)(ws + WS_CURBF);
  u16*   cin    = (u16*)(ws + WS_CIN);
  int*   flag   = (int*)(ws + WS_FLAG);

  // dtype probe + canonicalize all float inputs to bf16
  txl_probe<<<1, 64, 0, stream>>>((const u16*)d_in[0], flag);
  txl_convert<<<47144, 256, 0, stream>>>(
      d_in[0], d_in[3], d_in[4], d_in[5], d_in[6], d_in[7], d_in[8],
      d_in[9], d_in[10], d_in[11], d_in[12], d_in[13], d_in[14], d_in[15], d_in[16],
      cin, flag);

  const u16* ub = cin + OFF_UB;
  const u16* vb = cin + OFF_VB;

  txl_pe<<<SS, 256, 0, stream>>>(pe);
  txl_transpose_in<<<8192, 256, 0, stream>>>(cin + OFF_X, cur_bf, cur_f, d_out, flag);

  for (int l = 0; l < NLAYER; ++l) {
    // cat = [mems[l]; cur]
    hipMemcpyAsync(cat, cin + OFF_MEMS + (size_t)l * 1048576, 2097152,
                   hipMemcpyDeviceToDevice, stream);
    hipMemcpyAsync(cat + 1048576, cur_bf, 4194304, hipMemcpyDeviceToDevice, stream);
    // qkv (S=1)
    txl_gemm4<0><<<dim3(48, 12, 1), 256, 0, stream>>>(
        cat, cin + OFF_QKVW + (size_t)l * 786432, Cbuf, nullptr, nullptr, 6144, 1536, 512, 512);
    txl_qkv_scatter<<<36864, 256, 0, stream>>>(Cbuf, ub, vb, qu, qv, kb);
    txl_v_transpose<<<768, 256, 0, stream>>>(Cbuf, vT);
    // r = pe @ pos_w^T (S=1)
    txl_gemm4<0><<<dim3(12, 4, 1), 256, 0, stream>>>(
        pe, cin + OFF_POSW + (size_t)l * 262144, Cbuf, nullptr, nullptr, 1536, 512, 512, 512);
    txl_r_scatter<<<3072, 256, 0, stream>>>(Cbuf, rb);
    // attention: 2 balanced K-pieces per supertile + merge (piece bufs alias Cbuf)
    txl_attn9<<<1024, 256, 0, stream>>>(qu, qv, kb, vT, rb, Ob0, Ob1, Lb0, Lb1);
    txl_attn_merge<<<8192, 256, 0, stream>>>(Ob0, Ob1, Lb0, Lb1, ctx);
    // out projection: split-K S=2 (2 f32 partials, summed in ln1)
    txl_gemm4<0><<<dim3(32, 4, 2), 256, 0, stream>>>(
        ctx, cin + OFF_OUTW + (size_t)l * 262144, Cbuf, nullptr, nullptr, 4096, 512, 512, 256);
    txl_ln<<<4096, 256, 0, stream>>>(Cbuf, 2, nullptr, cur_f,
                                     cin + OFF_LN1S + l * 512, cin + OFF_LN1B + l * 512,
                                     hbf, hf, nullptr, 0, flag);
    // FFN1 (S=1, fused bias+relu)
    txl_gemm4<1><<<dim3(32, 16, 1), 256, 0, stream>>>(
        hbf, cin + OFF_L1W + (size_t)l * 1048576, nullptr, ff1,
        cin + OFF_L1B + l * 2048, 4096, 2048, 512, 512);
    // FFN2: split-K S=4 (4 f32 partials, summed in ln2)
    txl_gemm4<0><<<dim3(32, 4, 4), 256, 0, stream>>>(
        ff1, cin + OFF_L2W + (size_t)l * 1048576, Cbuf, nullptr, nullptr, 4096, 512, 2048, 512);
    // ln2 with fused new_mems[l+1] store
    txl_ln<<<4096, 256, 0, stream>>>(Cbuf, 4, cin + OFF_L2B + l * 512, hf,
                                     cin + OFF_LN2S + l * 512, cin + OFF_LN2B + l * 512,
                                     cur_bf, cur_f, d_out, 2097152 + (l + 1) * 1048576, flag);
  }
  // final = swapaxes(out, 0, 1)
  txl_store_final<<<8192, 256, 0, stream>>>(cur_bf, d_out, flag);
}

// Round 8
// 476.031 us; speedup vs baseline: 1.8572x; 1.0420x over previous
//
#include <hip/hip_runtime.h>

// ---------------- problem constants ----------------
constexpr int BB = 4, TT = 1024, DD = 512, HH = 8, HDIM = 64;
constexpr int FFD = 2048, NLAYER = 2, MM = 512, SS = 1536;
constexpr float LN_EPS = 1e-5f;
constexpr float SCALE = 0.04419417382415922f; // 1/sqrt(512)

typedef unsigned short u16;
typedef __attribute__((ext_vector_type(8))) short bf16x8;
typedef __attribute__((ext_vector_type(4))) float f32x4;

__device__ __forceinline__ float b2f(u16 u) {
  union { unsigned int i; float f; } c; c.i = ((unsigned int)u) << 16; return c.f;
}
__device__ __forceinline__ u16 f2b(float f) {
  unsigned int x = __builtin_bit_cast(unsigned int, f);
  x += 0x7fffu + ((x >> 16) & 1u);   // RNE (finite values only)
  return (u16)(x >> 16);
}

// async global->LDS DMA, 16B per lane. LDS dest = uniform base + lane*16.
__device__ __forceinline__ void dma16(const u16* g, u16* l) {
  __builtin_amdgcn_global_load_lds(
      (const __attribute__((address_space(1))) unsigned int*)g,
      (__attribute__((address_space(3))) unsigned int*)l, 16, 0, 0);
}

// ---------------- canonical input buffer offsets (elements) ----------------
constexpr int OFF_X    = 0;          // 2,097,152
constexpr int OFF_MEMS = 2097152;    // 3,145,728
constexpr int OFF_UB   = 5242880;    // 512
constexpr int OFF_VB   = 5243392;    // 512
constexpr int OFF_QKVW = 5243904;    // 1,572,864 (786,432 per layer)
constexpr int OFF_POSW = 6816768;    // 524,288 (262,144 per layer)
constexpr int OFF_OUTW = 7341056;    // 524,288
constexpr int OFF_L1W  = 7865344;    // 2,097,152 (1,048,576 per layer)
constexpr int OFF_L1B  = 9962496;    // 4,096 (2,048 per layer)
constexpr int OFF_L2W  = 9966592;    // 2,097,152
constexpr int OFF_L2B  = 12063744;   // 1,024 (512 per layer)
constexpr int OFF_LN1S = 12064768;
constexpr int OFF_LN1B = 12065792;
constexpr int OFF_LN2S = 12066816;
constexpr int OFF_LN2B = 12067840;
constexpr int TOT_IN   = 12068864;   // = 47,144 * 256
constexpr int PE_CNT   = SS * 256;   // 393,216 pe work items (folded into convert)

// ---------------- dtype probe ----------------
__global__ void txl_probe(const u16* __restrict__ xr, int* __restrict__ flag) {
  int lane = threadIdx.x;   // 64 threads
  int cnt = 0;
  for (int k = 0; k < 8; ++k) {
    u16 u = xr[lane * 8 + k];
    int e = (u >> 7) & 0xFF;
    if (e >= 0xC0) ++cnt;
  }
  for (int o = 32; o; o >>= 1) cnt += __shfl_xor(cnt, o);
  if (lane == 0) *flag = (cnt >= 32) ? 1 : 0;   // 1 => inputs are f32
}

// ---------------- convert all float inputs to bf16 + fused pe generation ----------------
__global__ __launch_bounds__(256) void txl_convert(
    const void* x, const void* mems, const void* ub, const void* vb,
    const void* qkvw, const void* posw, const void* outw,
    const void* l1w, const void* l1b, const void* l2w, const void* l2b,
    const void* ln1s, const void* ln1b, const void* ln2s, const void* ln2b,
    u16* __restrict__ dst, u16* __restrict__ pe, const int* __restrict__ flag) {
  int idx = blockIdx.x * 256 + threadIdx.x;
  if (idx >= TOT_IN) {                       // fused sinusoid pe (positions S-1..0)
    int idx2 = idx - TOT_IN;
    if (idx2 >= PE_CNT) return;
    int p = idx2 >> 8, m = idx2 & 255;
    float posf = (float)(SS - 1 - p);
    float div = expf((float)(2 * m) * (-9.210340371976184f / 512.0f));
    float a = posf * div;
    pe[(size_t)p * DD + 2 * m] = f2b(sinf(a));
    pe[(size_t)p * DD + 2 * m + 1] = f2b(cosf(a));
    return;
  }
  const void* p; int local;
  if      (idx < OFF_MEMS) { p = x;    local = idx; }
  else if (idx < OFF_UB)   { p = mems; local = idx - OFF_MEMS; }
  else if (idx < OFF_VB)   { p = ub;   local = idx - OFF_UB; }
  else if (idx < OFF_QKVW) { p = vb;   local = idx - OFF_VB; }
  else if (idx < OFF_POSW) { p = qkvw; local = idx - OFF_QKVW; }
  else if (idx < OFF_OUTW) { p = posw; local = idx - OFF_POSW; }
  else if (idx < OFF_L1W)  { p = outw; local = idx - OFF_OUTW; }
  else if (idx < OFF_L1B)  { p = l1w;  local = idx - OFF_L1W; }
  else if (idx < OFF_L2W)  { p = l1b;  local = idx - OFF_L1B; }
  else if (idx < OFF_L2B)  { p = l2w;  local = idx - OFF_L2W; }
  else if (idx < OFF_LN1S) { p = l2b;  local = idx - OFF_L2B; }
  else if (idx < OFF_LN1B) { p = ln1s; local = idx - OFF_LN1S; }
  else if (idx < OFF_LN2S) { p = ln1b; local = idx - OFF_LN1B; }
  else if (idx < OFF_LN2B) { p = ln2s; local = idx - OFF_LN2S; }
  else                     { p = ln2b; local = idx - OFF_LN2B; }
  dst[idx] = (*flag) ? f2b(((const float*)p)[local]) : ((const u16*)p)[local];
}

// ---------------- GEMM v4: split-K + double-buffered DMA staging ----------------
// C = A[M,K] * B[N,K]^T over K-range [z*KS,(z+1)*KS); 128x128 tile, BK=32.
// stage(k+1 -> buf^1) issued BEFORE compute(buf); iter-end barrier drains.
// EPI=0: f32 partial C at z*M*N (summed in following LayerNorm).
// EPI=1: fused bias+relu -> bf16 (S=1 only).
// R4 lesson (rule #20): keep epilogues simple so tm/tn fully unroll.
template <int EPI>
__global__ __launch_bounds__(256) void txl_gemm4(const u16* __restrict__ A,
                                                 const u16* __restrict__ B,
                                                 float* __restrict__ C,
                                                 u16* __restrict__ Obf,
                                                 const u16* __restrict__ bias,
                                                 int M, int N, int K, int KS) {
  __shared__ __align__(16) u16 As[2][128 * 32];
  __shared__ __align__(16) u16 Bs[2][128 * 32];
  const int tid = threadIdx.x;
  const int wave = tid >> 6, lane = tid & 63;
  const int wm = (wave & 1) * 64, wn = (wave >> 1) * 64;
  const int m0 = blockIdx.x * 128, n0 = blockIdx.y * 128;
  const int kbeg = blockIdx.z * KS, kend = kbeg + KS;
  const int L15 = lane & 15, quad = lane >> 4;

  auto stage = [&](int k0, int buf) {
    for (int c = 0; c < 2; ++c) {
      int segBase = c * 256 + wave * 64;
      int seg = segBase + lane;
      int row = seg >> 2, q = seg & 3;
      dma16(&A[(size_t)(m0 + row) * K + k0 + q * 8], &As[buf][segBase * 8]);
      dma16(&B[(size_t)(n0 + row) * K + k0 + q * 8], &Bs[buf][segBase * 8]);
    }
  };

  f32x4 acc[4][4] = {};
  stage(kbeg, 0);
  __syncthreads();                       // drain prologue DMA
  int buf = 0;
  for (int k0 = kbeg; k0 < kend; k0 += 32) {
    if (k0 + 32 < kend) stage(k0 + 32, buf ^ 1);   // prefetch next tile
    bf16x8 af[4], bfr[4];
    for (int t = 0; t < 4; ++t)
      af[t] = *reinterpret_cast<const bf16x8*>(&As[buf][(wm + t * 16 + L15) * 32 + quad * 8]);
    for (int t = 0; t < 4; ++t)
      bfr[t] = *reinterpret_cast<const bf16x8*>(&Bs[buf][(wn + t * 16 + L15) * 32 + quad * 8]);
    for (int tm = 0; tm < 4; ++tm)
      for (int tn = 0; tn < 4; ++tn)
        acc[tm][tn] = __builtin_amdgcn_mfma_f32_16x16x32_bf16(af[tm], bfr[tn], acc[tm][tn], 0, 0, 0);
    buf ^= 1;
    __syncthreads();                     // drains prefetch DMA + guards reuse
  }
  float* Cz = C + (size_t)blockIdx.z * ((size_t)M * N);
#pragma unroll
  for (int tm = 0; tm < 4; ++tm)
#pragma unroll
    for (int tn = 0; tn < 4; ++tn) {
      int col = n0 + wn + tn * 16 + L15;
#pragma unroll
      for (int r = 0; r < 4; ++r) {
        int row = m0 + wm + tm * 16 + quad * 4 + r;
        if (EPI == 0) {
          Cz[(size_t)row * N + col] = acc[tm][tn][r];
        } else {
          float v = acc[tm][tn][r] + b2f(bias[col]);
          Obf[(size_t)row * N + col] = f2b(fmaxf(v, 0.f));
        }
      }
    }
}

// ---------------- r GEMM with fused scatter epilogue (own kernel: risk contained) ----
// C[p, e] = pe[p,:] . posw[e,:]; writes rb[((e>>6)*SS + p)*64 + (e&63)] directly.
__global__ __launch_bounds__(256) void txl_gemm_r(const u16* __restrict__ A,
                                                  const u16* __restrict__ B,
                                                  u16* __restrict__ rb,
                                                  int M, int N, int K) {
  __shared__ __align__(16) u16 As[2][128 * 32];
  __shared__ __align__(16) u16 Bs[2][128 * 32];
  const int tid = threadIdx.x;
  const int wave = tid >> 6, lane = tid & 63;
  const int wm = (wave & 1) * 64, wn = (wave >> 1) * 64;
  const int m0 = blockIdx.x * 128, n0 = blockIdx.y * 128;
  const int L15 = lane & 15, quad = lane >> 4;

  auto stage = [&](int k0, int buf) {
    for (int c = 0; c < 2; ++c) {
      int segBase = c * 256 + wave * 64;
      int seg = segBase + lane;
      int row = seg >> 2, q = seg & 3;
      dma16(&A[(size_t)(m0 + row) * K + k0 + q * 8], &As[buf][segBase * 8]);
      dma16(&B[(size_t)(n0 + row) * K + k0 + q * 8], &Bs[buf][segBase * 8]);
    }
  };

  f32x4 acc[4][4] = {};
  stage(0, 0);
  __syncthreads();
  int buf = 0;
  for (int k0 = 0; k0 < K; k0 += 32) {
    if (k0 + 32 < K) stage(k0 + 32, buf ^ 1);
    bf16x8 af[4], bfr[4];
    for (int t = 0; t < 4; ++t)
      af[t] = *reinterpret_cast<const bf16x8*>(&As[buf][(wm + t * 16 + L15) * 32 + quad * 8]);
    for (int t = 0; t < 4; ++t)
      bfr[t] = *reinterpret_cast<const bf16x8*>(&Bs[buf][(wn + t * 16 + L15) * 32 + quad * 8]);
    for (int tm = 0; tm < 4; ++tm)
      for (int tn = 0; tn < 4; ++tn)
        acc[tm][tn] = __builtin_amdgcn_mfma_f32_16x16x32_bf16(af[tm], bfr[tn], acc[tm][tn], 0, 0, 0);
    buf ^= 1;
    __syncthreads();
  }
#pragma unroll
  for (int tm = 0; tm < 4; ++tm)
#pragma unroll
    for (int tn = 0; tn < 4; ++tn) {
      int col = n0 + wn + tn * 16 + L15;
      int n = col >> 6, d = col & 63;
#pragma unroll
      for (int r = 0; r < 4; ++r) {
        int row = m0 + wm + tm * 16 + quad * 4 + r;
        rb[((size_t)n * SS + row) * HDIM + d] = f2b(acc[tm][tn][r]);
      }
    }
}

// ---------------- [B,T,D] -> [T,B,D] + fused new_mems[0] store ----------------
__global__ void txl_transpose_in(const u16* __restrict__ x, u16* __restrict__ cur_bf,
                                 float* __restrict__ cur_f, void* __restrict__ outv,
                                 const int* __restrict__ flag) {
  int idx = blockIdx.x * 256 + threadIdx.x;    // BB*TT*DD
  if (idx >= BB * TT * DD) return;
  int b = idx >> 19, t = (idx >> 9) & 1023, d = idx & 511;
  u16 v = x[idx];
  size_t o = ((size_t)t * BB + b) * DD + d;
  cur_bf[o] = v; cur_f[o] = b2f(v);
  if (t >= 512) {                               // new_mems[0] = xs rows 512..1023
    size_t mo = 2097152 + (o - 1048576);
    if (*flag) ((float*)outv)[mo] = b2f(v);
    else       ((u16*)outv)[mo] = v;
  }
}

// ---------------- qkv scatter (q,k only; v handled by txl_v_transpose) ----------------
__global__ __launch_bounds__(256) void txl_qkv_scatter(
    const float* __restrict__ C, const u16* __restrict__ ub, const u16* __restrict__ vb,
    u16* __restrict__ qu, u16* __restrict__ qv, u16* __restrict__ kb) {
  size_t idx = (size_t)blockIdx.x * 256 + threadIdx.x;
  if (idx >= (size_t)SS * BB * 1536) return;
  int e = (int)(idx % 1536);
  if (e >= 1024) return;
  int row = (int)(idx / 1536);
  int s = row >> 2, b = row & 3;
  float val = C[idx];
  if (e < 512) {
    if (s >= MM) {
      int i = s - MM, n = e >> 6, d = e & 63;
      size_t o = ((size_t)(b * HH + n) * TT + i) * HDIM + d;
      qu[o] = f2b(val + b2f(ub[e]));
      qv[o] = f2b(val + b2f(vb[e]));
    }
  } else {
    int e2 = e - 512, n = e2 >> 6, d = e2 & 63;
    kb[((size_t)(b * HH + n) * SS + s) * HDIM + d] = f2b(val);
  }
}

// ---------------- V transpose via LDS: coalesced vT stores ----------------
__global__ __launch_bounds__(256) void txl_v_transpose(const float* __restrict__ C,
                                                       u16* __restrict__ vT) {
  __shared__ u16 t[64][68];
  int bx = blockIdx.x;
  int sb = bx >> 5;           // 0..23
  int bn = bx & 31;
  int n = bn & 7, b = bn >> 3;
  int tid = threadIdx.x;
  int s0 = sb * 64;
  {
    int d = tid & 63, sr = tid >> 6;
    for (int i = 0; i < 16; ++i) {
      int s = s0 + sr + i * 4;
      t[sr + i * 4][d] = f2b(C[(size_t)(s * 4 + b) * 1536 + 1024 + n * 64 + d]);
    }
  }
  __syncthreads();
  {
    int s = tid & 63, dr = tid >> 6;
    u16* dst = vT + (size_t)(b * HH + n) * HDIM * SS;
    for (int i = 0; i < 16; ++i) {
      int d2 = dr + i * 4;
      dst[(size_t)d2 * SS + s0 + s] = t[s][d2];
    }
  }
}

// ---------------- flash attention v10: balanced K-split pieces + LDS DMA staging ----
// 1024 blocks x 256 threads (4 waves), 4 blocks/CU. Each supertile split into 2
// EQUAL pieces of 9+st chunks. v9 imbalance: CU c got pieces {s,s+8,s,s+8} ->
// 52+4s chunks (52..80, 1.21x). v10: piece 1 serves supertile 15-st_i, so every
// CU carries exactly (9+s)+(17+s)+(24-s)+(16-s) = 66 chunks. Coverage is a
// bijection: supertile x gets its piece1 from block st_i = 15-x.
__global__ __launch_bounds__(256) void txl_attn9(
    const u16* __restrict__ qu, const u16* __restrict__ qv, const u16* __restrict__ kbuf,
    const u16* __restrict__ vT, const u16* __restrict__ rbuf,
    float* __restrict__ O0, float* __restrict__ O1,
    float* __restrict__ L0, float* __restrict__ L1) {
  __shared__ __align__(16) u16 Kb[2][2048];   // chunk K: 32 rows x 64
  __shared__ __align__(16) u16 Vb[2][2048];   // chunk V^T: 64 d-rows x 32
  __shared__ __align__(16) u16 Rr[8][1024];   // r ring: 8 slabs of 16 rows x 64
  __shared__ __align__(16) u16 ps4[4][640];   // per-wave P staging [16][40]

  const int bx = blockIdx.x;
  const int n = bx & 7;                 // XCD class = head
  const int rest = bx >> 3;
  const int b = rest & 3;
  const int rest2 = rest >> 2;          // 0..31
  const int piece = rest2 >> 4;
  const int st = piece ? (15 - (rest2 & 15)) : (rest2 & 15);   // LPT pairing
  const int i0b = st * 64;
  const int g0 = 63 - (i0b >> 4);
  const int jcEnd = 18 + 2 * st;        // chunks covering j <= i0b+63+512
  const int half = 9 + st;
  const int jcBeg = piece ? half : 0;
  const int jcLim = piece ? jcEnd : half;
  const int gB = g0 + 2 * jcBeg;

  const int tid = threadIdx.x, w = tid >> 6, lane = tid & 63;
  const int L15 = lane & 15, quad = lane >> 4;
  const int i0w = i0b + 16 * w;
  const int bh = b * HH + n;

  const u16* kB = kbuf + (size_t)bh * SS * HDIM;
  const u16* rB = rbuf + (size_t)n * SS * HDIM;
  const u16* vB = vT + (size_t)bh * HDIM * SS;

  // Q fragments (regular loads; drained by prologue barrier)
  const u16* quB = qu + ((size_t)bh * TT + i0w) * HDIM;
  const u16* qvB = qv + ((size_t)bh * TT + i0w) * HDIM;
  bf16x8 aqu[2], aqv[2];
  for (int c = 0; c < 2; ++c) {
    aqu[c] = *reinterpret_cast<const bf16x8*>(&quB[(size_t)L15 * HDIM + c * 32 + quad * 8]);
    aqv[c] = *reinterpret_cast<const bf16x8*>(&qvB[(size_t)L15 * HDIM + c * 32 + quad * 8]);
  }

  u16* ps = &ps4[w][0];

  auto stageK = [&](int jc) {
    const u16* src = kB + (size_t)(jc * 32 + (lane & 31)) * HDIM + (2 * w + (lane >> 5)) * 8;
    dma16(src, &Kb[jc & 1][512 * w]);
  };
  auto stageV = [&](int jc) {
    const u16* src = vB + (size_t)lane * SS + jc * 32 + 8 * w;
    dma16(src, &Vb[jc & 1][512 * w]);
  };
  auto stageRslab = [&](int slab) {
    int rrow = slab * 16 + (lane & 15);
    rrow = (rrow > SS - 1) ? (SS - 1) : rrow;   // clamped rows only feed masked lanes
    const u16* s0 = rB + (size_t)rrow * HDIM + (lane >> 4) * 8;
    dma16(s0, &Rr[slab & 7][0]);
    dma16(s0 + 32, &Rr[slab & 7][512]);
  };
  auto rfrag = [&](int slab, int h) {
    return *reinterpret_cast<const bf16x8*>(&Rr[slab & 7][((quad + 4 * h) * 16 + L15) * 8]);
  };

  // ---- prologue: stage chunk jcBeg + r window [gB-3, gB+2] ----
  stageK(jcBeg); stageV(jcBeg);
  stageRslab(gB - 3 + w);
  if (w < 2) stageRslab(gB + 1 + w);
  __syncthreads();

  f32x4 pT0 = {};
  pT0 = __builtin_amdgcn_mfma_f32_16x16x32_bf16(aqv[0], rfrag(gB - w, 0), pT0, 0, 0, 0);
  pT0 = __builtin_amdgcn_mfma_f32_16x16x32_bf16(aqv[1], rfrag(gB - w, 1), pT0, 0, 0, 0);

  float l_lane[4] = {0.f, 0.f, 0.f, 0.f};
  f32x4 Oacc[4] = {};

  for (int jc = jcBeg; jc < jcLim; ++jc) {
    if (jc + 1 < jcLim) {               // issue next-chunk DMA (disjoint LDS regions)
      stageK(jc + 1); stageV(jc + 1);
      if (w < 2) stageRslab(g0 + 3 + 2 * jc + w);
    }
    const int hslot = jc & 1, j0 = jc * 32;
    bf16x8 k00 = *reinterpret_cast<const bf16x8*>(&Kb[hslot][((quad) * 32 + L15) * 8]);
    bf16x8 k01 = *reinterpret_cast<const bf16x8*>(&Kb[hslot][((quad + 4) * 32 + L15) * 8]);
    bf16x8 k10 = *reinterpret_cast<const bf16x8*>(&Kb[hslot][((quad) * 32 + 16 + L15) * 8]);
    bf16x8 k11 = *reinterpret_cast<const bf16x8*>(&Kb[hslot][((quad + 4) * 32 + 16 + L15) * 8]);
    f32x4 s0v = {}, s1v = {};
    s0v = __builtin_amdgcn_mfma_f32_16x16x32_bf16(aqu[0], k00, s0v, 0, 0, 0);
    s0v = __builtin_amdgcn_mfma_f32_16x16x32_bf16(aqu[1], k01, s0v, 0, 0, 0);
    s1v = __builtin_amdgcn_mfma_f32_16x16x32_bf16(aqu[0], k10, s1v, 0, 0, 0);
    s1v = __builtin_amdgcn_mfma_f32_16x16x32_bf16(aqu[1], k11, s1v, 0, 0, 0);
    const int sl1 = g0 - w + 2 * jc + 1;
    f32x4 pT1 = {}, pT2 = {};
    pT1 = __builtin_amdgcn_mfma_f32_16x16x32_bf16(aqv[0], rfrag(sl1, 0), pT1, 0, 0, 0);
    pT1 = __builtin_amdgcn_mfma_f32_16x16x32_bf16(aqv[1], rfrag(sl1, 1), pT1, 0, 0, 0);
    pT2 = __builtin_amdgcn_mfma_f32_16x16x32_bf16(aqv[0], rfrag(sl1 + 1, 0), pT2, 0, 0, 0);
    pT2 = __builtin_amdgcn_mfma_f32_16x16x32_bf16(aqv[1], rfrag(sl1 + 1, 1), pT2, 0, 0, 0);
    for (int r = 0; r < 4; ++r) {
      int ii = quad * 4 + r;
      int i = i0w + ii;
      int c = 15 + L15 - ii;                       // [0,30]
      int srcLane = (quad << 4) | (c & 15);
      float a0 = __shfl(pT0[r], srcLane);
      float a1 = __shfl(pT1[r], srcLane);
      float b1v = __shfl(pT2[r], srcLane);
      float sv0 = s0v[r] + ((c < 16) ? a0 : a1);
      float sv1 = s1v[r] + ((c < 16) ? a1 : b1v);
      sv0 = (j0 + L15 <= i + MM) ? sv0 : -3e38f;
      sv1 = (j0 + 16 + L15 <= i + MM) ? sv1 : -3e38f;
      float e0 = __expf(sv0 * SCALE);              // masked -> 0
      float e1 = __expf(sv1 * SCALE);
      l_lane[r] += e0 + e1;
      int row = ii * 40;
      ps[row + L15] = f2b(e0);
      ps[row + 16 + L15] = f2b(e1);
    }
    bf16x8 ap = *reinterpret_cast<const bf16x8*>(&ps[L15 * 40 + quad * 8]);
    bf16x8 v0 = *reinterpret_cast<const bf16x8*>(&Vb[hslot][(quad * 64 + L15) * 8]);
    bf16x8 v1 = *reinterpret_cast<const bf16x8*>(&Vb[hslot][(quad * 64 + 16 + L15) * 8]);
    bf16x8 v2 = *reinterpret_cast<const bf16x8*>(&Vb[hslot][(quad * 64 + 32 + L15) * 8]);
    bf16x8 v3 = *reinterpret_cast<const bf16x8*>(&Vb[hslot][(quad * 64 + 48 + L15) * 8]);
    Oacc[0] = __builtin_amdgcn_mfma_f32_16x16x32_bf16(ap, v0, Oacc[0], 0, 0, 0);
    Oacc[1] = __builtin_amdgcn_mfma_f32_16x16x32_bf16(ap, v1, Oacc[1], 0, 0, 0);
    Oacc[2] = __builtin_amdgcn_mfma_f32_16x16x32_bf16(ap, v2, Oacc[2], 0, 0, 0);
    Oacc[3] = __builtin_amdgcn_mfma_f32_16x16x32_bf16(ap, v3, Oacc[3], 0, 0, 0);
    pT0 = pT2;
    __syncthreads();   // drains this iter's DMA + publishes staging
  }

  // ---- write unnormalized piece results ----
  float lsum[4];
  for (int r = 0; r < 4; ++r) {
    float s = l_lane[r];
    for (int o = 1; o < 16; o <<= 1) s += __shfl_xor(s, o);
    lsum[r] = s;
  }
  float* Op = piece ? O1 : O0;
  float* Lp = piece ? L1 : L0;
  for (int tn = 0; tn < 4; ++tn)
    for (int r = 0; r < 4; ++r) {
      int ii = quad * 4 + r;
      Op[((size_t)(i0w + ii) * BB + b) * DD + n * HDIM + tn * 16 + L15] = Oacc[tn][r];
    }
  if (L15 == 0)
    for (int r = 0; r < 4; ++r)
      Lp[(size_t)bh * TT + i0w + quad * 4 + r] = lsum[r];
}

// ---------------- merge attention pieces -> ctx bf16 ----------------
__global__ void txl_attn_merge(const float* __restrict__ O0, const float* __restrict__ O1,
                               const float* __restrict__ L0, const float* __restrict__ L1,
                               u16* __restrict__ ctx) {
  int o = blockIdx.x * 256 + threadIdx.x;   // 2,097,152
  if (o >= BB * TT * DD) return;
  int i = o >> 11, b = (o >> 9) & 3, e = o & 511, n = e >> 6;
  size_t li = (size_t)(b * HH + n) * TT + i;
  float l = L0[li] + L1[li];
  ctx[o] = f2b((O0[o] + O1[o]) / l);
}

// ---------------- LayerNorm over nparts f32 partials (+ fused mems/final stores) ----
__global__ __launch_bounds__(256) void txl_ln(
    const float* __restrict__ gout, int nparts, const u16* __restrict__ bias,
    const float* __restrict__ resid, const u16* __restrict__ gam, const u16* __restrict__ bet,
    u16* __restrict__ ybf, float* __restrict__ yf,
    void* __restrict__ outv, int off, void* __restrict__ finalv,
    const int* __restrict__ flag) {
  const int row = blockIdx.x, tid = threadIdx.x;
  const int lane = tid & 63, wave = tid >> 6;
  __shared__ float red[4];
  size_t base = (size_t)row * DD;
  float x0 = resid[base + tid];
  float x1 = resid[base + tid + 256];
  for (int p = 0; p < nparts; ++p) {          // split-K partial sum (scalar accum)
    x0 += gout[(size_t)p * 2097152 + base + tid];
    x1 += gout[(size_t)p * 2097152 + base + tid + 256];
  }
  if (bias) { x0 += b2f(bias[tid]); x1 += b2f(bias[tid + 256]); }
  float s = x0 + x1;
  for (int o = 32; o; o >>= 1) s += __shfl_xor(s, o);
  if (lane == 0) red[wave] = s;
  __syncthreads();
  float mean = (red[0] + red[1] + red[2] + red[3]) * (1.f / DD);
  __syncthreads();
  float d0 = x0 - mean, d1 = x1 - mean;
  float q = d0 * d0 + d1 * d1;
  for (int o = 32; o; o >>= 1) q += __shfl_xor(q, o);
  if (lane == 0) red[wave] = q;
  __syncthreads();
  float var = (red[0] + red[1] + red[2] + red[3]) * (1.f / DD);
  float rstd = rsqrtf(var + LN_EPS);
  float y0 = d0 * rstd * b2f(gam[tid]) + b2f(bet[tid]);
  float y1 = d1 * rstd * b2f(gam[tid + 256]) + b2f(bet[tid + 256]);
  u16 u0 = f2b(y0), u1 = f2b(y1);
  ybf[base + tid] = u0;
  ybf[base + tid + 256] = u1;
  yf[base + tid] = y0;
  yf[base + tid + 256] = y1;
  if (outv && row >= 2048) {   // fused new_mems[l+1] store (rows t>=512)
    size_t mo = (size_t)off + (size_t)(row - 2048) * DD;
    if (*flag) {
      ((float*)outv)[mo + tid] = y0;
      ((float*)outv)[mo + tid + 256] = y1;
    } else {
      ((u16*)outv)[mo + tid] = u0;
      ((u16*)outv)[mo + tid + 256] = u1;
    }
  }
  if (finalv) {                // fused final = swapaxes(out,0,1) (last layer only)
    int t = row >> 2, b = row & 3;
    size_t fo = ((size_t)b * TT + t) * DD;
    if (*flag) {
      ((float*)finalv)[fo + tid] = y0;
      ((float*)finalv)[fo + tid + 256] = y1;
    } else {
      ((u16*)finalv)[fo + tid] = u0;
      ((u16*)finalv)[fo + tid + 256] = u1;
    }
  }
}

// ---------------- workspace layout (bytes; R3-proven 138MB footprint) ----------------
constexpr size_t WS_CUR_F  = 0;
constexpr size_t WS_CAT    = 8388608;
constexpr size_t WS_CBUF   = 14680064;    // 37,748,736 (f32; fits split-K parts)
constexpr size_t WS_QU     = 52428800;
constexpr size_t WS_QV     = 56623104;
constexpr size_t WS_K      = 60817408;
constexpr size_t WS_VT     = 67108864;
constexpr size_t WS_R      = 73400320;
constexpr size_t WS_PE     = 74973184;
constexpr size_t WS_CTX    = 76546048;
constexpr size_t WS_HBF    = 80740352;
constexpr size_t WS_HF     = 84934656;
constexpr size_t WS_FF1    = 93323264;
constexpr size_t WS_CURBF  = 110100480;
constexpr size_t WS_CIN    = 114294784;   // bf16 [12,068,864] = 24,137,728 B
constexpr size_t WS_FLAG   = 138432512;   // int
constexpr size_t WS_TOTAL  = 138432576;
// attn piece buffers alias the (dead-at-that-point) Cbuf region:
constexpr size_t WS_OB0 = WS_CBUF;              // 8,388,608
constexpr size_t WS_OB1 = WS_CBUF + 8388608;    // 8,388,608
constexpr size_t WS_LB0 = WS_CBUF + 16777216;   // 131,072
constexpr size_t WS_LB1 = WS_CBUF + 16908288;   // 131,072

extern "C" void kernel_launch(void* const* d_in, const int* in_sizes, int n_in,
                              void* d_out, int out_size, void* d_ws, size_t ws_size,
                              hipStream_t stream) {
  (void)in_sizes; (void)n_in;

  if (ws_size < WS_TOTAL) {  // fail cleanly
    hipMemsetAsync(d_out, 0, (size_t)out_size * 2, stream);
    return;
  }
  char* ws = (char*)d_ws;
  float* cur_f  = (float*)(ws + WS_CUR_F);
  u16*   cat    = (u16*)(ws + WS_CAT);
  float* Cbuf   = (float*)(ws + WS_CBUF);
  float* Ob0    = (float*)(ws + WS_OB0);
  float* Ob1    = (float*)(ws + WS_OB1);
  float* Lb0    = (float*)(ws + WS_LB0);
  float* Lb1    = (float*)(ws + WS_LB1);
  u16*   qu     = (u16*)(ws + WS_QU);
  u16*   qv     = (u16*)(ws + WS_QV);
  u16*   kb     = (u16*)(ws + WS_K);
  u16*   vT     = (u16*)(ws + WS_VT);
  u16*   rb     = (u16*)(ws + WS_R);
  u16*   pe     = (u16*)(ws + WS_PE);
  u16*   ctx    = (u16*)(ws + WS_CTX);
  u16*   hbf    = (u16*)(ws + WS_HBF);
  float* hf     = (float*)(ws + WS_HF);
  u16*   ff1    = (u16*)(ws + WS_FF1);
  u16*   cur_bf = (u16*)(ws + WS_CURBF);
  u16*   cin    = (u16*)(ws + WS_CIN);
  int*   flag   = (int*)(ws + WS_FLAG);

  // dtype probe + canonicalize all float inputs to bf16 (+ fused pe)
  txl_probe<<<1, 64, 0, stream>>>((const u16*)d_in[0], flag);
  txl_convert<<<48680, 256, 0, stream>>>(
      d_in[0], d_in[3], d_in[4], d_in[5], d_in[6], d_in[7], d_in[8],
      d_in[9], d_in[10], d_in[11], d_in[12], d_in[13], d_in[14], d_in[15], d_in[16],
      cin, pe, flag);

  const u16* ub = cin + OFF_UB;
  const u16* vb = cin + OFF_VB;

  txl_transpose_in<<<8192, 256, 0, stream>>>(cin + OFF_X, cur_bf, cur_f, d_out, flag);

  for (int l = 0; l < NLAYER; ++l) {
    // cat = [mems[l]; cur]
    hipMemcpyAsync(cat, cin + OFF_MEMS + (size_t)l * 1048576, 2097152,
                   hipMemcpyDeviceToDevice, stream);
    hipMemcpyAsync(cat + 1048576, cur_bf, 4194304, hipMemcpyDeviceToDevice, stream);
    // qkv (S=1)
    txl_gemm4<0><<<dim3(48, 12, 1), 256, 0, stream>>>(
        cat, cin + OFF_QKVW + (size_t)l * 786432, Cbuf, nullptr, nullptr, 6144, 1536, 512, 512);
    txl_qkv_scatter<<<36864, 256, 0, stream>>>(Cbuf, ub, vb, qu, qv, kb);
    txl_v_transpose<<<768, 256, 0, stream>>>(Cbuf, vT);
    // r = pe @ pos_w^T with fused scatter epilogue
    txl_gemm_r<<<dim3(12, 4), 256, 0, stream>>>(
        pe, cin + OFF_POSW + (size_t)l * 262144, rb, 1536, 512, 512);
    // attention: 2 balanced K-pieces per supertile + merge (piece bufs alias Cbuf)
    txl_attn9<<<1024, 256, 0, stream>>>(qu, qv, kb, vT, rb, Ob0, Ob1, Lb0, Lb1);
    txl_attn_merge<<<8192, 256, 0, stream>>>(Ob0, Ob1, Lb0, Lb1, ctx);
    // out projection: split-K S=2 (2 f32 partials, summed in ln1)
    txl_gemm4<0><<<dim3(32, 4, 2), 256, 0, stream>>>(
        ctx, cin + OFF_OUTW + (size_t)l * 262144, Cbuf, nullptr, nullptr, 4096, 512, 512, 256);
    txl_ln<<<4096, 256, 0, stream>>>(Cbuf, 2, nullptr, cur_f,
                                     cin + OFF_LN1S + l * 512, cin + OFF_LN1B + l * 512,
                                     hbf, hf, nullptr, 0, nullptr, flag);
    // FFN1 (S=1, fused bias+relu)
    txl_gemm4<1><<<dim3(32, 16, 1), 256, 0, stream>>>(
        hbf, cin + OFF_L1W + (size_t)l * 1048576, nullptr, ff1,
        cin + OFF_L1B + l * 2048, 4096, 2048, 512, 512);
    // FFN2: split-K S=4 (4 f32 partials, summed in ln2)
    txl_gemm4<0><<<dim3(32, 4, 4), 256, 0, stream>>>(
        ff1, cin + OFF_L2W + (size_t)l * 1048576, Cbuf, nullptr, nullptr, 4096, 512, 2048, 512);
    // ln2 with fused new_mems[l+1] store (+ fused final transpose-store on last layer)
    txl_ln<<<4096, 256, 0, stream>>>(Cbuf, 4, cin + OFF_L2B + l * 512, hf,
                                     cin + OFF_LN2S + l * 512, cin + OFF_LN2B + l * 512,
                                     cur_bf, cur_f, d_out, 2097152 + (l + 1) * 1048576,
                                     (l == NLAYER - 1) ? d_out : nullptr, flag);
  }
}

// Round 9
// 448.621 us; speedup vs baseline: 1.9707x; 1.0611x over previous
//
#include <hip/hip_runtime.h>

// ---------------- problem constants ----------------
constexpr int BB = 4, TT = 1024, DD = 512, HH = 8, HDIM = 64;
constexpr int FFD = 2048, NLAYER = 2, MM = 512, SS = 1536;
constexpr float LN_EPS = 1e-5f;
constexpr float SCALE = 0.04419417382415922f; // 1/sqrt(512)

typedef unsigned short u16;
typedef __attribute__((ext_vector_type(8))) short bf16x8;
typedef __attribute__((ext_vector_type(4))) float f32x4;

__device__ __forceinline__ float b2f(u16 u) {
  union { unsigned int i; float f; } c; c.i = ((unsigned int)u) << 16; return c.f;
}
__device__ __forceinline__ u16 f2b(float f) {
  unsigned int x = __builtin_bit_cast(unsigned int, f);
  x += 0x7fffu + ((x >> 16) & 1u);   // RNE (finite values only)
  return (u16)(x >> 16);
}

// async global->LDS DMA, 16B per lane. LDS dest = uniform base + lane*16.
__device__ __forceinline__ void dma16(const u16* g, u16* l) {
  __builtin_amdgcn_global_load_lds(
      (const __attribute__((address_space(1))) unsigned int*)g,
      (__attribute__((address_space(3))) unsigned int*)l, 16, 0, 0);
}

// ---------------- canonical input buffer offsets (elements) ----------------
constexpr int OFF_X    = 0;          // 2,097,152
constexpr int OFF_MEMS = 2097152;    // 3,145,728
constexpr int OFF_UB   = 5242880;    // 512
constexpr int OFF_VB   = 5243392;    // 512
constexpr int OFF_QKVW = 5243904;    // 1,572,864 (786,432 per layer)
constexpr int OFF_POSW = 6816768;    // 524,288 (262,144 per layer)
constexpr int OFF_OUTW = 7341056;    // 524,288
constexpr int OFF_L1W  = 7865344;    // 2,097,152 (1,048,576 per layer)
constexpr int OFF_L1B  = 9962496;    // 4,096 (2,048 per layer)
constexpr int OFF_L2W  = 9966592;    // 2,097,152
constexpr int OFF_L2B  = 12063744;   // 1,024 (512 per layer)
constexpr int OFF_LN1S = 12064768;
constexpr int OFF_LN1B = 12065792;
constexpr int OFF_LN2S = 12066816;
constexpr int OFF_LN2B = 12067840;
constexpr int TOT_IN   = 12068864;   // = 47,144 * 256
constexpr int PE_CNT   = SS * 256;   // 393,216 pe work items (folded into convert)

// ---------------- dtype probe ----------------
__global__ void txl_probe(const u16* __restrict__ xr, int* __restrict__ flag) {
  int lane = threadIdx.x;   // 64 threads
  int cnt = 0;
  for (int k = 0; k < 8; ++k) {
    u16 u = xr[lane * 8 + k];
    int e = (u >> 7) & 0xFF;
    if (e >= 0xC0) ++cnt;
  }
  for (int o = 32; o; o >>= 1) cnt += __shfl_xor(cnt, o);
  if (lane == 0) *flag = (cnt >= 32) ? 1 : 0;   // 1 => inputs are f32
}

// ---------------- convert all float inputs to bf16 + fused pe generation ----------------
__global__ __launch_bounds__(256) void txl_convert(
    const void* x, const void* mems, const void* ub, const void* vb,
    const void* qkvw, const void* posw, const void* outw,
    const void* l1w, const void* l1b, const void* l2w, const void* l2b,
    const void* ln1s, const void* ln1b, const void* ln2s, const void* ln2b,
    u16* __restrict__ dst, u16* __restrict__ pe, const int* __restrict__ flag) {
  int idx = blockIdx.x * 256 + threadIdx.x;
  if (idx >= TOT_IN) {                       // fused sinusoid pe (positions S-1..0)
    int idx2 = idx - TOT_IN;
    if (idx2 >= PE_CNT) return;
    int p = idx2 >> 8, m = idx2 & 255;
    float posf = (float)(SS - 1 - p);
    float div = expf((float)(2 * m) * (-9.210340371976184f / 512.0f));
    float a = posf * div;
    pe[(size_t)p * DD + 2 * m] = f2b(sinf(a));
    pe[(size_t)p * DD + 2 * m + 1] = f2b(cosf(a));
    return;
  }
  const void* p; int local;
  if      (idx < OFF_MEMS) { p = x;    local = idx; }
  else if (idx < OFF_UB)   { p = mems; local = idx - OFF_MEMS; }
  else if (idx < OFF_VB)   { p = ub;   local = idx - OFF_UB; }
  else if (idx < OFF_QKVW) { p = vb;   local = idx - OFF_VB; }
  else if (idx < OFF_POSW) { p = qkvw; local = idx - OFF_QKVW; }
  else if (idx < OFF_OUTW) { p = posw; local = idx - OFF_POSW; }
  else if (idx < OFF_L1W)  { p = outw; local = idx - OFF_OUTW; }
  else if (idx < OFF_L1B)  { p = l1w;  local = idx - OFF_L1W; }
  else if (idx < OFF_L2W)  { p = l1b;  local = idx - OFF_L1B; }
  else if (idx < OFF_L2B)  { p = l2w;  local = idx - OFF_L2W; }
  else if (idx < OFF_LN1S) { p = l2b;  local = idx - OFF_L2B; }
  else if (idx < OFF_LN1B) { p = ln1s; local = idx - OFF_LN1S; }
  else if (idx < OFF_LN2S) { p = ln1b; local = idx - OFF_LN1B; }
  else if (idx < OFF_LN2B) { p = ln2s; local = idx - OFF_LN2S; }
  else                     { p = ln2b; local = idx - OFF_LN2B; }
  dst[idx] = (*flag) ? f2b(((const float*)p)[local]) : ((const u16*)p)[local];
}

// ---------------- GEMM v5: split-K + dbuf DMA staging + A-split prologue ----------------
// C = A[M,K] * B[N,K]^T over K-range [z*KS,(z+1)*KS); 128x128 tile, BK=32.
// A-split: tile rows < msplit read from A, else A2 (block-uniform pointer select;
// msplit is a multiple of 128 so tiles never straddle). Removes the cat memcpys.
// EPI=0: f32 partial C at z*M*N (summed in following LayerNorm).
// EPI=1: fused bias+relu -> bf16 (S=1 only).
// R4 lesson (rule #20): keep EPILOGUES simple so tm/tn fully unroll; the A-split
// is prologue-only. Counter guard: if VGPR drops to ~32 / WRITE_SIZE balloons,
// codegen regressed -> revert the split.
template <int EPI>
__global__ __launch_bounds__(256) void txl_gemm4(const u16* __restrict__ A,
                                                 const u16* __restrict__ A2, int msplit,
                                                 const u16* __restrict__ B,
                                                 float* __restrict__ C,
                                                 u16* __restrict__ Obf,
                                                 const u16* __restrict__ bias,
                                                 int M, int N, int K, int KS) {
  __shared__ __align__(16) u16 As[2][128 * 32];
  __shared__ __align__(16) u16 Bs[2][128 * 32];
  const int tid = threadIdx.x;
  const int wave = tid >> 6, lane = tid & 63;
  const int wm = (wave & 1) * 64, wn = (wave >> 1) * 64;
  const int m0 = blockIdx.x * 128, n0 = blockIdx.y * 128;
  const int kbeg = blockIdx.z * KS, kend = kbeg + KS;
  const int L15 = lane & 15, quad = lane >> 4;
  const u16* Abase = (m0 < msplit) ? (A + (size_t)m0 * K) : (A2 + (size_t)(m0 - msplit) * K);

  auto stage = [&](int k0, int buf) {
    for (int c = 0; c < 2; ++c) {
      int segBase = c * 256 + wave * 64;
      int seg = segBase + lane;
      int row = seg >> 2, q = seg & 3;
      dma16(&Abase[(size_t)row * K + k0 + q * 8], &As[buf][segBase * 8]);
      dma16(&B[(size_t)(n0 + row) * K + k0 + q * 8], &Bs[buf][segBase * 8]);
    }
  };

  f32x4 acc[4][4] = {};
  stage(kbeg, 0);
  __syncthreads();                       // drain prologue DMA
  int buf = 0;
  for (int k0 = kbeg; k0 < kend; k0 += 32) {
    if (k0 + 32 < kend) stage(k0 + 32, buf ^ 1);   // prefetch next tile
    bf16x8 af[4], bfr[4];
    for (int t = 0; t < 4; ++t)
      af[t] = *reinterpret_cast<const bf16x8*>(&As[buf][(wm + t * 16 + L15) * 32 + quad * 8]);
    for (int t = 0; t < 4; ++t)
      bfr[t] = *reinterpret_cast<const bf16x8*>(&Bs[buf][(wn + t * 16 + L15) * 32 + quad * 8]);
    for (int tm = 0; tm < 4; ++tm)
      for (int tn = 0; tn < 4; ++tn)
        acc[tm][tn] = __builtin_amdgcn_mfma_f32_16x16x32_bf16(af[tm], bfr[tn], acc[tm][tn], 0, 0, 0);
    buf ^= 1;
    __syncthreads();                     // drains prefetch DMA + guards reuse
  }
  float* Cz = C + (size_t)blockIdx.z * ((size_t)M * N);
#pragma unroll
  for (int tm = 0; tm < 4; ++tm)
#pragma unroll
    for (int tn = 0; tn < 4; ++tn) {
      int col = n0 + wn + tn * 16 + L15;
#pragma unroll
      for (int r = 0; r < 4; ++r) {
        int row = m0 + wm + tm * 16 + quad * 4 + r;
        if (EPI == 0) {
          Cz[(size_t)row * N + col] = acc[tm][tn][r];
        } else {
          float v = acc[tm][tn][r] + b2f(bias[col]);
          Obf[(size_t)row * N + col] = f2b(fmaxf(v, 0.f));
        }
      }
    }
}

// ---------------- r GEMM, both layers batched (z = layer), fused scatter epilogue ----
// rb_z[((e>>6)*SS + p)*64 + (e&63)] = pe[p,:] . posw_z[e,:]
__global__ __launch_bounds__(256) void txl_gemm_r(const u16* __restrict__ A,
                                                  const u16* __restrict__ B,
                                                  u16* __restrict__ rb,
                                                  int M, int N, int K) {
  __shared__ __align__(16) u16 As[2][128 * 32];
  __shared__ __align__(16) u16 Bs[2][128 * 32];
  const int tid = threadIdx.x;
  const int wave = tid >> 6, lane = tid & 63;
  const int wm = (wave & 1) * 64, wn = (wave >> 1) * 64;
  const int m0 = blockIdx.x * 128, n0 = blockIdx.y * 128;
  const int L15 = lane & 15, quad = lane >> 4;
  const u16* Bz = B + (size_t)blockIdx.z * 262144;
  u16* rbz = rb + (size_t)blockIdx.z * 786432;

  auto stage = [&](int k0, int buf) {
    for (int c = 0; c < 2; ++c) {
      int segBase = c * 256 + wave * 64;
      int seg = segBase + lane;
      int row = seg >> 2, q = seg & 3;
      dma16(&A[(size_t)(m0 + row) * K + k0 + q * 8], &As[buf][segBase * 8]);
      dma16(&Bz[(size_t)(n0 + row) * K + k0 + q * 8], &Bs[buf][segBase * 8]);
    }
  };

  f32x4 acc[4][4] = {};
  stage(0, 0);
  __syncthreads();
  int buf = 0;
  for (int k0 = 0; k0 < K; k0 += 32) {
    if (k0 + 32 < K) stage(k0 + 32, buf ^ 1);
    bf16x8 af[4], bfr[4];
    for (int t = 0; t < 4; ++t)
      af[t] = *reinterpret_cast<const bf16x8*>(&As[buf][(wm + t * 16 + L15) * 32 + quad * 8]);
    for (int t = 0; t < 4; ++t)
      bfr[t] = *reinterpret_cast<const bf16x8*>(&Bs[buf][(wn + t * 16 + L15) * 32 + quad * 8]);
    for (int tm = 0; tm < 4; ++tm)
      for (int tn = 0; tn < 4; ++tn)
        acc[tm][tn] = __builtin_amdgcn_mfma_f32_16x16x32_bf16(af[tm], bfr[tn], acc[tm][tn], 0, 0, 0);
    buf ^= 1;
    __syncthreads();
  }
#pragma unroll
  for (int tm = 0; tm < 4; ++tm)
#pragma unroll
    for (int tn = 0; tn < 4; ++tn) {
      int col = n0 + wn + tn * 16 + L15;
      int n = col >> 6, d = col & 63;
#pragma unroll
      for (int r = 0; r < 4; ++r) {
        int row = m0 + wm + tm * 16 + quad * 4 + r;
        rbz[((size_t)n * SS + row) * HDIM + d] = f2b(acc[tm][tn][r]);
      }
    }
}

// ---------------- [B,T,D] -> [T,B,D] + fused new_mems[0] store ----------------
__global__ void txl_transpose_in(const u16* __restrict__ x, u16* __restrict__ cur_bf,
                                 float* __restrict__ cur_f, void* __restrict__ outv,
                                 const int* __restrict__ flag) {
  int idx = blockIdx.x * 256 + threadIdx.x;    // BB*TT*DD
  if (idx >= BB * TT * DD) return;
  int b = idx >> 19, t = (idx >> 9) & 1023, d = idx & 511;
  u16 v = x[idx];
  size_t o = ((size_t)t * BB + b) * DD + d;
  cur_bf[o] = v; cur_f[o] = b2f(v);
  if (t >= 512) {                               // new_mems[0] = xs rows 512..1023
    size_t mo = 2097152 + (o - 1048576);
    if (*flag) ((float*)outv)[mo] = b2f(v);
    else       ((u16*)outv)[mo] = v;
  }
}

// ---------------- fused qkv post-pass: V transpose (blocks 0..767) + q/k scatter ----
// Replaces txl_qkv_scatter + txl_v_transpose (one launch; scatter path indexes only
// the e<1024 two-thirds -> pow2 div, no dead lanes).
__global__ __launch_bounds__(256) void txl_qkv_post(
    const float* __restrict__ C, const u16* __restrict__ ub, const u16* __restrict__ vb,
    u16* __restrict__ qu, u16* __restrict__ qv, u16* __restrict__ kb,
    u16* __restrict__ vT) {
  __shared__ u16 t[64][68];
  const int bx = blockIdx.x;
  const int tid = threadIdx.x;
  if (bx < 768) {                      // ---- V transpose via LDS ----
    int sb = bx >> 5;                  // 0..23
    int bn = bx & 31;
    int n = bn & 7, b = bn >> 3;
    int s0 = sb * 64;
    {
      int d = tid & 63, sr = tid >> 6;
      for (int i = 0; i < 16; ++i) {
        int s = s0 + sr + i * 4;
        t[sr + i * 4][d] = f2b(C[(size_t)(s * 4 + b) * 1536 + 1024 + n * 64 + d]);
      }
    }
    __syncthreads();
    {
      int s = tid & 63, dr = tid >> 6;
      u16* dst = vT + (size_t)(b * HH + n) * HDIM * SS;
      for (int i = 0; i < 16; ++i) {
        int d2 = dr + i * 4;
        dst[(size_t)d2 * SS + s0 + s] = t[s][d2];
      }
    }
    return;
  }
  // ---- q/k scatter over e in [0,1024) ----
  int idx = (bx - 768) * 256 + tid;    // [0, SS*BB*1024)
  int row = idx >> 10, e = idx & 1023;
  int s = row >> 2, b = row & 3;
  float val = C[(size_t)row * 1536 + e];
  if (e < 512) {
    if (s >= MM) {
      int i = s - MM, n = e >> 6, d = e & 63;
      size_t o = ((size_t)(b * HH + n) * TT + i) * HDIM + d;
      qu[o] = f2b(val + b2f(ub[e]));
      qv[o] = f2b(val + b2f(vb[e]));
    }
  } else {
    int e2 = e - 512, n = e2 >> 6, d = e2 & 63;
    kb[((size_t)(b * HH + n) * SS + s) * HDIM + d] = f2b(val);
  }
}

// ---------------- flash attention v10: balanced K-split pieces + LDS DMA staging ----
// 1024 blocks x 256 threads (4 waves), 4 blocks/CU. Each supertile split into 2
// EQUAL pieces of 9+st chunks; piece 1 serves supertile 15-st_i so every CU
// carries exactly 66 chunks (v9 was 52..80). Measured R8: 41.0us, occ 28%.
__global__ __launch_bounds__(256) void txl_attn9(
    const u16* __restrict__ qu, const u16* __restrict__ qv, const u16* __restrict__ kbuf,
    const u16* __restrict__ vT, const u16* __restrict__ rbuf,
    float* __restrict__ O0, float* __restrict__ O1,
    float* __restrict__ L0, float* __restrict__ L1) {
  __shared__ __align__(16) u16 Kb[2][2048];   // chunk K: 32 rows x 64
  __shared__ __align__(16) u16 Vb[2][2048];   // chunk V^T: 64 d-rows x 32
  __shared__ __align__(16) u16 Rr[8][1024];   // r ring: 8 slabs of 16 rows x 64
  __shared__ __align__(16) u16 ps4[4][640];   // per-wave P staging [16][40]

  const int bx = blockIdx.x;
  const int n = bx & 7;                 // XCD class = head
  const int rest = bx >> 3;
  const int b = rest & 3;
  const int rest2 = rest >> 2;          // 0..31
  const int piece = rest2 >> 4;
  const int st = piece ? (15 - (rest2 & 15)) : (rest2 & 15);   // LPT pairing
  const int i0b = st * 64;
  const int g0 = 63 - (i0b >> 4);
  const int jcEnd = 18 + 2 * st;        // chunks covering j <= i0b+63+512
  const int half = 9 + st;
  const int jcBeg = piece ? half : 0;
  const int jcLim = piece ? jcEnd : half;
  const int gB = g0 + 2 * jcBeg;

  const int tid = threadIdx.x, w = tid >> 6, lane = tid & 63;
  const int L15 = lane & 15, quad = lane >> 4;
  const int i0w = i0b + 16 * w;
  const int bh = b * HH + n;

  const u16* kB = kbuf + (size_t)bh * SS * HDIM;
  const u16* rB = rbuf + (size_t)n * SS * HDIM;
  const u16* vB = vT + (size_t)bh * HDIM * SS;

  // Q fragments (regular loads; drained by prologue barrier)
  const u16* quB = qu + ((size_t)bh * TT + i0w) * HDIM;
  const u16* qvB = qv + ((size_t)bh * TT + i0w) * HDIM;
  bf16x8 aqu[2], aqv[2];
  for (int c = 0; c < 2; ++c) {
    aqu[c] = *reinterpret_cast<const bf16x8*>(&quB[(size_t)L15 * HDIM + c * 32 + quad * 8]);
    aqv[c] = *reinterpret_cast<const bf16x8*>(&qvB[(size_t)L15 * HDIM + c * 32 + quad * 8]);
  }

  u16* ps = &ps4[w][0];

  auto stageK = [&](int jc) {
    const u16* src = kB + (size_t)(jc * 32 + (lane & 31)) * HDIM + (2 * w + (lane >> 5)) * 8;
    dma16(src, &Kb[jc & 1][512 * w]);
  };
  auto stageV = [&](int jc) {
    const u16* src = vB + (size_t)lane * SS + jc * 32 + 8 * w;
    dma16(src, &Vb[jc & 1][512 * w]);
  };
  auto stageRslab = [&](int slab) {
    int rrow = slab * 16 + (lane & 15);
    rrow = (rrow > SS - 1) ? (SS - 1) : rrow;   // clamped rows only feed masked lanes
    const u16* s0 = rB + (size_t)rrow * HDIM + (lane >> 4) * 8;
    dma16(s0, &Rr[slab & 7][0]);
    dma16(s0 + 32, &Rr[slab & 7][512]);
  };
  auto rfrag = [&](int slab, int h) {
    return *reinterpret_cast<const bf16x8*>(&Rr[slab & 7][((quad + 4 * h) * 16 + L15) * 8]);
  };

  // ---- prologue: stage chunk jcBeg + r window [gB-3, gB+2] ----
  stageK(jcBeg); stageV(jcBeg);
  stageRslab(gB - 3 + w);
  if (w < 2) stageRslab(gB + 1 + w);
  __syncthreads();

  f32x4 pT0 = {};
  pT0 = __builtin_amdgcn_mfma_f32_16x16x32_bf16(aqv[0], rfrag(gB - w, 0), pT0, 0, 0, 0);
  pT0 = __builtin_amdgcn_mfma_f32_16x16x32_bf16(aqv[1], rfrag(gB - w, 1), pT0, 0, 0, 0);

  float l_lane[4] = {0.f, 0.f, 0.f, 0.f};
  f32x4 Oacc[4] = {};

  for (int jc = jcBeg; jc < jcLim; ++jc) {
    if (jc + 1 < jcLim) {               // issue next-chunk DMA (disjoint LDS regions)
      stageK(jc + 1); stageV(jc + 1);
      if (w < 2) stageRslab(g0 + 3 + 2 * jc + w);
    }
    const int hslot = jc & 1, j0 = jc * 32;
    bf16x8 k00 = *reinterpret_cast<const bf16x8*>(&Kb[hslot][((quad) * 32 + L15) * 8]);
    bf16x8 k01 = *reinterpret_cast<const bf16x8*>(&Kb[hslot][((quad + 4) * 32 + L15) * 8]);
    bf16x8 k10 = *reinterpret_cast<const bf16x8*>(&Kb[hslot][((quad) * 32 + 16 + L15) * 8]);
    bf16x8 k11 = *reinterpret_cast<const bf16x8*>(&Kb[hslot][((quad + 4) * 32 + 16 + L15) * 8]);
    f32x4 s0v = {}, s1v = {};
    s0v = __builtin_amdgcn_mfma_f32_16x16x32_bf16(aqu[0], k00, s0v, 0, 0, 0);
    s0v = __builtin_amdgcn_mfma_f32_16x16x32_bf16(aqu[1], k01, s0v, 0, 0, 0);
    s1v = __builtin_amdgcn_mfma_f32_16x16x32_bf16(aqu[0], k10, s1v, 0, 0, 0);
    s1v = __builtin_amdgcn_mfma_f32_16x16x32_bf16(aqu[1], k11, s1v, 0, 0, 0);
    const int sl1 = g0 - w + 2 * jc + 1;
    f32x4 pT1 = {}, pT2 = {};
    pT1 = __builtin_amdgcn_mfma_f32_16x16x32_bf16(aqv[0], rfrag(sl1, 0), pT1, 0, 0, 0);
    pT1 = __builtin_amdgcn_mfma_f32_16x16x32_bf16(aqv[1], rfrag(sl1, 1), pT1, 0, 0, 0);
    pT2 = __builtin_amdgcn_mfma_f32_16x16x32_bf16(aqv[0], rfrag(sl1 + 1, 0), pT2, 0, 0, 0);
    pT2 = __builtin_amdgcn_mfma_f32_16x16x32_bf16(aqv[1], rfrag(sl1 + 1, 1), pT2, 0, 0, 0);
    for (int r = 0; r < 4; ++r) {
      int ii = quad * 4 + r;
      int i = i0w + ii;
      int c = 15 + L15 - ii;                       // [0,30]
      int srcLane = (quad << 4) | (c & 15);
      float a0 = __shfl(pT0[r], srcLane);
      float a1 = __shfl(pT1[r], srcLane);
      float b1v = __shfl(pT2[r], srcLane);
      float sv0 = s0v[r] + ((c < 16) ? a0 : a1);
      float sv1 = s1v[r] + ((c < 16) ? a1 : b1v);
      sv0 = (j0 + L15 <= i + MM) ? sv0 : -3e38f;
      sv1 = (j0 + 16 + L15 <= i + MM) ? sv1 : -3e38f;
      float e0 = __expf(sv0 * SCALE);              // masked -> 0
      float e1 = __expf(sv1 * SCALE);
      l_lane[r] += e0 + e1;
      int row = ii * 40;
      ps[row + L15] = f2b(e0);
      ps[row + 16 + L15] = f2b(e1);
    }
    bf16x8 ap = *reinterpret_cast<const bf16x8*>(&ps[L15 * 40 + quad * 8]);
    bf16x8 v0 = *reinterpret_cast<const bf16x8*>(&Vb[hslot][(quad * 64 + L15) * 8]);
    bf16x8 v1 = *reinterpret_cast<const bf16x8*>(&Vb[hslot][(quad * 64 + 16 + L15) * 8]);
    bf16x8 v2 = *reinterpret_cast<const bf16x8*>(&Vb[hslot][(quad * 64 + 32 + L15) * 8]);
    bf16x8 v3 = *reinterpret_cast<const bf16x8*>(&Vb[hslot][(quad * 64 + 48 + L15) * 8]);
    Oacc[0] = __builtin_amdgcn_mfma_f32_16x16x32_bf16(ap, v0, Oacc[0], 0, 0, 0);
    Oacc[1] = __builtin_amdgcn_mfma_f32_16x16x32_bf16(ap, v1, Oacc[1], 0, 0, 0);
    Oacc[2] = __builtin_amdgcn_mfma_f32_16x16x32_bf16(ap, v2, Oacc[2], 0, 0, 0);
    Oacc[3] = __builtin_amdgcn_mfma_f32_16x16x32_bf16(ap, v3, Oacc[3], 0, 0, 0);
    pT0 = pT2;
    __syncthreads();   // drains this iter's DMA + publishes staging
  }

  // ---- write unnormalized piece results ----
  float lsum[4];
  for (int r = 0; r < 4; ++r) {
    float s = l_lane[r];
    for (int o = 1; o < 16; o <<= 1) s += __shfl_xor(s, o);
    lsum[r] = s;
  }
  float* Op = piece ? O1 : O0;
  float* Lp = piece ? L1 : L0;
  for (int tn = 0; tn < 4; ++tn)
    for (int r = 0; r < 4; ++r) {
      int ii = quad * 4 + r;
      Op[((size_t)(i0w + ii) * BB + b) * DD + n * HDIM + tn * 16 + L15] = Oacc[tn][r];
    }
  if (L15 == 0)
    for (int r = 0; r < 4; ++r)
      Lp[(size_t)bh * TT + i0w + quad * 4 + r] = lsum[r];
}

// ---------------- merge attention pieces -> ctx bf16 ----------------
__global__ void txl_attn_merge(const float* __restrict__ O0, const float* __restrict__ O1,
                               const float* __restrict__ L0, const float* __restrict__ L1,
                               u16* __restrict__ ctx) {
  int o = blockIdx.x * 256 + threadIdx.x;   // 2,097,152
  if (o >= BB * TT * DD) return;
  int i = o >> 11, b = (o >> 9) & 3, e = o & 511, n = e >> 6;
  size_t li = (size_t)(b * HH + n) * TT + i;
  float l = L0[li] + L1[li];
  ctx[o] = f2b((O0[o] + O1[o]) / l);
}

// ---------------- LayerNorm over nparts f32 partials (+ fused mems/final stores) ----
__global__ __launch_bounds__(256) void txl_ln(
    const float* __restrict__ gout, int nparts, const u16* __restrict__ bias,
    const float* __restrict__ resid, const u16* __restrict__ gam, const u16* __restrict__ bet,
    u16* __restrict__ ybf, float* __restrict__ yf,
    void* __restrict__ outv, int off, void* __restrict__ finalv,
    const int* __restrict__ flag) {
  const int row = blockIdx.x, tid = threadIdx.x;
  const int lane = tid & 63, wave = tid >> 6;
  __shared__ float red[4];
  size_t base = (size_t)row * DD;
  float x0 = resid[base + tid];
  float x1 = resid[base + tid + 256];
  for (int p = 0; p < nparts; ++p) {          // split-K partial sum (scalar accum)
    x0 += gout[(size_t)p * 2097152 + base + tid];
    x1 += gout[(size_t)p * 2097152 + base + tid + 256];
  }
  if (bias) { x0 += b2f(bias[tid]); x1 += b2f(bias[tid + 256]); }
  float s = x0 + x1;
  for (int o = 32; o; o >>= 1) s += __shfl_xor(s, o);
  if (lane == 0) red[wave] = s;
  __syncthreads();
  float mean = (red[0] + red[1] + red[2] + red[3]) * (1.f / DD);
  __syncthreads();
  float d0 = x0 - mean, d1 = x1 - mean;
  float q = d0 * d0 + d1 * d1;
  for (int o = 32; o; o >>= 1) q += __shfl_xor(q, o);
  if (lane == 0) red[wave] = q;
  __syncthreads();
  float var = (red[0] + red[1] + red[2] + red[3]) * (1.f / DD);
  float rstd = rsqrtf(var + LN_EPS);
  float y0 = d0 * rstd * b2f(gam[tid]) + b2f(bet[tid]);
  float y1 = d1 * rstd * b2f(gam[tid + 256]) + b2f(bet[tid + 256]);
  u16 u0 = f2b(y0), u1 = f2b(y1);
  ybf[base + tid] = u0;
  ybf[base + tid + 256] = u1;
  yf[base + tid] = y0;
  yf[base + tid + 256] = y1;
  if (outv && row >= 2048) {   // fused new_mems[l+1] store (rows t>=512)
    size_t mo = (size_t)off + (size_t)(row - 2048) * DD;
    if (*flag) {
      ((float*)outv)[mo + tid] = y0;
      ((float*)outv)[mo + tid + 256] = y1;
    } else {
      ((u16*)outv)[mo + tid] = u0;
      ((u16*)outv)[mo + tid + 256] = u1;
    }
  }
  if (finalv) {                // fused final = swapaxes(out,0,1) (last layer only)
    int t = row >> 2, b = row & 3;
    size_t fo = ((size_t)b * TT + t) * DD;
    if (*flag) {
      ((float*)finalv)[fo + tid] = y0;
      ((float*)finalv)[fo + tid + 256] = y1;
    } else {
      ((u16*)finalv)[fo + tid] = u0;
      ((u16*)finalv)[fo + tid + 256] = u1;
    }
  }
}

// ---------------- workspace layout (bytes; R3-proven 138MB footprint) ----------------
constexpr size_t WS_CUR_F  = 0;
constexpr size_t WS_RB2    = 8388608;     // 2x 1,572,864 rb (layer 0,1) in old cat region
constexpr size_t WS_CBUF   = 14680064;    // 37,748,736 (f32; fits split-K parts)
constexpr size_t WS_QU     = 52428800;
constexpr size_t WS_QV     = 56623104;
constexpr size_t WS_K      = 60817408;
constexpr size_t WS_VT     = 67108864;
constexpr size_t WS_R      = 73400320;    // unused (kept for layout stability)
constexpr size_t WS_PE     = 74973184;
constexpr size_t WS_CTX    = 76546048;
constexpr size_t WS_HBF    = 80740352;
constexpr size_t WS_HF     = 84934656;
constexpr size_t WS_FF1    = 93323264;
constexpr size_t WS_CURBF  = 110100480;
constexpr size_t WS_CIN    = 114294784;   // bf16 [12,068,864] = 24,137,728 B
constexpr size_t WS_FLAG   = 138432512;   // int
constexpr size_t WS_TOTAL  = 138432576;
// attn piece buffers alias the (dead-at-that-point) Cbuf region:
constexpr size_t WS_OB0 = WS_CBUF;              // 8,388,608
constexpr size_t WS_OB1 = WS_CBUF + 8388608;    // 8,388,608
constexpr size_t WS_LB0 = WS_CBUF + 16777216;   // 131,072
constexpr size_t WS_LB1 = WS_CBUF + 16908288;   // 131,072

extern "C" void kernel_launch(void* const* d_in, const int* in_sizes, int n_in,
                              void* d_out, int out_size, void* d_ws, size_t ws_size,
                              hipStream_t stream) {
  (void)in_sizes; (void)n_in;

  if (ws_size < WS_TOTAL) {  // fail cleanly
    hipMemsetAsync(d_out, 0, (size_t)out_size * 2, stream);
    return;
  }
  char* ws = (char*)d_ws;
  float* cur_f  = (float*)(ws + WS_CUR_F);
  u16*   rb2    = (u16*)(ws + WS_RB2);
  float* Cbuf   = (float*)(ws + WS_CBUF);
  float* Ob0    = (float*)(ws + WS_OB0);
  float* Ob1    = (float*)(ws + WS_OB1);
  float* Lb0    = (float*)(ws + WS_LB0);
  float* Lb1    = (float*)(ws + WS_LB1);
  u16*   qu     = (u16*)(ws + WS_QU);
  u16*   qv     = (u16*)(ws + WS_QV);
  u16*   kb     = (u16*)(ws + WS_K);
  u16*   vT     = (u16*)(ws + WS_VT);
  u16*   pe     = (u16*)(ws + WS_PE);
  u16*   ctx    = (u16*)(ws + WS_CTX);
  u16*   hbf    = (u16*)(ws + WS_HBF);
  float* hf     = (float*)(ws + WS_HF);
  u16*   ff1    = (u16*)(ws + WS_FF1);
  u16*   cur_bf = (u16*)(ws + WS_CURBF);
  u16*   cin    = (u16*)(ws + WS_CIN);
  int*   flag   = (int*)(ws + WS_FLAG);

  // dtype probe + canonicalize all float inputs to bf16 (+ fused pe)
  txl_probe<<<1, 64, 0, stream>>>((const u16*)d_in[0], flag);
  txl_convert<<<48680, 256, 0, stream>>>(
      d_in[0], d_in[3], d_in[4], d_in[5], d_in[6], d_in[7], d_in[8],
      d_in[9], d_in[10], d_in[11], d_in[12], d_in[13], d_in[14], d_in[15], d_in[16],
      cin, pe, flag);

  const u16* ub = cin + OFF_UB;
  const u16* vb = cin + OFF_VB;

  // r = pe @ pos_w^T for BOTH layers (layer-independent; z = layer)
  txl_gemm_r<<<dim3(12, 4, 2), 256, 0, stream>>>(
      pe, cin + OFF_POSW, rb2, 1536, 512, 512);
  txl_transpose_in<<<8192, 256, 0, stream>>>(cin + OFF_X, cur_bf, cur_f, d_out, flag);

  for (int l = 0; l < NLAYER; ++l) {
    // qkv: A-split (rows<2048 from mems[l], rest from cur_bf) — no cat memcpys
    txl_gemm4<0><<<dim3(48, 12, 1), 256, 0, stream>>>(
        cin + OFF_MEMS + (size_t)l * 1048576, cur_bf, 2048,
        cin + OFF_QKVW + (size_t)l * 786432, Cbuf, nullptr, nullptr, 6144, 1536, 512, 512);
    // fused V-transpose + q/k scatter (one launch)
    txl_qkv_post<<<25344, 256, 0, stream>>>(Cbuf, ub, vb, qu, qv, kb, vT);
    // attention: 2 balanced K-pieces per supertile + merge (piece bufs alias Cbuf)
    txl_attn9<<<1024, 256, 0, stream>>>(qu, qv, kb, vT, rb2 + (size_t)l * 786432,
                                        Ob0, Ob1, Lb0, Lb1);
    txl_attn_merge<<<8192, 256, 0, stream>>>(Ob0, Ob1, Lb0, Lb1, ctx);
    // out projection: split-K S=2 (2 f32 partials, summed in ln1)
    txl_gemm4<0><<<dim3(32, 4, 2), 256, 0, stream>>>(
        ctx, ctx, 1 << 30, cin + OFF_OUTW + (size_t)l * 262144, Cbuf,
        nullptr, nullptr, 4096, 512, 512, 256);
    txl_ln<<<4096, 256, 0, stream>>>(Cbuf, 2, nullptr, cur_f,
                                     cin + OFF_LN1S + l * 512, cin + OFF_LN1B + l * 512,
                                     hbf, hf, nullptr, 0, nullptr, flag);
    // FFN1 (S=1, fused bias+relu)
    txl_gemm4<1><<<dim3(32, 16, 1), 256, 0, stream>>>(
        hbf, hbf, 1 << 30, cin + OFF_L1W + (size_t)l * 1048576, nullptr,
        ff1, cin + OFF_L1B + l * 2048, 4096, 2048, 512, 512);
    // FFN2: split-K S=4 (4 f32 partials, summed in ln2)
    txl_gemm4<0><<<dim3(32, 4, 4), 256, 0, stream>>>(
        ff1, ff1, 1 << 30, cin + OFF_L2W + (size_t)l * 1048576, Cbuf,
        nullptr, nullptr, 4096, 512, 2048, 512);
    // ln2 with fused new_mems[l+1] store (+ fused final transpose-store on last layer)
    txl_ln<<<4096, 256, 0, stream>>>(Cbuf, 4, cin + OFF_L2B + l * 512, hf,
                                     cin + OFF_LN2S + l * 512, cin + OFF_LN2B + l * 512,
                                     cur_bf, cur_f, d_out, 2097152 + (l + 1) * 1048576,
                                     (l == NLAYER - 1) ? d_out : nullptr, flag);
  }
}

// Round 10
// 443.638 us; speedup vs baseline: 1.9928x; 1.0112x over previous
//
#include <hip/hip_runtime.h>

// ---------------- problem constants ----------------
constexpr int BB = 4, TT = 1024, DD = 512, HH = 8, HDIM = 64;
constexpr int FFD = 2048, NLAYER = 2, MM = 512, SS = 1536;
constexpr float LN_EPS = 1e-5f;
constexpr float SCALE = 0.04419417382415922f; // 1/sqrt(512)

typedef unsigned short u16;
typedef __attribute__((ext_vector_type(8))) short bf16x8;
typedef __attribute__((ext_vector_type(4))) float f32x4;

__device__ __forceinline__ float b2f(u16 u) {
  union { unsigned int i; float f; } c; c.i = ((unsigned int)u) << 16; return c.f;
}
__device__ __forceinline__ u16 f2b(float f) {
  unsigned int x = __builtin_bit_cast(unsigned int, f);
  x += 0x7fffu + ((x >> 16) & 1u);   // RNE (finite values only)
  return (u16)(x >> 16);
}

// async global->LDS DMA, 16B per lane. LDS dest = uniform base + lane*16.
__device__ __forceinline__ void dma16(const u16* g, u16* l) {
  __builtin_amdgcn_global_load_lds(
      (const __attribute__((address_space(1))) unsigned int*)g,
      (__attribute__((address_space(3))) unsigned int*)l, 16, 0, 0);
}

// ---------------- canonical input buffer offsets (elements) ----------------
constexpr int OFF_X    = 0;          // 2,097,152
constexpr int OFF_MEMS = 2097152;    // 3,145,728
constexpr int OFF_UB   = 5242880;    // 512
constexpr int OFF_VB   = 5243392;    // 512
constexpr int OFF_QKVW = 5243904;    // 1,572,864 (786,432 per layer)
constexpr int OFF_POSW = 6816768;    // 524,288 (262,144 per layer)
constexpr int OFF_OUTW = 7341056;    // 524,288
constexpr int OFF_L1W  = 7865344;    // 2,097,152 (1,048,576 per layer)
constexpr int OFF_L1B  = 9962496;    // 4,096 (2,048 per layer)
constexpr int OFF_L2W  = 9966592;    // 2,097,152
constexpr int OFF_L2B  = 12063744;   // 1,024 (512 per layer)
constexpr int OFF_LN1S = 12064768;
constexpr int OFF_LN1B = 12065792;
constexpr int OFF_LN2S = 12066816;
constexpr int OFF_LN2B = 12067840;
constexpr int TOT_IN   = 12068864;   // = 47,144 * 256
constexpr int PE_CNT   = SS * 256;   // 393,216 pe work items (folded into convert)

// ---------------- dtype probe ----------------
__global__ void txl_probe(const u16* __restrict__ xr, int* __restrict__ flag) {
  int lane = threadIdx.x;   // 64 threads
  int cnt = 0;
  for (int k = 0; k < 8; ++k) {
    u16 u = xr[lane * 8 + k];
    int e = (u >> 7) & 0xFF;
    if (e >= 0xC0) ++cnt;
  }
  for (int o = 32; o; o >>= 1) cnt += __shfl_xor(cnt, o);
  if (lane == 0) *flag = (cnt >= 32) ? 1 : 0;   // 1 => inputs are f32
}

// ---------------- convert all float inputs to bf16 + fused pe generation ----------------
__global__ __launch_bounds__(256) void txl_convert(
    const void* x, const void* mems, const void* ub, const void* vb,
    const void* qkvw, const void* posw, const void* outw,
    const void* l1w, const void* l1b, const void* l2w, const void* l2b,
    const void* ln1s, const void* ln1b, const void* ln2s, const void* ln2b,
    u16* __restrict__ dst, u16* __restrict__ pe, const int* __restrict__ flag) {
  int idx = blockIdx.x * 256 + threadIdx.x;
  if (idx >= TOT_IN) {                       // fused sinusoid pe (positions S-1..0)
    int idx2 = idx - TOT_IN;
    if (idx2 >= PE_CNT) return;
    int p = idx2 >> 8, m = idx2 & 255;
    float posf = (float)(SS - 1 - p);
    float div = expf((float)(2 * m) * (-9.210340371976184f / 512.0f));
    float a = posf * div;
    pe[(size_t)p * DD + 2 * m] = f2b(sinf(a));
    pe[(size_t)p * DD + 2 * m + 1] = f2b(cosf(a));
    return;
  }
  const void* p; int local;
  if      (idx < OFF_MEMS) { p = x;    local = idx; }
  else if (idx < OFF_UB)   { p = mems; local = idx - OFF_MEMS; }
  else if (idx < OFF_VB)   { p = ub;   local = idx - OFF_UB; }
  else if (idx < OFF_QKVW) { p = vb;   local = idx - OFF_VB; }
  else if (idx < OFF_POSW) { p = qkvw; local = idx - OFF_QKVW; }
  else if (idx < OFF_OUTW) { p = posw; local = idx - OFF_POSW; }
  else if (idx < OFF_L1W)  { p = outw; local = idx - OFF_OUTW; }
  else if (idx < OFF_L1B)  { p = l1w;  local = idx - OFF_L1W; }
  else if (idx < OFF_L2W)  { p = l1b;  local = idx - OFF_L1B; }
  else if (idx < OFF_L2B)  { p = l2w;  local = idx - OFF_L2W; }
  else if (idx < OFF_LN1S) { p = l2b;  local = idx - OFF_L2B; }
  else if (idx < OFF_LN1B) { p = ln1s; local = idx - OFF_LN1S; }
  else if (idx < OFF_LN2S) { p = ln1b; local = idx - OFF_LN1B; }
  else if (idx < OFF_LN2B) { p = ln2s; local = idx - OFF_LN2S; }
  else                     { p = ln2b; local = idx - OFF_LN2B; }
  dst[idx] = (*flag) ? f2b(((const float*)p)[local]) : ((const u16*)p)[local];
}

// ---------------- GEMM v5: split-K + dbuf DMA staging + A-split prologue ----------------
// C = A[M,K] * B[N,K]^T over K-range [z*KS,(z+1)*KS); 128x128 tile, BK=32.
// A-split: tile rows < msplit read from A, else A2 (block-uniform pointer select).
// EPI=0: f32 partial C at z*M*N (summed in following LayerNorm).
// EPI=1: fused bias+relu -> bf16 (S=1 only).
// EPI=2: plain bf16 C (qkv; halves the intermediate traffic) + dead-block
//        early-exit (q-cols x mem-rows never read downstream).
// R4 lesson (rule #20): keep EPILOGUES simple so tm/tn fully unroll.
template <int EPI>
__global__ __launch_bounds__(256) void txl_gemm4(const u16* __restrict__ A,
                                                 const u16* __restrict__ A2, int msplit,
                                                 const u16* __restrict__ B,
                                                 float* __restrict__ C,
                                                 u16* __restrict__ Obf,
                                                 const u16* __restrict__ bias,
                                                 int M, int N, int K, int KS) {
  const int m0 = blockIdx.x * 128, n0 = blockIdx.y * 128;
  if (EPI == 2 && n0 < 512 && m0 < 2048) return;   // q-output for mem rows: unused
  __shared__ __align__(16) u16 As[2][128 * 32];
  __shared__ __align__(16) u16 Bs[2][128 * 32];
  const int tid = threadIdx.x;
  const int wave = tid >> 6, lane = tid & 63;
  const int wm = (wave & 1) * 64, wn = (wave >> 1) * 64;
  const int kbeg = blockIdx.z * KS, kend = kbeg + KS;
  const int L15 = lane & 15, quad = lane >> 4;
  const u16* Abase = (m0 < msplit) ? (A + (size_t)m0 * K) : (A2 + (size_t)(m0 - msplit) * K);

  auto stage = [&](int k0, int buf) {
    for (int c = 0; c < 2; ++c) {
      int segBase = c * 256 + wave * 64;
      int seg = segBase + lane;
      int row = seg >> 2, q = seg & 3;
      dma16(&Abase[(size_t)row * K + k0 + q * 8], &As[buf][segBase * 8]);
      dma16(&B[(size_t)(n0 + row) * K + k0 + q * 8], &Bs[buf][segBase * 8]);
    }
  };

  f32x4 acc[4][4] = {};
  stage(kbeg, 0);
  __syncthreads();                       // drain prologue DMA
  int buf = 0;
  for (int k0 = kbeg; k0 < kend; k0 += 32) {
    if (k0 + 32 < kend) stage(k0 + 32, buf ^ 1);   // prefetch next tile
    bf16x8 af[4], bfr[4];
    for (int t = 0; t < 4; ++t)
      af[t] = *reinterpret_cast<const bf16x8*>(&As[buf][(wm + t * 16 + L15) * 32 + quad * 8]);
    for (int t = 0; t < 4; ++t)
      bfr[t] = *reinterpret_cast<const bf16x8*>(&Bs[buf][(wn + t * 16 + L15) * 32 + quad * 8]);
    for (int tm = 0; tm < 4; ++tm)
      for (int tn = 0; tn < 4; ++tn)
        acc[tm][tn] = __builtin_amdgcn_mfma_f32_16x16x32_bf16(af[tm], bfr[tn], acc[tm][tn], 0, 0, 0);
    buf ^= 1;
    __syncthreads();                     // drains prefetch DMA + guards reuse
  }
  float* Cz = C + (size_t)blockIdx.z * ((size_t)M * N);
#pragma unroll
  for (int tm = 0; tm < 4; ++tm)
#pragma unroll
    for (int tn = 0; tn < 4; ++tn) {
      int col = n0 + wn + tn * 16 + L15;
#pragma unroll
      for (int r = 0; r < 4; ++r) {
        int row = m0 + wm + tm * 16 + quad * 4 + r;
        if (EPI == 0) {
          Cz[(size_t)row * N + col] = acc[tm][tn][r];
        } else if (EPI == 1) {
          float v = acc[tm][tn][r] + b2f(bias[col]);
          Obf[(size_t)row * N + col] = f2b(fmaxf(v, 0.f));
        } else {
          Obf[(size_t)row * N + col] = f2b(acc[tm][tn][r]);
        }
      }
    }
}

// ---------------- r GEMM, both layers batched (z = layer), fused scatter epilogue ----
// rb_z[((e>>6)*SS + p)*64 + (e&63)] = pe[p,:] . posw_z[e,:]
__global__ __launch_bounds__(256) void txl_gemm_r(const u16* __restrict__ A,
                                                  const u16* __restrict__ B,
                                                  u16* __restrict__ rb,
                                                  int M, int N, int K) {
  __shared__ __align__(16) u16 As[2][128 * 32];
  __shared__ __align__(16) u16 Bs[2][128 * 32];
  const int tid = threadIdx.x;
  const int wave = tid >> 6, lane = tid & 63;
  const int wm = (wave & 1) * 64, wn = (wave >> 1) * 64;
  const int m0 = blockIdx.x * 128, n0 = blockIdx.y * 128;
  const int L15 = lane & 15, quad = lane >> 4;
  const u16* Bz = B + (size_t)blockIdx.z * 262144;
  u16* rbz = rb + (size_t)blockIdx.z * 786432;

  auto stage = [&](int k0, int buf) {
    for (int c = 0; c < 2; ++c) {
      int segBase = c * 256 + wave * 64;
      int seg = segBase + lane;
      int row = seg >> 2, q = seg & 3;
      dma16(&A[(size_t)(m0 + row) * K + k0 + q * 8], &As[buf][segBase * 8]);
      dma16(&Bz[(size_t)(n0 + row) * K + k0 + q * 8], &Bs[buf][segBase * 8]);
    }
  };

  f32x4 acc[4][4] = {};
  stage(0, 0);
  __syncthreads();
  int buf = 0;
  for (int k0 = 0; k0 < K; k0 += 32) {
    if (k0 + 32 < K) stage(k0 + 32, buf ^ 1);
    bf16x8 af[4], bfr[4];
    for (int t = 0; t < 4; ++t)
      af[t] = *reinterpret_cast<const bf16x8*>(&As[buf][(wm + t * 16 + L15) * 32 + quad * 8]);
    for (int t = 0; t < 4; ++t)
      bfr[t] = *reinterpret_cast<const bf16x8*>(&Bs[buf][(wn + t * 16 + L15) * 32 + quad * 8]);
    for (int tm = 0; tm < 4; ++tm)
      for (int tn = 0; tn < 4; ++tn)
        acc[tm][tn] = __builtin_amdgcn_mfma_f32_16x16x32_bf16(af[tm], bfr[tn], acc[tm][tn], 0, 0, 0);
    buf ^= 1;
    __syncthreads();
  }
#pragma unroll
  for (int tm = 0; tm < 4; ++tm)
#pragma unroll
    for (int tn = 0; tn < 4; ++tn) {
      int col = n0 + wn + tn * 16 + L15;
      int n = col >> 6, d = col & 63;
#pragma unroll
      for (int r = 0; r < 4; ++r) {
        int row = m0 + wm + tm * 16 + quad * 4 + r;
        rbz[((size_t)n * SS + row) * HDIM + d] = f2b(acc[tm][tn][r]);
      }
    }
}

// ---------------- [B,T,D] -> [T,B,D] + fused new_mems[0] store ----------------
__global__ void txl_transpose_in(const u16* __restrict__ x, u16* __restrict__ cur_bf,
                                 float* __restrict__ cur_f, void* __restrict__ outv,
                                 const int* __restrict__ flag) {
  int idx = blockIdx.x * 256 + threadIdx.x;    // BB*TT*DD
  if (idx >= BB * TT * DD) return;
  int b = idx >> 19, t = (idx >> 9) & 1023, d = idx & 511;
  u16 v = x[idx];
  size_t o = ((size_t)t * BB + b) * DD + d;
  cur_bf[o] = v; cur_f[o] = b2f(v);
  if (t >= 512) {                               // new_mems[0] = xs rows 512..1023
    size_t mo = 2097152 + (o - 1048576);
    if (*flag) ((float*)outv)[mo] = b2f(v);
    else       ((u16*)outv)[mo] = v;
  }
}

// ---------------- fused qkv post-pass (bf16 C): V transpose + q/k scatter ----------------
// q/qv are PRE-SCALED by 1/sqrt(512) so attention skips the per-score multiply.
__global__ __launch_bounds__(256) void txl_qkv_post(
    const u16* __restrict__ C, const u16* __restrict__ ub, const u16* __restrict__ vb,
    u16* __restrict__ qu, u16* __restrict__ qv, u16* __restrict__ kb,
    u16* __restrict__ vT) {
  __shared__ u16 t[64][68];
  const int bx = blockIdx.x;
  const int tid = threadIdx.x;
  if (bx < 768) {                      // ---- V transpose via LDS ----
    int sb = bx >> 5;                  // 0..23
    int bn = bx & 31;
    int n = bn & 7, b = bn >> 3;
    int s0 = sb * 64;
    {
      int d = tid & 63, sr = tid >> 6;
      for (int i = 0; i < 16; ++i) {
        int s = s0 + sr + i * 4;
        t[sr + i * 4][d] = C[(size_t)(s * 4 + b) * 1536 + 1024 + n * 64 + d];
      }
    }
    __syncthreads();
    {
      int s = tid & 63, dr = tid >> 6;
      u16* dst = vT + (size_t)(b * HH + n) * HDIM * SS;
      for (int i = 0; i < 16; ++i) {
        int d2 = dr + i * 4;
        dst[(size_t)d2 * SS + s0 + s] = t[s][d2];
      }
    }
    return;
  }
  // ---- q/k scatter over e in [0,1024) ----
  int idx = (bx - 768) * 256 + tid;    // [0, SS*BB*1024)
  int row = idx >> 10, e = idx & 1023;
  int s = row >> 2, b = row & 3;
  u16 cv = C[(size_t)row * 1536 + e];
  if (e < 512) {
    if (s >= MM) {
      int i = s - MM, n = e >> 6, d = e & 63;
      size_t o = ((size_t)(b * HH + n) * TT + i) * HDIM + d;
      float val = b2f(cv);
      qu[o] = f2b((val + b2f(ub[e])) * SCALE);
      qv[o] = f2b((val + b2f(vb[e])) * SCALE);
    }
  } else {
    int e2 = e - 512, n = e2 >> 6, d = e2 & 63;
    kb[((size_t)(b * HH + n) * SS + s) * HDIM + d] = cv;
  }
}

// ---------------- flash attention v10b: balanced K-split + pre-scaled q ----------------
// 1024 blocks x 256 threads (4 waves), 4 blocks/CU; every CU carries exactly 66
// chunks (LPT pairing: piece 1 serves supertile 15-st_i). R9: 43.5us — analysis:
// SIMD-issue-bound (4 waves x 12 MFMA ~930cy + ~600cy VALU per chunk ~ measured
// 1580cy/chunk/CU). q is pre-scaled so the score multiply is gone.
__global__ __launch_bounds__(256) void txl_attn9(
    const u16* __restrict__ qu, const u16* __restrict__ qv, const u16* __restrict__ kbuf,
    const u16* __restrict__ vT, const u16* __restrict__ rbuf,
    float* __restrict__ O0, float* __restrict__ O1,
    float* __restrict__ L0, float* __restrict__ L1) {
  __shared__ __align__(16) u16 Kb[2][2048];   // chunk K: 32 rows x 64
  __shared__ __align__(16) u16 Vb[2][2048];   // chunk V^T: 64 d-rows x 32
  __shared__ __align__(16) u16 Rr[8][1024];   // r ring: 8 slabs of 16 rows x 64
  __shared__ __align__(16) u16 ps4[4][640];   // per-wave P staging [16][40]

  const int bx = blockIdx.x;
  const int n = bx & 7;                 // XCD class = head
  const int rest = bx >> 3;
  const int b = rest & 3;
  const int rest2 = rest >> 2;          // 0..31
  const int piece = rest2 >> 4;
  const int st = piece ? (15 - (rest2 & 15)) : (rest2 & 15);   // LPT pairing
  const int i0b = st * 64;
  const int g0 = 63 - (i0b >> 4);
  const int jcEnd = 18 + 2 * st;        // chunks covering j <= i0b+63+512
  const int half = 9 + st;
  const int jcBeg = piece ? half : 0;
  const int jcLim = piece ? jcEnd : half;
  const int gB = g0 + 2 * jcBeg;

  const int tid = threadIdx.x, w = tid >> 6, lane = tid & 63;
  const int L15 = lane & 15, quad = lane >> 4;
  const int i0w = i0b + 16 * w;
  const int bh = b * HH + n;

  const u16* kB = kbuf + (size_t)bh * SS * HDIM;
  const u16* rB = rbuf + (size_t)n * SS * HDIM;
  const u16* vB = vT + (size_t)bh * HDIM * SS;

  // Q fragments (regular loads; drained by prologue barrier)
  const u16* quB = qu + ((size_t)bh * TT + i0w) * HDIM;
  const u16* qvB = qv + ((size_t)bh * TT + i0w) * HDIM;
  bf16x8 aqu[2], aqv[2];
  for (int c = 0; c < 2; ++c) {
    aqu[c] = *reinterpret_cast<const bf16x8*>(&quB[(size_t)L15 * HDIM + c * 32 + quad * 8]);
    aqv[c] = *reinterpret_cast<const bf16x8*>(&qvB[(size_t)L15 * HDIM + c * 32 + quad * 8]);
  }

  u16* ps = &ps4[w][0];

  auto stageK = [&](int jc) {
    const u16* src = kB + (size_t)(jc * 32 + (lane & 31)) * HDIM + (2 * w + (lane >> 5)) * 8;
    dma16(src, &Kb[jc & 1][512 * w]);
  };
  auto stageV = [&](int jc) {
    const u16* src = vB + (size_t)lane * SS + jc * 32 + 8 * w;
    dma16(src, &Vb[jc & 1][512 * w]);
  };
  auto stageRslab = [&](int slab) {
    int rrow = slab * 16 + (lane & 15);
    rrow = (rrow > SS - 1) ? (SS - 1) : rrow;   // clamped rows only feed masked lanes
    const u16* s0 = rB + (size_t)rrow * HDIM + (lane >> 4) * 8;
    dma16(s0, &Rr[slab & 7][0]);
    dma16(s0 + 32, &Rr[slab & 7][512]);
  };
  auto rfrag = [&](int slab, int h) {
    return *reinterpret_cast<const bf16x8*>(&Rr[slab & 7][((quad + 4 * h) * 16 + L15) * 8]);
  };

  // ---- prologue: stage chunk jcBeg + r window [gB-3, gB+2] ----
  stageK(jcBeg); stageV(jcBeg);
  stageRslab(gB - 3 + w);
  if (w < 2) stageRslab(gB + 1 + w);
  __syncthreads();

  f32x4 pT0 = {};
  pT0 = __builtin_amdgcn_mfma_f32_16x16x32_bf16(aqv[0], rfrag(gB - w, 0), pT0, 0, 0, 0);
  pT0 = __builtin_amdgcn_mfma_f32_16x16x32_bf16(aqv[1], rfrag(gB - w, 1), pT0, 0, 0, 0);

  float l_lane[4] = {0.f, 0.f, 0.f, 0.f};
  f32x4 Oacc[4] = {};

  for (int jc = jcBeg; jc < jcLim; ++jc) {
    if (jc + 1 < jcLim) {               // issue next-chunk DMA (disjoint LDS regions)
      stageK(jc + 1); stageV(jc + 1);
      if (w < 2) stageRslab(g0 + 3 + 2 * jc + w);
    }
    const int hslot = jc & 1, j0 = jc * 32;
    bf16x8 k00 = *reinterpret_cast<const bf16x8*>(&Kb[hslot][((quad) * 32 + L15) * 8]);
    bf16x8 k01 = *reinterpret_cast<const bf16x8*>(&Kb[hslot][((quad + 4) * 32 + L15) * 8]);
    bf16x8 k10 = *reinterpret_cast<const bf16x8*>(&Kb[hslot][((quad) * 32 + 16 + L15) * 8]);
    bf16x8 k11 = *reinterpret_cast<const bf16x8*>(&Kb[hslot][((quad + 4) * 32 + 16 + L15) * 8]);
    f32x4 s0v = {}, s1v = {};
    s0v = __builtin_amdgcn_mfma_f32_16x16x32_bf16(aqu[0], k00, s0v, 0, 0, 0);
    s0v = __builtin_amdgcn_mfma_f32_16x16x32_bf16(aqu[1], k01, s0v, 0, 0, 0);
    s1v = __builtin_amdgcn_mfma_f32_16x16x32_bf16(aqu[0], k10, s1v, 0, 0, 0);
    s1v = __builtin_amdgcn_mfma_f32_16x16x32_bf16(aqu[1], k11, s1v, 0, 0, 0);
    const int sl1 = g0 - w + 2 * jc + 1;
    f32x4 pT1 = {}, pT2 = {};
    pT1 = __builtin_amdgcn_mfma_f32_16x16x32_bf16(aqv[0], rfrag(sl1, 0), pT1, 0, 0, 0);
    pT1 = __builtin_amdgcn_mfma_f32_16x16x32_bf16(aqv[1], rfrag(sl1, 1), pT1, 0, 0, 0);
    pT2 = __builtin_amdgcn_mfma_f32_16x16x32_bf16(aqv[0], rfrag(sl1 + 1, 0), pT2, 0, 0, 0);
    pT2 = __builtin_amdgcn_mfma_f32_16x16x32_bf16(aqv[1], rfrag(sl1 + 1, 1), pT2, 0, 0, 0);
    for (int r = 0; r < 4; ++r) {
      int ii = quad * 4 + r;
      int i = i0w + ii;
      int c = 15 + L15 - ii;                       // [0,30]
      int srcLane = (quad << 4) | (c & 15);
      float a0 = __shfl(pT0[r], srcLane);
      float a1 = __shfl(pT1[r], srcLane);
      float b1v = __shfl(pT2[r], srcLane);
      float sv0 = s0v[r] + ((c < 16) ? a0 : a1);
      float sv1 = s1v[r] + ((c < 16) ? a1 : b1v);
      sv0 = (j0 + L15 <= i + MM) ? sv0 : -3e38f;
      sv1 = (j0 + 16 + L15 <= i + MM) ? sv1 : -3e38f;
      float e0 = __expf(sv0);                      // q pre-scaled; masked -> 0
      float e1 = __expf(sv1);
      l_lane[r] += e0 + e1;
      int row = ii * 40;
      ps[row + L15] = f2b(e0);
      ps[row + 16 + L15] = f2b(e1);
    }
    bf16x8 ap = *reinterpret_cast<const bf16x8*>(&ps[L15 * 40 + quad * 8]);
    bf16x8 v0 = *reinterpret_cast<const bf16x8*>(&Vb[hslot][(quad * 64 + L15) * 8]);
    bf16x8 v1 = *reinterpret_cast<const bf16x8*>(&Vb[hslot][(quad * 64 + 16 + L15) * 8]);
    bf16x8 v2 = *reinterpret_cast<const bf16x8*>(&Vb[hslot][(quad * 64 + 32 + L15) * 8]);
    bf16x8 v3 = *reinterpret_cast<const bf16x8*>(&Vb[hslot][(quad * 64 + 48 + L15) * 8]);
    Oacc[0] = __builtin_amdgcn_mfma_f32_16x16x32_bf16(ap, v0, Oacc[0], 0, 0, 0);
    Oacc[1] = __builtin_amdgcn_mfma_f32_16x16x32_bf16(ap, v1, Oacc[1], 0, 0, 0);
    Oacc[2] = __builtin_amdgcn_mfma_f32_16x16x32_bf16(ap, v2, Oacc[2], 0, 0, 0);
    Oacc[3] = __builtin_amdgcn_mfma_f32_16x16x32_bf16(ap, v3, Oacc[3], 0, 0, 0);
    pT0 = pT2;
    __syncthreads();   // drains this iter's DMA + publishes staging
  }

  // ---- write unnormalized piece results ----
  float lsum[4];
  for (int r = 0; r < 4; ++r) {
    float s = l_lane[r];
    for (int o = 1; o < 16; o <<= 1) s += __shfl_xor(s, o);
    lsum[r] = s;
  }
  float* Op = piece ? O1 : O0;
  float* Lp = piece ? L1 : L0;
  for (int tn = 0; tn < 4; ++tn)
    for (int r = 0; r < 4; ++r) {
      int ii = quad * 4 + r;
      Op[((size_t)(i0w + ii) * BB + b) * DD + n * HDIM + tn * 16 + L15] = Oacc[tn][r];
    }
  if (L15 == 0)
    for (int r = 0; r < 4; ++r)
      Lp[(size_t)bh * TT + i0w + quad * 4 + r] = lsum[r];
}

// ---------------- merge attention pieces -> ctx bf16 ----------------
__global__ void txl_attn_merge(const float* __restrict__ O0, const float* __restrict__ O1,
                               const float* __restrict__ L0, const float* __restrict__ L1,
                               u16* __restrict__ ctx) {
  int o = blockIdx.x * 256 + threadIdx.x;   // 2,097,152
  if (o >= BB * TT * DD) return;
  int i = o >> 11, b = (o >> 9) & 3, e = o & 511, n = e >> 6;
  size_t li = (size_t)(b * HH + n) * TT + i;
  float l = L0[li] + L1[li];
  ctx[o] = f2b((O0[o] + O1[o]) / l);
}

// ---------------- LayerNorm over nparts f32 partials (+ fused mems/final stores) ----
__global__ __launch_bounds__(256) void txl_ln(
    const float* __restrict__ gout, int nparts, const u16* __restrict__ bias,
    const float* __restrict__ resid, const u16* __restrict__ gam, const u16* __restrict__ bet,
    u16* __restrict__ ybf, float* __restrict__ yf,
    void* __restrict__ outv, int off, void* __restrict__ finalv,
    const int* __restrict__ flag) {
  const int row = blockIdx.x, tid = threadIdx.x;
  const int lane = tid & 63, wave = tid >> 6;
  __shared__ float red[4];
  size_t base = (size_t)row * DD;
  float x0 = resid[base + tid];
  float x1 = resid[base + tid + 256];
  for (int p = 0; p < nparts; ++p) {          // split-K partial sum (scalar accum)
    x0 += gout[(size_t)p * 2097152 + base + tid];
    x1 += gout[(size_t)p * 2097152 + base + tid + 256];
  }
  if (bias) { x0 += b2f(bias[tid]); x1 += b2f(bias[tid + 256]); }
  float s = x0 + x1;
  for (int o = 32; o; o >>= 1) s += __shfl_xor(s, o);
  if (lane == 0) red[wave] = s;
  __syncthreads();
  float mean = (red[0] + red[1] + red[2] + red[3]) * (1.f / DD);
  __syncthreads();
  float d0 = x0 - mean, d1 = x1 - mean;
  float q = d0 * d0 + d1 * d1;
  for (int o = 32; o; o >>= 1) q += __shfl_xor(q, o);
  if (lane == 0) red[wave] = q;
  __syncthreads();
  float var = (red[0] + red[1] + red[2] + red[3]) * (1.f / DD);
  float rstd = rsqrtf(var + LN_EPS);
  float y0 = d0 * rstd * b2f(gam[tid]) + b2f(bet[tid]);
  float y1 = d1 * rstd * b2f(gam[tid + 256]) + b2f(bet[tid + 256]);
  u16 u0 = f2b(y0), u1 = f2b(y1);
  ybf[base + tid] = u0;
  ybf[base + tid + 256] = u1;
  yf[base + tid] = y0;
  yf[base + tid + 256] = y1;
  if (outv && row >= 2048) {   // fused new_mems[l+1] store (rows t>=512)
    size_t mo = (size_t)off + (size_t)(row - 2048) * DD;
    if (*flag) {
      ((float*)outv)[mo + tid] = y0;
      ((float*)outv)[mo + tid + 256] = y1;
    } else {
      ((u16*)outv)[mo + tid] = u0;
      ((u16*)outv)[mo + tid + 256] = u1;
    }
  }
  if (finalv) {                // fused final = swapaxes(out,0,1) (last layer only)
    int t = row >> 2, b = row & 3;
    size_t fo = ((size_t)b * TT + t) * DD;
    if (*flag) {
      ((float*)finalv)[fo + tid] = y0;
      ((float*)finalv)[fo + tid + 256] = y1;
    } else {
      ((u16*)finalv)[fo + tid] = u0;
      ((u16*)finalv)[fo + tid + 256] = u1;
    }
  }
}

// ---------------- workspace layout (bytes; R3-proven 138MB footprint) ----------------
// (Harness poisons a fixed 256 MiB workspace regardless of WS_TOTAL — R8 trace —
// so no benefit to compaction; layout kept stable.)
constexpr size_t WS_CUR_F  = 0;
constexpr size_t WS_RB2    = 8388608;     // 2x 1,572,864 rb (layer 0,1)
constexpr size_t WS_CBUF   = 14680064;    // 37,748,736 (f32 split-K parts / bf16 qkv C / attn pieces)
constexpr size_t WS_QU     = 52428800;
constexpr size_t WS_QV     = 56623104;
constexpr size_t WS_K      = 60817408;
constexpr size_t WS_VT     = 67108864;
constexpr size_t WS_R      = 73400320;    // unused (kept for layout stability)
constexpr size_t WS_PE     = 74973184;
constexpr size_t WS_CTX    = 76546048;
constexpr size_t WS_HBF    = 80740352;
constexpr size_t WS_HF     = 84934656;
constexpr size_t WS_FF1    = 93323264;
constexpr size_t WS_CURBF  = 110100480;
constexpr size_t WS_CIN    = 114294784;   // bf16 [12,068,864] = 24,137,728 B
constexpr size_t WS_FLAG   = 138432512;   // int
constexpr size_t WS_TOTAL  = 138432576;
// attn piece buffers alias the (dead-at-that-point) Cbuf region:
constexpr size_t WS_OB0 = WS_CBUF;              // 8,388,608
constexpr size_t WS_OB1 = WS_CBUF + 8388608;    // 8,388,608
constexpr size_t WS_LB0 = WS_CBUF + 16777216;   // 131,072
constexpr size_t WS_LB1 = WS_CBUF + 16908288;   // 131,072

extern "C" void kernel_launch(void* const* d_in, const int* in_sizes, int n_in,
                              void* d_out, int out_size, void* d_ws, size_t ws_size,
                              hipStream_t stream) {
  (void)in_sizes; (void)n_in;

  if (ws_size < WS_TOTAL) {  // fail cleanly
    hipMemsetAsync(d_out, 0, (size_t)out_size * 2, stream);
    return;
  }
  char* ws = (char*)d_ws;
  float* cur_f  = (float*)(ws + WS_CUR_F);
  u16*   rb2    = (u16*)(ws + WS_RB2);
  float* Cbuf   = (float*)(ws + WS_CBUF);
  u16*   Cqkv   = (u16*)(ws + WS_CBUF);     // bf16 qkv C aliases Cbuf
  float* Ob0    = (float*)(ws + WS_OB0);
  float* Ob1    = (float*)(ws + WS_OB1);
  float* Lb0    = (float*)(ws + WS_LB0);
  float* Lb1    = (float*)(ws + WS_LB1);
  u16*   qu     = (u16*)(ws + WS_QU);
  u16*   qv     = (u16*)(ws + WS_QV);
  u16*   kb     = (u16*)(ws + WS_K);
  u16*   vT     = (u16*)(ws + WS_VT);
  u16*   pe     = (u16*)(ws + WS_PE);
  u16*   ctx    = (u16*)(ws + WS_CTX);
  u16*   hbf    = (u16*)(ws + WS_HBF);
  float* hf     = (float*)(ws + WS_HF);
  u16*   ff1    = (u16*)(ws + WS_FF1);
  u16*   cur_bf = (u16*)(ws + WS_CURBF);
  u16*   cin    = (u16*)(ws + WS_CIN);
  int*   flag   = (int*)(ws + WS_FLAG);

  // dtype probe + canonicalize all float inputs to bf16 (+ fused pe)
  txl_probe<<<1, 64, 0, stream>>>((const u16*)d_in[0], flag);
  txl_convert<<<48680, 256, 0, stream>>>(
      d_in[0], d_in[3], d_in[4], d_in[5], d_in[6], d_in[7], d_in[8],
      d_in[9], d_in[10], d_in[11], d_in[12], d_in[13], d_in[14], d_in[15], d_in[16],
      cin, pe, flag);

  const u16* ub = cin + OFF_UB;
  const u16* vb = cin + OFF_VB;

  // r = pe @ pos_w^T for BOTH layers (layer-independent; z = layer)
  txl_gemm_r<<<dim3(12, 4, 2), 256, 0, stream>>>(
      pe, cin + OFF_POSW, rb2, 1536, 512, 512);
  txl_transpose_in<<<8192, 256, 0, stream>>>(cin + OFF_X, cur_bf, cur_f, d_out, flag);

  for (int l = 0; l < NLAYER; ++l) {
    // qkv: A-split (rows<2048 from mems[l], rest from cur_bf); bf16 compact C;
    // dead q-blocks (mem rows) early-exit
    txl_gemm4<2><<<dim3(48, 12, 1), 256, 0, stream>>>(
        cin + OFF_MEMS + (size_t)l * 1048576, cur_bf, 2048,
        cin + OFF_QKVW + (size_t)l * 786432, nullptr, Cqkv, nullptr, 6144, 1536, 512, 512);
    // fused V-transpose + q/k scatter (bf16 C; q pre-scaled by 1/sqrt(512))
    txl_qkv_post<<<25344, 256, 0, stream>>>(Cqkv, ub, vb, qu, qv, kb, vT);
    // attention: 2 balanced K-pieces per supertile + merge (piece bufs alias Cbuf)
    txl_attn9<<<1024, 256, 0, stream>>>(qu, qv, kb, vT, rb2 + (size_t)l * 786432,
                                        Ob0, Ob1, Lb0, Lb1);
    txl_attn_merge<<<8192, 256, 0, stream>>>(Ob0, Ob1, Lb0, Lb1, ctx);
    // out projection: split-K S=2 (2 f32 partials, summed in ln1)
    txl_gemm4<0><<<dim3(32, 4, 2), 256, 0, stream>>>(
        ctx, ctx, 1 << 30, cin + OFF_OUTW + (size_t)l * 262144, Cbuf,
        nullptr, nullptr, 4096, 512, 512, 256);
    txl_ln<<<4096, 256, 0, stream>>>(Cbuf, 2, nullptr, cur_f,
                                     cin + OFF_LN1S + l * 512, cin + OFF_LN1B + l * 512,
                                     hbf, hf, nullptr, 0, nullptr, flag);
    // FFN1 (S=1, fused bias+relu)
    txl_gemm4<1><<<dim3(32, 16, 1), 256, 0, stream>>>(
        hbf, hbf, 1 << 30, cin + OFF_L1W + (size_t)l * 1048576, nullptr,
        ff1, cin + OFF_L1B + l * 2048, 4096, 2048, 512, 512);
    // FFN2: split-K S=4 (4 f32 partials, summed in ln2)
    txl_gemm4<0><<<dim3(32, 4, 4), 256, 0, stream>>>(
        ff1, ff1, 1 << 30, cin + OFF_L2W + (size_t)l * 1048576, Cbuf,
        nullptr, nullptr, 4096, 512, 2048, 512);
    // ln2 with fused new_mems[l+1] store (+ fused final transpose-store on last layer)
    txl_ln<<<4096, 256, 0, stream>>>(Cbuf, 4, cin + OFF_L2B + l * 512, hf,
                                     cin + OFF_LN2S + l * 512, cin + OFF_LN2B + l * 512,
                                     cur_bf, cur_f, d_out, 2097152 + (l + 1) * 1048576,
                                     (l == NLAYER - 1) ? d_out : nullptr, flag);
  }
}

// Round 12
// 439.516 us; speedup vs baseline: 2.0115x; 1.0094x over previous
//
#include <hip/hip_runtime.h>

// ---------------- problem constants ----------------
constexpr int BB = 4, TT = 1024, DD = 512, HH = 8, HDIM = 64;
constexpr int FFD = 2048, NLAYER = 2, MM = 512, SS = 1536;
constexpr float LN_EPS = 1e-5f;
// q pre-scale folds softmax scale AND log2(e) so attention uses exp2 directly:
// SCALE2 = (1/sqrt(512)) * log2(e)
constexpr float SCALE2 = 0.06376281516217733f;

typedef unsigned short u16;
typedef __attribute__((ext_vector_type(8))) short bf16x8;
typedef __attribute__((ext_vector_type(4))) float f32x4;

__device__ __forceinline__ float b2f(u16 u) {
  union { unsigned int i; float f; } c; c.i = ((unsigned int)u) << 16; return c.f;
}
__device__ __forceinline__ u16 f2b(float f) {
  unsigned int x = __builtin_bit_cast(unsigned int, f);
  x += 0x7fffu + ((x >> 16) & 1u);   // RNE (finite values only)
  return (u16)(x >> 16);
}
// device 2^x (v_exp_f32). NOTE: __exp2f collides with a glibc math.h macro on
// this toolchain (R11 compile failure); the amdgcn builtin is the safe spelling.
__device__ __forceinline__ float dexp2(float x) { return __builtin_amdgcn_exp2f(x); }

// async global->LDS DMA, 16B per lane. LDS dest = uniform base + lane*16.
__device__ __forceinline__ void dma16(const u16* g, u16* l) {
  __builtin_amdgcn_global_load_lds(
      (const __attribute__((address_space(1))) unsigned int*)g,
      (__attribute__((address_space(3))) unsigned int*)l, 16, 0, 0);
}

// ---------------- canonical input buffer offsets (elements) ----------------
constexpr int OFF_X    = 0;          // 2,097,152 (region now unused; x read raw)
constexpr int OFF_MEMS = 2097152;    // 3,145,728
constexpr int OFF_UB   = 5242880;    // 512
constexpr int OFF_VB   = 5243392;    // 512
constexpr int OFF_QKVW = 5243904;    // 1,572,864 (786,432 per layer)
constexpr int OFF_POSW = 6816768;    // 524,288 (262,144 per layer)
constexpr int OFF_OUTW = 7341056;    // 524,288
constexpr int OFF_L1W  = 7865344;    // 2,097,152 (1,048,576 per layer)
constexpr int OFF_L1B  = 9962496;    // 4,096 (2,048 per layer)
constexpr int OFF_L2W  = 9966592;    // 2,097,152
constexpr int OFF_L2B  = 12063744;   // 1,024 (512 per layer)
constexpr int OFF_LN1S = 12064768;
constexpr int OFF_LN1B = 12065792;
constexpr int OFF_LN2S = 12066816;
constexpr int OFF_LN2B = 12067840;
constexpr int TOT_IN   = 12068864;
constexpr int CONV_CNT = TOT_IN - OFF_MEMS;  // 9,971,712 (x dropped from convert)
constexpr int PE_CNT   = SS * 256;           // 393,216 pe work items

// ---------------- dtype probe ----------------
__global__ void txl_probe(const u16* __restrict__ xr, int* __restrict__ flag) {
  int lane = threadIdx.x;   // 64 threads
  int cnt = 0;
  for (int k = 0; k < 8; ++k) {
    u16 u = xr[lane * 8 + k];
    int e = (u >> 7) & 0xFF;
    if (e >= 0xC0) ++cnt;
  }
  for (int o = 32; o; o >>= 1) cnt += __shfl_xor(cnt, o);
  if (lane == 0) *flag = (cnt >= 32) ? 1 : 0;   // 1 => inputs are f32
}

// ---------------- convert non-x float inputs to bf16 + fused pe generation ----------------
__global__ __launch_bounds__(256) void txl_convert(
    const void* mems, const void* ub, const void* vb,
    const void* qkvw, const void* posw, const void* outw,
    const void* l1w, const void* l1b, const void* l2w, const void* l2b,
    const void* ln1s, const void* ln1b, const void* ln2s, const void* ln2b,
    u16* __restrict__ dst, u16* __restrict__ pe, const int* __restrict__ flag) {
  int idx = blockIdx.x * 256 + threadIdx.x;
  if (idx >= CONV_CNT) {                     // fused sinusoid pe (positions S-1..0)
    int idx2 = idx - CONV_CNT;
    if (idx2 >= PE_CNT) return;
    int p = idx2 >> 8, m = idx2 & 255;
    float posf = (float)(SS - 1 - p);
    float div = expf((float)(2 * m) * (-9.210340371976184f / 512.0f));
    float a = posf * div;
    pe[(size_t)p * DD + 2 * m] = f2b(sinf(a));
    pe[(size_t)p * DD + 2 * m + 1] = f2b(cosf(a));
    return;
  }
  const int gidx = idx + OFF_MEMS;
  const void* p; int local;
  if      (gidx < OFF_UB)   { p = mems; local = gidx - OFF_MEMS; }
  else if (gidx < OFF_VB)   { p = ub;   local = gidx - OFF_UB; }
  else if (gidx < OFF_QKVW) { p = vb;   local = gidx - OFF_VB; }
  else if (gidx < OFF_POSW) { p = qkvw; local = gidx - OFF_QKVW; }
  else if (gidx < OFF_OUTW) { p = posw; local = gidx - OFF_POSW; }
  else if (gidx < OFF_L1W)  { p = outw; local = gidx - OFF_OUTW; }
  else if (gidx < OFF_L1B)  { p = l1w;  local = gidx - OFF_L1W; }
  else if (gidx < OFF_L2W)  { p = l1b;  local = gidx - OFF_L1B; }
  else if (gidx < OFF_L2B)  { p = l2w;  local = gidx - OFF_L2W; }
  else if (gidx < OFF_LN1S) { p = l2b;  local = gidx - OFF_L2B; }
  else if (gidx < OFF_LN1B) { p = ln1s; local = gidx - OFF_LN1S; }
  else if (gidx < OFF_LN2S) { p = ln1b; local = gidx - OFF_LN1B; }
  else if (gidx < OFF_LN2B) { p = ln2s; local = gidx - OFF_LN2S; }
  else                      { p = ln2b; local = gidx - OFF_LN2B; }
  dst[gidx] = (*flag) ? f2b(((const float*)p)[local]) : ((const u16*)p)[local];
}

// ---------------- GEMM v5: split-K + dbuf DMA staging + A-split prologue ----------------
// C = A[M,K] * B[N,K]^T over K-range [z*KS,(z+1)*KS); 128x128 tile, BK=32.
// A-split: tile rows < msplit read from A, else A2 (block-uniform pointer select).
// EPI=0: f32 partial C at z*M*N.  EPI=1: fused bias+relu -> bf16 (S=1 only).
// EPI=2: plain bf16 C (qkv) + dead-block early-exit.
// R4 lesson (rule #20): keep EPILOGUES simple so tm/tn fully unroll.
template <int EPI>
__global__ __launch_bounds__(256) void txl_gemm4(const u16* __restrict__ A,
                                                 const u16* __restrict__ A2, int msplit,
                                                 const u16* __restrict__ B,
                                                 float* __restrict__ C,
                                                 u16* __restrict__ Obf,
                                                 const u16* __restrict__ bias,
                                                 int M, int N, int K, int KS) {
  const int m0 = blockIdx.x * 128, n0 = blockIdx.y * 128;
  if (EPI == 2 && n0 < 512 && m0 < 2048) return;   // q-output for mem rows: unused
  __shared__ __align__(16) u16 As[2][128 * 32];
  __shared__ __align__(16) u16 Bs[2][128 * 32];
  const int tid = threadIdx.x;
  const int wave = tid >> 6, lane = tid & 63;
  const int wm = (wave & 1) * 64, wn = (wave >> 1) * 64;
  const int kbeg = blockIdx.z * KS, kend = kbeg + KS;
  const int L15 = lane & 15, quad = lane >> 4;
  const u16* Abase = (m0 < msplit) ? (A + (size_t)m0 * K) : (A2 + (size_t)(m0 - msplit) * K);

  auto stage = [&](int k0, int buf) {
    for (int c = 0; c < 2; ++c) {
      int segBase = c * 256 + wave * 64;
      int seg = segBase + lane;
      int row = seg >> 2, q = seg & 3;
      dma16(&Abase[(size_t)row * K + k0 + q * 8], &As[buf][segBase * 8]);
      dma16(&B[(size_t)(n0 + row) * K + k0 + q * 8], &Bs[buf][segBase * 8]);
    }
  };

  f32x4 acc[4][4] = {};
  stage(kbeg, 0);
  __syncthreads();                       // drain prologue DMA
  int buf = 0;
  for (int k0 = kbeg; k0 < kend; k0 += 32) {
    if (k0 + 32 < kend) stage(k0 + 32, buf ^ 1);   // prefetch next tile
    bf16x8 af[4], bfr[4];
    for (int t = 0; t < 4; ++t)
      af[t] = *reinterpret_cast<const bf16x8*>(&As[buf][(wm + t * 16 + L15) * 32 + quad * 8]);
    for (int t = 0; t < 4; ++t)
      bfr[t] = *reinterpret_cast<const bf16x8*>(&Bs[buf][(wn + t * 16 + L15) * 32 + quad * 8]);
    for (int tm = 0; tm < 4; ++tm)
      for (int tn = 0; tn < 4; ++tn)
        acc[tm][tn] = __builtin_amdgcn_mfma_f32_16x16x32_bf16(af[tm], bfr[tn], acc[tm][tn], 0, 0, 0);
    buf ^= 1;
    __syncthreads();                     // drains prefetch DMA + guards reuse
  }
  float* Cz = C + (size_t)blockIdx.z * ((size_t)M * N);
#pragma unroll
  for (int tm = 0; tm < 4; ++tm)
#pragma unroll
    for (int tn = 0; tn < 4; ++tn) {
      int col = n0 + wn + tn * 16 + L15;
#pragma unroll
      for (int r = 0; r < 4; ++r) {
        int row = m0 + wm + tm * 16 + quad * 4 + r;
        if (EPI == 0) {
          Cz[(size_t)row * N + col] = acc[tm][tn][r];
        } else if (EPI == 1) {
          float v = acc[tm][tn][r] + b2f(bias[col]);
          Obf[(size_t)row * N + col] = f2b(fmaxf(v, 0.f));
        } else {
          Obf[(size_t)row * N + col] = f2b(acc[tm][tn][r]);
        }
      }
    }
}

// ---------------- r GEMM, both layers batched (z = layer), fused scatter epilogue ----
__global__ __launch_bounds__(256) void txl_gemm_r(const u16* __restrict__ A,
                                                  const u16* __restrict__ B,
                                                  u16* __restrict__ rb,
                                                  int M, int N, int K) {
  __shared__ __align__(16) u16 As[2][128 * 32];
  __shared__ __align__(16) u16 Bs[2][128 * 32];
  const int tid = threadIdx.x;
  const int wave = tid >> 6, lane = tid & 63;
  const int wm = (wave & 1) * 64, wn = (wave >> 1) * 64;
  const int m0 = blockIdx.x * 128, n0 = blockIdx.y * 128;
  const int L15 = lane & 15, quad = lane >> 4;
  const u16* Bz = B + (size_t)blockIdx.z * 262144;
  u16* rbz = rb + (size_t)blockIdx.z * 786432;

  auto stage = [&](int k0, int buf) {
    for (int c = 0; c < 2; ++c) {
      int segBase = c * 256 + wave * 64;
      int seg = segBase + lane;
      int row = seg >> 2, q = seg & 3;
      dma16(&A[(size_t)(m0 + row) * K + k0 + q * 8], &As[buf][segBase * 8]);
      dma16(&Bz[(size_t)(n0 + row) * K + k0 + q * 8], &Bs[buf][segBase * 8]);
    }
  };

  f32x4 acc[4][4] = {};
  stage(0, 0);
  __syncthreads();
  int buf = 0;
  for (int k0 = 0; k0 < K; k0 += 32) {
    if (k0 + 32 < K) stage(k0 + 32, buf ^ 1);
    bf16x8 af[4], bfr[4];
    for (int t = 0; t < 4; ++t)
      af[t] = *reinterpret_cast<const bf16x8*>(&As[buf][(wm + t * 16 + L15) * 32 + quad * 8]);
    for (int t = 0; t < 4; ++t)
      bfr[t] = *reinterpret_cast<const bf16x8*>(&Bs[buf][(wn + t * 16 + L15) * 32 + quad * 8]);
    for (int tm = 0; tm < 4; ++tm)
      for (int tn = 0; tn < 4; ++tn)
        acc[tm][tn] = __builtin_amdgcn_mfma_f32_16x16x32_bf16(af[tm], bfr[tn], acc[tm][tn], 0, 0, 0);
    buf ^= 1;
    __syncthreads();
  }
#pragma unroll
  for (int tm = 0; tm < 4; ++tm)
#pragma unroll
    for (int tn = 0; tn < 4; ++tn) {
      int col = n0 + wn + tn * 16 + L15;
      int n = col >> 6, d = col & 63;
#pragma unroll
      for (int r = 0; r < 4; ++r) {
        int row = m0 + wm + tm * 16 + quad * 4 + r;
        rbz[((size_t)n * SS + row) * HDIM + d] = f2b(acc[tm][tn][r]);
      }
    }
}

// ---------------- [B,T,D] -> [T,B,D] from RAW input + fused new_mems[0] store ----------
__global__ void txl_transpose_in(const void* __restrict__ x, u16* __restrict__ cur_bf,
                                 float* __restrict__ cur_f, void* __restrict__ outv,
                                 const int* __restrict__ flag) {
  int idx = blockIdx.x * 256 + threadIdx.x;    // BB*TT*DD
  if (idx >= BB * TT * DD) return;
  int b = idx >> 19, t = (idx >> 9) & 1023, d = idx & 511;
  u16 v;
  if (*flag) v = f2b(((const float*)x)[idx]);
  else       v = ((const u16*)x)[idx];
  size_t o = ((size_t)t * BB + b) * DD + d;
  cur_bf[o] = v; cur_f[o] = b2f(v);
  if (t >= 512) {                               // new_mems[0] = xs rows 512..1023
    size_t mo = 2097152 + (o - 1048576);
    if (*flag) ((float*)outv)[mo] = b2f(v);
    else       ((u16*)outv)[mo] = v;
  }
}

// ---------------- fused qkv post-pass (bf16 C): V transpose + q/k scatter ----------------
// q/qv PRE-SCALED by SCALE2 = (1/sqrt(512))*log2(e) so attention uses exp2 directly.
__global__ __launch_bounds__(256) void txl_qkv_post(
    const u16* __restrict__ C, const u16* __restrict__ ub, const u16* __restrict__ vb,
    u16* __restrict__ qu, u16* __restrict__ qv, u16* __restrict__ kb,
    u16* __restrict__ vT) {
  __shared__ u16 t[64][68];
  const int bx = blockIdx.x;
  const int tid = threadIdx.x;
  if (bx < 768) {                      // ---- V transpose via LDS ----
    int sb = bx >> 5;                  // 0..23
    int bn = bx & 31;
    int n = bn & 7, b = bn >> 3;
    int s0 = sb * 64;
    {
      int d = tid & 63, sr = tid >> 6;
      for (int i = 0; i < 16; ++i) {
        int s = s0 + sr + i * 4;
        t[sr + i * 4][d] = C[(size_t)(s * 4 + b) * 1536 + 1024 + n * 64 + d];
      }
    }
    __syncthreads();
    {
      int s = tid & 63, dr = tid >> 6;
      u16* dst = vT + (size_t)(b * HH + n) * HDIM * SS;
      for (int i = 0; i < 16; ++i) {
        int d2 = dr + i * 4;
        dst[(size_t)d2 * SS + s0 + s] = t[s][d2];
      }
    }
    return;
  }
  // ---- q/k scatter over e in [0,1024) ----
  int idx = (bx - 768) * 256 + tid;    // [0, SS*BB*1024)
  int row = idx >> 10, e = idx & 1023;
  int s = row >> 2, b = row & 3;
  u16 cv = C[(size_t)row * 1536 + e];
  if (e < 512) {
    if (s >= MM) {
      int i = s - MM, n = e >> 6, d = e & 63;
      size_t o = ((size_t)(b * HH + n) * TT + i) * HDIM + d;
      float val = b2f(cv);
      qu[o] = f2b((val + b2f(ub[e])) * SCALE2);
      qv[o] = f2b((val + b2f(vb[e])) * SCALE2);
    }
  } else {
    int e2 = e - 512, n = e2 >> 6, d = e2 & 63;
    kb[((size_t)(b * HH + n) * SS + s) * HDIM + d] = cv;
  }
}

// ---------------- flash attention v10c: balanced K-split + exp2 softmax ----------------
// 1024 blocks x 256 threads (4 waves), 4 blocks/CU; every CU carries exactly 66
// chunks (LPT pairing). R10 analysis: dependency-chain-bound (MfmaUtil 11% +
// VALU 35%); 2-chunk unroll rejected (+24KB LDS -> 2-3 blocks/CU); r-ring
// cannot shrink below 8 (live window 7). exp2 via pre-scaled q saves the
// hidden log2e multiply in __expf.
__global__ __launch_bounds__(256) void txl_attn9(
    const u16* __restrict__ qu, const u16* __restrict__ qv, const u16* __restrict__ kbuf,
    const u16* __restrict__ vT, const u16* __restrict__ rbuf,
    float* __restrict__ O0, float* __restrict__ O1,
    float* __restrict__ L0, float* __restrict__ L1) {
  __shared__ __align__(16) u16 Kb[2][2048];   // chunk K: 32 rows x 64
  __shared__ __align__(16) u16 Vb[2][2048];   // chunk V^T: 64 d-rows x 32
  __shared__ __align__(16) u16 Rr[8][1024];   // r ring: 8 slabs of 16 rows x 64
  __shared__ __align__(16) u16 ps4[4][640];   // per-wave P staging [16][40]

  const int bx = blockIdx.x;
  const int n = bx & 7;                 // XCD class = head
  const int rest = bx >> 3;
  const int b = rest & 3;
  const int rest2 = rest >> 2;          // 0..31
  const int piece = rest2 >> 4;
  const int st = piece ? (15 - (rest2 & 15)) : (rest2 & 15);   // LPT pairing
  const int i0b = st * 64;
  const int g0 = 63 - (i0b >> 4);
  const int jcEnd = 18 + 2 * st;        // chunks covering j <= i0b+63+512
  const int half = 9 + st;
  const int jcBeg = piece ? half : 0;
  const int jcLim = piece ? jcEnd : half;
  const int gB = g0 + 2 * jcBeg;

  const int tid = threadIdx.x, w = tid >> 6, lane = tid & 63;
  const int L15 = lane & 15, quad = lane >> 4;
  const int i0w = i0b + 16 * w;
  const int bh = b * HH + n;

  const u16* kB = kbuf + (size_t)bh * SS * HDIM;
  const u16* rB = rbuf + (size_t)n * SS * HDIM;
  const u16* vB = vT + (size_t)bh * HDIM * SS;

  // Q fragments (regular loads; drained by prologue barrier)
  const u16* quB = qu + ((size_t)bh * TT + i0w) * HDIM;
  const u16* qvB = qv + ((size_t)bh * TT + i0w) * HDIM;
  bf16x8 aqu[2], aqv[2];
  for (int c = 0; c < 2; ++c) {
    aqu[c] = *reinterpret_cast<const bf16x8*>(&quB[(size_t)L15 * HDIM + c * 32 + quad * 8]);
    aqv[c] = *reinterpret_cast<const bf16x8*>(&qvB[(size_t)L15 * HDIM + c * 32 + quad * 8]);
  }

  u16* ps = &ps4[w][0];

  auto stageK = [&](int jc) {
    const u16* src = kB + (size_t)(jc * 32 + (lane & 31)) * HDIM + (2 * w + (lane >> 5)) * 8;
    dma16(src, &Kb[jc & 1][512 * w]);
  };
  auto stageV = [&](int jc) {
    const u16* src = vB + (size_t)lane * SS + jc * 32 + 8 * w;
    dma16(src, &Vb[jc & 1][512 * w]);
  };
  auto stageRslab = [&](int slab) {
    int rrow = slab * 16 + (lane & 15);
    rrow = (rrow > SS - 1) ? (SS - 1) : rrow;   // clamped rows only feed masked lanes
    const u16* s0 = rB + (size_t)rrow * HDIM + (lane >> 4) * 8;
    dma16(s0, &Rr[slab & 7][0]);
    dma16(s0 + 32, &Rr[slab & 7][512]);
  };
  auto rfrag = [&](int slab, int h) {
    return *reinterpret_cast<const bf16x8*>(&Rr[slab & 7][((quad + 4 * h) * 16 + L15) * 8]);
  };

  // ---- prologue: stage chunk jcBeg + r window [gB-3, gB+2] ----
  stageK(jcBeg); stageV(jcBeg);
  stageRslab(gB - 3 + w);
  if (w < 2) stageRslab(gB + 1 + w);
  __syncthreads();

  f32x4 pT0 = {};
  pT0 = __builtin_amdgcn_mfma_f32_16x16x32_bf16(aqv[0], rfrag(gB - w, 0), pT0, 0, 0, 0);
  pT0 = __builtin_amdgcn_mfma_f32_16x16x32_bf16(aqv[1], rfrag(gB - w, 1), pT0, 0, 0, 0);

  float l_lane[4] = {0.f, 0.f, 0.f, 0.f};
  f32x4 Oacc[4] = {};

  for (int jc = jcBeg; jc < jcLim; ++jc) {
    if (jc + 1 < jcLim) {               // issue next-chunk DMA (disjoint LDS regions)
      stageK(jc + 1); stageV(jc + 1);
      if (w < 2) stageRslab(g0 + 3 + 2 * jc + w);
    }
    const int hslot = jc & 1, j0 = jc * 32;
    bf16x8 k00 = *reinterpret_cast<const bf16x8*>(&Kb[hslot][((quad) * 32 + L15) * 8]);
    bf16x8 k01 = *reinterpret_cast<const bf16x8*>(&Kb[hslot][((quad + 4) * 32 + L15) * 8]);
    bf16x8 k10 = *reinterpret_cast<const bf16x8*>(&Kb[hslot][((quad) * 32 + 16 + L15) * 8]);
    bf16x8 k11 = *reinterpret_cast<const bf16x8*>(&Kb[hslot][((quad + 4) * 32 + 16 + L15) * 8]);
    f32x4 s0v = {}, s1v = {};
    s0v = __builtin_amdgcn_mfma_f32_16x16x32_bf16(aqu[0], k00, s0v, 0, 0, 0);
    s0v = __builtin_amdgcn_mfma_f32_16x16x32_bf16(aqu[1], k01, s0v, 0, 0, 0);
    s1v = __builtin_amdgcn_mfma_f32_16x16x32_bf16(aqu[0], k10, s1v, 0, 0, 0);
    s1v = __builtin_amdgcn_mfma_f32_16x16x32_bf16(aqu[1], k11, s1v, 0, 0, 0);
    const int sl1 = g0 - w + 2 * jc + 1;
    f32x4 pT1 = {}, pT2 = {};
    pT1 = __builtin_amdgcn_mfma_f32_16x16x32_bf16(aqv[0], rfrag(sl1, 0), pT1, 0, 0, 0);
    pT1 = __builtin_amdgcn_mfma_f32_16x16x32_bf16(aqv[1], rfrag(sl1, 1), pT1, 0, 0, 0);
    pT2 = __builtin_amdgcn_mfma_f32_16x16x32_bf16(aqv[0], rfrag(sl1 + 1, 0), pT2, 0, 0, 0);
    pT2 = __builtin_amdgcn_mfma_f32_16x16x32_bf16(aqv[1], rfrag(sl1 + 1, 1), pT2, 0, 0, 0);
    for (int r = 0; r < 4; ++r) {
      int ii = quad * 4 + r;
      int i = i0w + ii;
      int c = 15 + L15 - ii;                       // [0,30]
      int srcLane = (quad << 4) | (c & 15);
      float a0 = __shfl(pT0[r], srcLane);
      float a1 = __shfl(pT1[r], srcLane);
      float b1v = __shfl(pT2[r], srcLane);
      float sv0 = s0v[r] + ((c < 16) ? a0 : a1);
      float sv1 = s1v[r] + ((c < 16) ? a1 : b1v);
      sv0 = (j0 + L15 <= i + MM) ? sv0 : -3e38f;
      sv1 = (j0 + 16 + L15 <= i + MM) ? sv1 : -3e38f;
      float e0 = dexp2(sv0);                       // q pre-scaled incl log2e
      float e1 = dexp2(sv1);
      l_lane[r] += e0 + e1;
      int row = ii * 40;
      ps[row + L15] = f2b(e0);
      ps[row + 16 + L15] = f2b(e1);
    }
    bf16x8 ap = *reinterpret_cast<const bf16x8*>(&ps[L15 * 40 + quad * 8]);
    bf16x8 v0 = *reinterpret_cast<const bf16x8*>(&Vb[hslot][(quad * 64 + L15) * 8]);
    bf16x8 v1 = *reinterpret_cast<const bf16x8*>(&Vb[hslot][(quad * 64 + 16 + L15) * 8]);
    bf16x8 v2 = *reinterpret_cast<const bf16x8*>(&Vb[hslot][(quad * 64 + 32 + L15) * 8]);
    bf16x8 v3 = *reinterpret_cast<const bf16x8*>(&Vb[hslot][(quad * 64 + 48 + L15) * 8]);
    Oacc[0] = __builtin_amdgcn_mfma_f32_16x16x32_bf16(ap, v0, Oacc[0], 0, 0, 0);
    Oacc[1] = __builtin_amdgcn_mfma_f32_16x16x32_bf16(ap, v1, Oacc[1], 0, 0, 0);
    Oacc[2] = __builtin_amdgcn_mfma_f32_16x16x32_bf16(ap, v2, Oacc[2], 0, 0, 0);
    Oacc[3] = __builtin_amdgcn_mfma_f32_16x16x32_bf16(ap, v3, Oacc[3], 0, 0, 0);
    pT0 = pT2;
    __syncthreads();   // drains this iter's DMA + publishes staging
  }

  // ---- write unnormalized piece results ----
  float lsum[4];
  for (int r = 0; r < 4; ++r) {
    float s = l_lane[r];
    for (int o = 1; o < 16; o <<= 1) s += __shfl_xor(s, o);
    lsum[r] = s;
  }
  float* Op = piece ? O1 : O0;
  float* Lp = piece ? L1 : L0;
  for (int tn = 0; tn < 4; ++tn)
    for (int r = 0; r < 4; ++r) {
      int ii = quad * 4 + r;
      Op[((size_t)(i0w + ii) * BB + b) * DD + n * HDIM + tn * 16 + L15] = Oacc[tn][r];
    }
  if (L15 == 0)
    for (int r = 0; r < 4; ++r)
      Lp[(size_t)bh * TT + i0w + quad * 4 + r] = lsum[r];
}

// ---------------- merge attention pieces -> ctx bf16 ----------------
__global__ void txl_attn_merge(const float* __restrict__ O0, const float* __restrict__ O1,
                               const float* __restrict__ L0, const float* __restrict__ L1,
                               u16* __restrict__ ctx) {
  int o = blockIdx.x * 256 + threadIdx.x;   // 2,097,152
  if (o >= BB * TT * DD) return;
  int i = o >> 11, b = (o >> 9) & 3, e = o & 511, n = e >> 6;
  size_t li = (size_t)(b * HH + n) * TT + i;
  float l = L0[li] + L1[li];
  ctx[o] = f2b((O0[o] + O1[o]) / l);
}

// ---------------- LayerNorm over nparts f32 partials (+ fused mems/final stores) ----
__global__ __launch_bounds__(256) void txl_ln(
    const float* __restrict__ gout, int nparts, const u16* __restrict__ bias,
    const float* __restrict__ resid, const u16* __restrict__ gam, const u16* __restrict__ bet,
    u16* __restrict__ ybf, float* __restrict__ yf,
    void* __restrict__ outv, int off, void* __restrict__ finalv,
    const int* __restrict__ flag) {
  const int row = blockIdx.x, tid = threadIdx.x;
  const int lane = tid & 63, wave = tid >> 6;
  __shared__ float red[4];
  size_t base = (size_t)row * DD;
  float x0 = resid[base + tid];
  float x1 = resid[base + tid + 256];
  for (int p = 0; p < nparts; ++p) {          // split-K partial sum (scalar accum)
    x0 += gout[(size_t)p * 2097152 + base + tid];
    x1 += gout[(size_t)p * 2097152 + base + tid + 256];
  }
  if (bias) { x0 += b2f(bias[tid]); x1 += b2f(bias[tid + 256]); }
  float s = x0 + x1;
  for (int o = 32; o; o >>= 1) s += __shfl_xor(s, o);
  if (lane == 0) red[wave] = s;
  __syncthreads();
  float mean = (red[0] + red[1] + red[2] + red[3]) * (1.f / DD);
  __syncthreads();
  float d0 = x0 - mean, d1 = x1 - mean;
  float q = d0 * d0 + d1 * d1;
  for (int o = 32; o; o >>= 1) q += __shfl_xor(q, o);
  if (lane == 0) red[wave] = q;
  __syncthreads();
  float var = (red[0] + red[1] + red[2] + red[3]) * (1.f / DD);
  float rstd = rsqrtf(var + LN_EPS);
  float y0 = d0 * rstd * b2f(gam[tid]) + b2f(bet[tid]);
  float y1 = d1 * rstd * b2f(gam[tid + 256]) + b2f(bet[tid + 256]);
  u16 u0 = f2b(y0), u1 = f2b(y1);
  ybf[base + tid] = u0;
  ybf[base + tid + 256] = u1;
  yf[base + tid] = y0;
  yf[base + tid + 256] = y1;
  if (outv && row >= 2048) {   // fused new_mems[l+1] store (rows t>=512)
    size_t mo = (size_t)off + (size_t)(row - 2048) * DD;
    if (*flag) {
      ((float*)outv)[mo + tid] = y0;
      ((float*)outv)[mo + tid + 256] = y1;
    } else {
      ((u16*)outv)[mo + tid] = u0;
      ((u16*)outv)[mo + tid + 256] = u1;
    }
  }
  if (finalv) {                // fused final = swapaxes(out,0,1) (last layer only)
    int t = row >> 2, b = row & 3;
    size_t fo = ((size_t)b * TT + t) * DD;
    if (*flag) {
      ((float*)finalv)[fo + tid] = y0;
      ((float*)finalv)[fo + tid + 256] = y1;
    } else {
      ((u16*)finalv)[fo + tid] = u0;
      ((u16*)finalv)[fo + tid + 256] = u1;
    }
  }
}

// ---------------- workspace layout (bytes; stable) ----------------
constexpr size_t WS_CUR_F  = 0;
constexpr size_t WS_RB2    = 8388608;     // 2x 1,572,864 rb (layer 0,1)
constexpr size_t WS_CBUF   = 14680064;    // f32 split-K parts / bf16 qkv C / attn pieces
constexpr size_t WS_QU     = 52428800;
constexpr size_t WS_QV     = 56623104;
constexpr size_t WS_K      = 60817408;
constexpr size_t WS_VT     = 67108864;
constexpr size_t WS_R      = 73400320;    // unused (layout stability)
constexpr size_t WS_PE     = 74973184;
constexpr size_t WS_CTX    = 76546048;
constexpr size_t WS_HBF    = 80740352;
constexpr size_t WS_HF     = 84934656;
constexpr size_t WS_FF1    = 93323264;
constexpr size_t WS_CURBF  = 110100480;
constexpr size_t WS_CIN    = 114294784;
constexpr size_t WS_FLAG   = 138432512;
constexpr size_t WS_TOTAL  = 138432576;
constexpr size_t WS_OB0 = WS_CBUF;
constexpr size_t WS_OB1 = WS_CBUF + 8388608;
constexpr size_t WS_LB0 = WS_CBUF + 16777216;
constexpr size_t WS_LB1 = WS_CBUF + 16908288;

extern "C" void kernel_launch(void* const* d_in, const int* in_sizes, int n_in,
                              void* d_out, int out_size, void* d_ws, size_t ws_size,
                              hipStream_t stream) {
  (void)in_sizes; (void)n_in;

  if (ws_size < WS_TOTAL) {  // fail cleanly
    (void)hipMemsetAsync(d_out, 0, (size_t)out_size * 2, stream);
    return;
  }
  char* ws = (char*)d_ws;
  float* cur_f  = (float*)(ws + WS_CUR_F);
  u16*   rb2    = (u16*)(ws + WS_RB2);
  float* Cbuf   = (float*)(ws + WS_CBUF);
  u16*   Cqkv   = (u16*)(ws + WS_CBUF);
  float* Ob0    = (float*)(ws + WS_OB0);
  float* Ob1    = (float*)(ws + WS_OB1);
  float* Lb0    = (float*)(ws + WS_LB0);
  float* Lb1    = (float*)(ws + WS_LB1);
  u16*   qu     = (u16*)(ws + WS_QU);
  u16*   qv     = (u16*)(ws + WS_QV);
  u16*   kb     = (u16*)(ws + WS_K);
  u16*   vT     = (u16*)(ws + WS_VT);
  u16*   pe     = (u16*)(ws + WS_PE);
  u16*   ctx    = (u16*)(ws + WS_CTX);
  u16*   hbf    = (u16*)(ws + WS_HBF);
  float* hf     = (float*)(ws + WS_HF);
  u16*   ff1    = (u16*)(ws + WS_FF1);
  u16*   cur_bf = (u16*)(ws + WS_CURBF);
  u16*   cin    = (u16*)(ws + WS_CIN);
  int*   flag   = (int*)(ws + WS_FLAG);

  // dtype probe + canonicalize non-x float inputs to bf16 (+ fused pe)
  txl_probe<<<1, 64, 0, stream>>>((const u16*)d_in[0], flag);
  txl_convert<<<40488, 256, 0, stream>>>(
      d_in[3], d_in[4], d_in[5], d_in[6], d_in[7], d_in[8],
      d_in[9], d_in[10], d_in[11], d_in[12], d_in[13], d_in[14], d_in[15], d_in[16],
      cin, pe, flag);
  // x -> [T,B,D] directly from raw input (depends only on probe; overlaps convert)
  txl_transpose_in<<<8192, 256, 0, stream>>>(d_in[0], cur_bf, cur_f, d_out, flag);

  const u16* ub = cin + OFF_UB;
  const u16* vb = cin + OFF_VB;

  // r = pe @ pos_w^T for BOTH layers (z = layer)
  txl_gemm_r<<<dim3(12, 4, 2), 256, 0, stream>>>(
      pe, cin + OFF_POSW, rb2, 1536, 512, 512);

  for (int l = 0; l < NLAYER; ++l) {
    // qkv: A-split (rows<2048 from mems[l], rest from cur_bf); bf16 compact C
    txl_gemm4<2><<<dim3(48, 12, 1), 256, 0, stream>>>(
        cin + OFF_MEMS + (size_t)l * 1048576, cur_bf, 2048,
        cin + OFF_QKVW + (size_t)l * 786432, nullptr, Cqkv, nullptr, 6144, 1536, 512, 512);
    // fused V-transpose + q/k scatter (q pre-scaled by SCALE2)
    txl_qkv_post<<<25344, 256, 0, stream>>>(Cqkv, ub, vb, qu, qv, kb, vT);
    // attention: 2 balanced K-pieces per supertile + merge
    txl_attn9<<<1024, 256, 0, stream>>>(qu, qv, kb, vT, rb2 + (size_t)l * 786432,
                                        Ob0, Ob1, Lb0, Lb1);
    txl_attn_merge<<<8192, 256, 0, stream>>>(Ob0, Ob1, Lb0, Lb1, ctx);
    // out projection: split-K S=2 (partials summed in ln1)
    txl_gemm4<0><<<dim3(32, 4, 2), 256, 0, stream>>>(
        ctx, ctx, 1 << 30, cin + OFF_OUTW + (size_t)l * 262144, Cbuf,
        nullptr, nullptr, 4096, 512, 512, 256);
    txl_ln<<<4096, 256, 0, stream>>>(Cbuf, 2, nullptr, cur_f,
                                     cin + OFF_LN1S + l * 512, cin + OFF_LN1B + l * 512,
                                     hbf, hf, nullptr, 0, nullptr, flag);
    // FFN1 (S=1, fused bias+relu)
    txl_gemm4<1><<<dim3(32, 16, 1), 256, 0, stream>>>(
        hbf, hbf, 1 << 30, cin + OFF_L1W + (size_t)l * 1048576, nullptr,
        ff1, cin + OFF_L1B + l * 2048, 4096, 2048, 512, 512);
    // FFN2: split-K S=4 (partials summed in ln2)
    txl_gemm4<0><<<dim3(32, 4, 4), 256, 0, stream>>>(
        ff1, ff1, 1 << 30, cin + OFF_L2W + (size_t)l * 1048576, Cbuf,
        nullptr, nullptr, 4096, 512, 2048, 512);
    // ln2 with fused new_mems[l+1] store (+ fused final transpose-store on last layer)
    txl_ln<<<4096, 256, 0, stream>>>(Cbuf, 4, cin + OFF_L2B + l * 512, hf,
                                     cin + OFF_LN2S + l * 512, cin + OFF_LN2B + l * 512,
                                     cur_bf, cur_f, d_out, 2097152 + (l + 1) * 1048576,
                                     (l == NLAYER - 1) ? d_out : nullptr, flag);
  }
}